// Round 1
// baseline (1117.669 us; speedup 1.0000x reference)
//
#include <hip/hip_runtime.h>

constexpr int GS_BLOCKS = 2048;
constexpr int THREADS   = 256;

// ---------------- ego0 = concat(user, item), vectorized float4 ----------------
__global__ void k_concat(const float4* __restrict__ u, const float4* __restrict__ it,
                         float4* __restrict__ dst, int uf4, int tot) {
  int stride = gridDim.x * blockDim.x;
  for (int i = blockIdx.x * blockDim.x + threadIdx.x; i < tot; i += stride)
    dst[i] = (i < uf4) ? u[i] : it[i - uf4];
}

// ---------------- CSR build: histogram ----------------
__global__ void k_hist(const int* __restrict__ rows, int nnz, int* __restrict__ cnt) {
  int stride = gridDim.x * blockDim.x;
  for (int i = blockIdx.x * blockDim.x + threadIdx.x; i < nnz; i += stride)
    atomicAdd(&cnt[rows[i]], 1);
}

// ---------------- scan step 1: per-block (1024 elems) sums ----------------
__global__ void k_scan_partial(const int* __restrict__ cnt, int n, int* __restrict__ bsums) {
  __shared__ int sh[THREADS];
  int t = threadIdx.x;
  int base = blockIdx.x * 1024 + t * 4;
  int s = 0;
#pragma unroll
  for (int k = 0; k < 4; k++) { int i = base + k; if (i < n) s += cnt[i]; }
  sh[t] = s; __syncthreads();
  for (int off = THREADS / 2; off > 0; off >>= 1) {
    if (t < off) sh[t] += sh[t + off];
    __syncthreads();
  }
  if (t == 0) bsums[blockIdx.x] = sh[0];
}

// ---------------- scan step 2: exclusive scan of block sums (<=512) ----------------
__global__ void k_scan_bsums(const int* __restrict__ bsums, int nb, int* __restrict__ boffs) {
  __shared__ int a[512];
  int t = threadIdx.x;
  int mine = (t < nb) ? bsums[t] : 0;
  a[t] = mine; __syncthreads();
  for (int off = 1; off < 512; off <<= 1) {
    int x = (t >= off) ? a[t - off] : 0;
    __syncthreads();
    a[t] += x;
    __syncthreads();
  }
  if (t < nb) boffs[t] = a[t] - mine;  // exclusive
}

// ---------------- scan step 3: final exclusive scan -> row_ptr, row_fill ----------------
__global__ void k_scan_final(const int* __restrict__ cnt, int n, const int* __restrict__ boffs,
                             int* __restrict__ row_ptr, int* __restrict__ row_fill, int nnz) {
  __shared__ int sh[THREADS];
  int t = threadIdx.x;
  int base = blockIdx.x * 1024 + t * 4;
  int v0 = (base + 0 < n) ? cnt[base + 0] : 0;
  int v1 = (base + 1 < n) ? cnt[base + 1] : 0;
  int v2 = (base + 2 < n) ? cnt[base + 2] : 0;
  int v3 = (base + 3 < n) ? cnt[base + 3] : 0;
  int mysum = v0 + v1 + v2 + v3;
  sh[t] = mysum; __syncthreads();
  for (int off = 1; off < THREADS; off <<= 1) {
    int x = (t >= off) ? sh[t - off] : 0;
    __syncthreads();
    sh[t] += x;
    __syncthreads();
  }
  int run = sh[t] - mysum + boffs[blockIdx.x];
  if (base + 0 < n) { row_ptr[base + 0] = run; row_fill[base + 0] = run; run += v0; }
  if (base + 1 < n) { row_ptr[base + 1] = run; row_fill[base + 1] = run; run += v1; }
  if (base + 2 < n) { row_ptr[base + 2] = run; row_fill[base + 2] = run; run += v2; }
  if (base + 3 < n) { row_ptr[base + 3] = run; row_fill[base + 3] = run; run += v3; }
  if (blockIdx.x == 0 && t == 0) row_ptr[n] = nnz;
}

// ---------------- scatter edges into CSR order, packed (col, val) ----------------
__global__ void k_scatter(const int* __restrict__ rows, const int* __restrict__ cols,
                          const float* __restrict__ vals, int nnz,
                          int* __restrict__ row_fill, int2* __restrict__ sedge) {
  int stride = gridDim.x * blockDim.x;
  for (int i = blockIdx.x * blockDim.x + threadIdx.x; i < nnz; i += stride) {
    int r = rows[i];
    int pos = atomicAdd(&row_fill[r], 1);
    sedge[pos] = make_int2(cols[i], __float_as_int(vals[i]));
  }
}

// ---------------- row-parallel SpMM: 16 lanes per row, float4 per lane ----------------
// Fused epilogue: next = spmm; out = layer0 ? next : out+next; layer2 also *1/3
__global__ void k_spmm(const int* __restrict__ row_ptr, const int2* __restrict__ sedge,
                       const float* __restrict__ prev, float* __restrict__ next,
                       float* __restrict__ out, int n, int layer) {
  int gid = blockIdx.x * blockDim.x + threadIdx.x;
  int row = gid >> 4, l = gid & 15;
  if (row >= n) return;
  int s = row_ptr[row], e = row_ptr[row + 1];
  float ax = 0.f, ay = 0.f, az = 0.f, aw = 0.f;
  for (int j = s; j < e; ++j) {
    int2 ed = sedge[j];
    float v = __int_as_float(ed.y);
    const float4 x = *reinterpret_cast<const float4*>(prev + (size_t)ed.x * 64 + l * 4);
    ax = fmaf(v, x.x, ax); ay = fmaf(v, x.y, ay);
    az = fmaf(v, x.z, az); aw = fmaf(v, x.w, aw);
  }
  *reinterpret_cast<float4*>(next + (size_t)row * 64 + l * 4) = make_float4(ax, ay, az, aw);
  float4* op = reinterpret_cast<float4*>(out + (size_t)row * 64 + l * 4);
  if (layer == 0) {
    *op = make_float4(ax, ay, az, aw);
  } else if (layer == 1) {
    float4 o = *op; o.x += ax; o.y += ay; o.z += az; o.w += aw; *op = o;
  } else {
    const float inv3 = 1.0f / 3.0f;
    float4 o = *op;
    o.x = (o.x + ax) * inv3; o.y = (o.y + ay) * inv3;
    o.z = (o.z + az) * inv3; o.w = (o.w + aw) * inv3;
    *op = o;
  }
}

// ---------------- fallback path: edge-parallel atomics (if ws too small for CSR) ----------------
__global__ void k_edge_atomic(const int* __restrict__ rows, const int* __restrict__ cols,
                              const float* __restrict__ vals, long long tot16,
                              const float* __restrict__ prev, float* __restrict__ nxt) {
  long long stride = (long long)gridDim.x * blockDim.x;
  for (long long i = (long long)blockIdx.x * blockDim.x + threadIdx.x; i < tot16; i += stride) {
    int e = (int)(i >> 4), l = (int)(i & 15);
    int r = rows[e], c = cols[e];
    float v = vals[e];
    const float4 x = *reinterpret_cast<const float4*>(prev + (size_t)c * 64 + l * 4);
    float* d = nxt + (size_t)r * 64 + l * 4;
    atomicAdd(d + 0, v * x.x); atomicAdd(d + 1, v * x.y);
    atomicAdd(d + 2, v * x.z); atomicAdd(d + 3, v * x.w);
  }
}

__global__ void k_accum(const float4* __restrict__ nxt, float4* __restrict__ out, int tot, int layer) {
  int stride = gridDim.x * blockDim.x;
  for (int i = blockIdx.x * blockDim.x + threadIdx.x; i < tot; i += stride) {
    float4 a = nxt[i];
    if (layer == 0) {
      out[i] = a;
    } else if (layer == 1) {
      float4 o = out[i]; o.x += a.x; o.y += a.y; o.z += a.z; o.w += a.w; out[i] = o;
    } else {
      const float inv3 = 1.0f / 3.0f;
      float4 o = out[i];
      o.x = (o.x + a.x) * inv3; o.y = (o.y + a.y) * inv3;
      o.z = (o.z + a.z) * inv3; o.w = (o.w + a.w) * inv3;
      out[i] = o;
    }
  }
}

extern "C" void kernel_launch(void* const* d_in, const int* in_sizes, int n_in,
                              void* d_out, int out_size, void* d_ws, size_t ws_size,
                              hipStream_t stream) {
  const float* user = (const float*)d_in[0];
  const float* item = (const float*)d_in[1];
  const float* vals = (const float*)d_in[2];
  const int*   rows = (const int*)d_in[3];
  const int*   cols = (const int*)d_in[4];
  const int D = 64;
  const int num_users = in_sizes[0] / D;
  const int num_items = in_sizes[1] / D;
  const int nnz = in_sizes[2];
  const int N = num_users + num_items;
  float* out = (float*)d_out;

  // ---- carve workspace ----
  size_t off = 0;
  auto carve = [&](size_t bytes) -> char* {
    char* p = (char*)d_ws + off;
    off = (off + bytes + 255) & ~(size_t)255;
    return p;
  };
  size_t egoBytes = (size_t)N * D * sizeof(float);
  float* egoA = (float*)carve(egoBytes);
  float* egoB = (float*)carve(egoBytes);
  int nb = (N + 1023) / 1024;
  int*  row_cnt  = (int*)carve((size_t)N * 4);
  int*  row_ptr  = (int*)carve((size_t)(N + 1) * 4);
  int*  row_fill = (int*)carve((size_t)N * 4);
  int*  bsums    = (int*)carve(512 * 4);
  int*  boffs    = (int*)carve(512 * 4);
  int2* sedge    = (int2*)carve((size_t)nnz * 8);
  bool use_csr = (off <= ws_size) && (nb <= 512);

  int totF4 = N * (D / 4);
  int uf4   = num_users * (D / 4);
  k_concat<<<GS_BLOCKS, THREADS, 0, stream>>>((const float4*)user, (const float4*)item,
                                              (float4*)egoA, uf4, totF4);

  if (use_csr) {
    hipMemsetAsync(row_cnt, 0, (size_t)N * 4, stream);
    k_hist<<<GS_BLOCKS, THREADS, 0, stream>>>(rows, nnz, row_cnt);
    k_scan_partial<<<nb, THREADS, 0, stream>>>(row_cnt, N, bsums);
    k_scan_bsums<<<1, 512, 0, stream>>>(bsums, nb, boffs);
    k_scan_final<<<nb, THREADS, 0, stream>>>(row_cnt, N, boffs, row_ptr, row_fill, nnz);
    k_scatter<<<GS_BLOCKS, THREADS, 0, stream>>>(rows, cols, vals, nnz, row_fill, sedge);

    float* prev = egoA;
    float* next = egoB;
    int spmm_blocks = (N * 16 + THREADS - 1) / THREADS;
    for (int layer = 0; layer < 3; ++layer) {
      k_spmm<<<spmm_blocks, THREADS, 0, stream>>>(row_ptr, sedge, prev, next, out, N, layer);
      float* t = prev; prev = next; next = t;
    }
  } else {
    // atomic fallback: needs only the two ego buffers
    float* prev = egoA;
    float* next = egoB;
    long long tot16 = (long long)nnz * 16;
    for (int layer = 0; layer < 3; ++layer) {
      hipMemsetAsync(next, 0, egoBytes, stream);
      k_edge_atomic<<<GS_BLOCKS * 2, THREADS, 0, stream>>>(rows, cols, vals, tot16, prev, next);
      k_accum<<<GS_BLOCKS, THREADS, 0, stream>>>((const float4*)next, (float4*)out, totF4, layer);
      float* t = prev; prev = next; next = t;
    }
  }
}

// Round 2
// 1112.673 us; speedup vs baseline: 1.0045x; 1.0045x over previous
//
#include <hip/hip_runtime.h>

constexpr int GS_BLOCKS = 2048;
constexpr int THREADS   = 256;

// ---------------- ego0 = concat(user, item), vectorized float4 ----------------
__global__ void k_concat(const float4* __restrict__ u, const float4* __restrict__ it,
                         float4* __restrict__ dst, int uf4, int tot) {
  int stride = gridDim.x * blockDim.x;
  for (int i = blockIdx.x * blockDim.x + threadIdx.x; i < tot; i += stride)
    dst[i] = (i < uf4) ? u[i] : it[i - uf4];
}

// ---------------- CSR build: histogram ----------------
__global__ void k_hist(const int* __restrict__ rows, int nnz, int* __restrict__ cnt) {
  int stride = gridDim.x * blockDim.x;
  for (int i = blockIdx.x * blockDim.x + threadIdx.x; i < nnz; i += stride)
    atomicAdd(&cnt[__builtin_nontemporal_load(rows + i)], 1);
}

// ---------------- scan step 1: per-block (1024 elems) sums ----------------
__global__ void k_scan_partial(const int* __restrict__ cnt, int n, int* __restrict__ bsums) {
  __shared__ int sh[THREADS];
  int t = threadIdx.x;
  int base = blockIdx.x * 1024 + t * 4;
  int s = 0;
#pragma unroll
  for (int k = 0; k < 4; k++) { int i = base + k; if (i < n) s += cnt[i]; }
  sh[t] = s; __syncthreads();
  for (int off = THREADS / 2; off > 0; off >>= 1) {
    if (t < off) sh[t] += sh[t + off];
    __syncthreads();
  }
  if (t == 0) bsums[blockIdx.x] = sh[0];
}

// ---------------- scan step 2: exclusive scan of block sums (<=512) ----------------
__global__ void k_scan_bsums(const int* __restrict__ bsums, int nb, int* __restrict__ boffs) {
  __shared__ int a[512];
  int t = threadIdx.x;
  int mine = (t < nb) ? bsums[t] : 0;
  a[t] = mine; __syncthreads();
  for (int off = 1; off < 512; off <<= 1) {
    int x = (t >= off) ? a[t - off] : 0;
    __syncthreads();
    a[t] += x;
    __syncthreads();
  }
  if (t < nb) boffs[t] = a[t] - mine;  // exclusive
}

// ---------------- scan step 3: final exclusive scan -> row_ptr, row_fill ----------------
__global__ void k_scan_final(const int* __restrict__ cnt, int n, const int* __restrict__ boffs,
                             int* __restrict__ row_ptr, int* __restrict__ row_fill, int nnz) {
  __shared__ int sh[THREADS];
  int t = threadIdx.x;
  int base = blockIdx.x * 1024 + t * 4;
  int v0 = (base + 0 < n) ? cnt[base + 0] : 0;
  int v1 = (base + 1 < n) ? cnt[base + 1] : 0;
  int v2 = (base + 2 < n) ? cnt[base + 2] : 0;
  int v3 = (base + 3 < n) ? cnt[base + 3] : 0;
  int mysum = v0 + v1 + v2 + v3;
  sh[t] = mysum; __syncthreads();
  for (int off = 1; off < THREADS; off <<= 1) {
    int x = (t >= off) ? sh[t - off] : 0;
    __syncthreads();
    sh[t] += x;
    __syncthreads();
  }
  int run = sh[t] - mysum + boffs[blockIdx.x];
  if (base + 0 < n) { row_ptr[base + 0] = run; row_fill[base + 0] = run; run += v0; }
  if (base + 1 < n) { row_ptr[base + 1] = run; row_fill[base + 1] = run; run += v1; }
  if (base + 2 < n) { row_ptr[base + 2] = run; row_fill[base + 2] = run; run += v2; }
  if (base + 3 < n) { row_ptr[base + 3] = run; row_fill[base + 3] = run; run += v3; }
  if (blockIdx.x == 0 && t == 0) row_ptr[n] = nnz;
}

// ---------------- XCD-pinned filter-scan scatter ----------------
// 16 contiguous row-groups (~2.5 MB CSR output each). Cohort = blocks with the
// same blockIdx%8 (one XCD on MI355X's round-robin dispatch). Each cohort makes
// 2 full passes over the edge list, handling groups {x, x+8}: scattered writes
// land only inside that group's 2.5 MB window, which stays L2-resident on that
// XCD, so lines fill completely before a single full-line writeback.
// Correctness does NOT depend on the XCD mapping (filter is by row value).
__global__ void k_scatter_xcd(const int* __restrict__ rows, const int* __restrict__ cols,
                              const float* __restrict__ vals, int nnz, int RG,
                              int* __restrict__ row_fill, int2* __restrict__ sedge) {
  int x = blockIdx.x & 7;
  int cb = blockIdx.x >> 3;
  int cohortThreads = (gridDim.x >> 3) * blockDim.x;
  int tid = cb * blockDim.x + threadIdx.x;
#pragma unroll
  for (int s = 0; s < 2; ++s) {
    int lo = (x + 8 * s) * RG;
    int hi = lo + RG;
    for (int i = tid; i < nnz; i += cohortThreads) {
      int r = __builtin_nontemporal_load(rows + i);
      if (r >= lo && r < hi) {
        int c = __builtin_nontemporal_load(cols + i);
        float v = __builtin_nontemporal_load(vals + i);
        int pos = atomicAdd(&row_fill[r], 1);
        sedge[pos] = make_int2(c, __float_as_int(v));
      }
    }
  }
}

// ---------------- row-parallel SpMM: 16 lanes per row, float4 per lane ----------------
// 2-edge unroll: two independent gathers in flight, two accumulator sets.
// Fused epilogue: next = spmm; out = layer0 ? next : out+next; layer2 also *1/3
__global__ void k_spmm(const int* __restrict__ row_ptr, const int2* __restrict__ sedge,
                       const float* __restrict__ prev, float* __restrict__ next,
                       float* __restrict__ out, int n, int layer) {
  int gid = blockIdx.x * blockDim.x + threadIdx.x;
  int row = gid >> 4, l = gid & 15;
  if (row >= n) return;
  int s = row_ptr[row], e = row_ptr[row + 1];
  float ax = 0.f, ay = 0.f, az = 0.f, aw = 0.f;
  float bx = 0.f, by = 0.f, bz = 0.f, bw = 0.f;
  int j = s;
  for (; j + 2 <= e; j += 2) {
    int2 e0 = sedge[j];
    int2 e1 = sedge[j + 1];
    float v0 = __int_as_float(e0.y);
    float v1 = __int_as_float(e1.y);
    const float4 x0 = *reinterpret_cast<const float4*>(prev + (size_t)e0.x * 64 + l * 4);
    const float4 x1 = *reinterpret_cast<const float4*>(prev + (size_t)e1.x * 64 + l * 4);
    ax = fmaf(v0, x0.x, ax); ay = fmaf(v0, x0.y, ay);
    az = fmaf(v0, x0.z, az); aw = fmaf(v0, x0.w, aw);
    bx = fmaf(v1, x1.x, bx); by = fmaf(v1, x1.y, by);
    bz = fmaf(v1, x1.z, bz); bw = fmaf(v1, x1.w, bw);
  }
  if (j < e) {
    int2 e0 = sedge[j];
    float v0 = __int_as_float(e0.y);
    const float4 x0 = *reinterpret_cast<const float4*>(prev + (size_t)e0.x * 64 + l * 4);
    ax = fmaf(v0, x0.x, ax); ay = fmaf(v0, x0.y, ay);
    az = fmaf(v0, x0.z, az); aw = fmaf(v0, x0.w, aw);
  }
  ax += bx; ay += by; az += bz; aw += bw;
  *reinterpret_cast<float4*>(next + (size_t)row * 64 + l * 4) = make_float4(ax, ay, az, aw);
  float4* op = reinterpret_cast<float4*>(out + (size_t)row * 64 + l * 4);
  if (layer == 0) {
    *op = make_float4(ax, ay, az, aw);
  } else if (layer == 1) {
    float4 o = *op; o.x += ax; o.y += ay; o.z += az; o.w += aw; *op = o;
  } else {
    const float inv3 = 1.0f / 3.0f;
    float4 o = *op;
    o.x = (o.x + ax) * inv3; o.y = (o.y + ay) * inv3;
    o.z = (o.z + az) * inv3; o.w = (o.w + aw) * inv3;
    *op = o;
  }
}

// ---------------- fallback path: edge-parallel atomics (if ws too small for CSR) ----------------
__global__ void k_edge_atomic(const int* __restrict__ rows, const int* __restrict__ cols,
                              const float* __restrict__ vals, long long tot16,
                              const float* __restrict__ prev, float* __restrict__ nxt) {
  long long stride = (long long)gridDim.x * blockDim.x;
  for (long long i = (long long)blockIdx.x * blockDim.x + threadIdx.x; i < tot16; i += stride) {
    int e = (int)(i >> 4), l = (int)(i & 15);
    int r = rows[e], c = cols[e];
    float v = vals[e];
    const float4 x = *reinterpret_cast<const float4*>(prev + (size_t)c * 64 + l * 4);
    float* d = nxt + (size_t)r * 64 + l * 4;
    atomicAdd(d + 0, v * x.x); atomicAdd(d + 1, v * x.y);
    atomicAdd(d + 2, v * x.z); atomicAdd(d + 3, v * x.w);
  }
}

__global__ void k_accum(const float4* __restrict__ nxt, float4* __restrict__ out, int tot, int layer) {
  int stride = gridDim.x * blockDim.x;
  for (int i = blockIdx.x * blockDim.x + threadIdx.x; i < tot; i += stride) {
    float4 a = nxt[i];
    if (layer == 0) {
      out[i] = a;
    } else if (layer == 1) {
      float4 o = out[i]; o.x += a.x; o.y += a.y; o.z += a.z; o.w += a.w; out[i] = o;
    } else {
      const float inv3 = 1.0f / 3.0f;
      float4 o = out[i];
      o.x = (o.x + a.x) * inv3; o.y = (o.y + a.y) * inv3;
      o.z = (o.z + a.z) * inv3; o.w = (o.w + a.w) * inv3;
      out[i] = o;
    }
  }
}

extern "C" void kernel_launch(void* const* d_in, const int* in_sizes, int n_in,
                              void* d_out, int out_size, void* d_ws, size_t ws_size,
                              hipStream_t stream) {
  const float* user = (const float*)d_in[0];
  const float* item = (const float*)d_in[1];
  const float* vals = (const float*)d_in[2];
  const int*   rows = (const int*)d_in[3];
  const int*   cols = (const int*)d_in[4];
  const int D = 64;
  const int num_users = in_sizes[0] / D;
  const int num_items = in_sizes[1] / D;
  const int nnz = in_sizes[2];
  const int N = num_users + num_items;
  float* out = (float*)d_out;

  // ---- carve workspace ----
  size_t off = 0;
  auto carve = [&](size_t bytes) -> char* {
    char* p = (char*)d_ws + off;
    off = (off + bytes + 255) & ~(size_t)255;
    return p;
  };
  size_t egoBytes = (size_t)N * D * sizeof(float);
  float* egoA = (float*)carve(egoBytes);
  float* egoB = (float*)carve(egoBytes);
  int nb = (N + 1023) / 1024;
  int*  row_cnt  = (int*)carve((size_t)N * 4);
  int*  row_ptr  = (int*)carve((size_t)(N + 1) * 4);
  int*  row_fill = (int*)carve((size_t)N * 4);
  int*  bsums    = (int*)carve(512 * 4);
  int*  boffs    = (int*)carve(512 * 4);
  int2* sedge    = (int2*)carve((size_t)nnz * 8);
  bool use_csr = (off <= ws_size) && (nb <= 512);

  int totF4 = N * (D / 4);
  int uf4   = num_users * (D / 4);
  k_concat<<<GS_BLOCKS, THREADS, 0, stream>>>((const float4*)user, (const float4*)item,
                                              (float4*)egoA, uf4, totF4);

  if (use_csr) {
    hipMemsetAsync(row_cnt, 0, (size_t)N * 4, stream);
    k_hist<<<GS_BLOCKS, THREADS, 0, stream>>>(rows, nnz, row_cnt);
    k_scan_partial<<<nb, THREADS, 0, stream>>>(row_cnt, N, bsums);
    k_scan_bsums<<<1, 512, 0, stream>>>(bsums, nb, boffs);
    k_scan_final<<<nb, THREADS, 0, stream>>>(row_cnt, N, boffs, row_ptr, row_fill, nnz);
    int RG = (N + 15) / 16;  // 16 row-groups, 2 per XCD
    k_scatter_xcd<<<GS_BLOCKS, THREADS, 0, stream>>>(rows, cols, vals, nnz, RG, row_fill, sedge);

    float* prev = egoA;
    float* next = egoB;
    int spmm_blocks = (N * 16 + THREADS - 1) / THREADS;
    for (int layer = 0; layer < 3; ++layer) {
      k_spmm<<<spmm_blocks, THREADS, 0, stream>>>(row_ptr, sedge, prev, next, out, N, layer);
      float* t = prev; prev = next; next = t;
    }
  } else {
    // atomic fallback: needs only the two ego buffers
    float* prev = egoA;
    float* next = egoB;
    long long tot16 = (long long)nnz * 16;
    for (int layer = 0; layer < 3; ++layer) {
      hipMemsetAsync(next, 0, egoBytes, stream);
      k_edge_atomic<<<GS_BLOCKS * 2, THREADS, 0, stream>>>(rows, cols, vals, tot16, prev, next);
      k_accum<<<GS_BLOCKS, THREADS, 0, stream>>>((const float4*)next, (float4*)out, totF4, layer);
      float* t = prev; prev = next; next = t;
    }
  }
}

// Round 3
// 1042.417 us; speedup vs baseline: 1.0722x; 1.0674x over previous
//
#include <hip/hip_runtime.h>

constexpr int GS_BLOCKS = 2048;
constexpr int THREADS   = 256;
constexpr int RB_LOG    = 9;               // rows per bucket = 512
constexpr int RB        = 1 << RB_LOG;
constexpr int CH        = 8192;            // edges per Pass-A chunk
constexpr int COL_BITS  = 19;              // N < 2^19
constexpr int COL_MASK  = (1 << COL_BITS) - 1;
constexpr int MAX_NB    = 1024;            // max buckets supported by LDS arrays

// ---------------- ego0 = concat(user, item) (fallback path only) ----------------
__global__ void k_concat(const float4* __restrict__ u, const float4* __restrict__ it,
                         float4* __restrict__ dst, int uf4, int tot) {
  int stride = gridDim.x * blockDim.x;
  for (int i = blockIdx.x * blockDim.x + threadIdx.x; i < tot; i += stride)
    dst[i] = (i < uf4) ? u[i] : it[i - uf4];
}

// ---------------- hist: per-row counts + per-bucket counts (one edge-stream pass) ----------------
__global__ void k_hist2(const int* __restrict__ rows, int nnz, int nB,
                        int* __restrict__ row_cnt, int* __restrict__ bucket_cnt) {
  __shared__ int lcnt[MAX_NB];
  int t = threadIdx.x;
  for (int j = t; j < nB; j += THREADS) lcnt[j] = 0;
  __syncthreads();
  int stride = gridDim.x * blockDim.x;
  for (int i = blockIdx.x * blockDim.x + t; i < nnz; i += stride) {
    int r = rows[i];
    atomicAdd(&row_cnt[r], 1);
    atomicAdd(&lcnt[r >> RB_LOG], 1);
  }
  __syncthreads();
  for (int j = t; j < nB; j += THREADS)
    if (lcnt[j]) atomicAdd(&bucket_cnt[j], lcnt[j]);
}

// ---------------- exclusive scan of bucket counts (nB <= 1024), 1 block ----------------
__global__ void __launch_bounds__(1024)
k_scan_buckets(const int* __restrict__ bucket_cnt, int nB,
               int* __restrict__ bucket_base, int* __restrict__ bucket_fill) {
  __shared__ int a[1024];
  int t = threadIdx.x;
  int mine = (t < nB) ? bucket_cnt[t] : 0;
  a[t] = mine; __syncthreads();
  for (int off = 1; off < 1024; off <<= 1) {
    int x = (t >= off) ? a[t - off] : 0;
    __syncthreads();
    a[t] += x;
    __syncthreads();
  }
  int excl = a[t] - mine;
  if (t < nB) { bucket_base[t] = excl; bucket_fill[t] = excl; }
  if (t == 1023) bucket_base[nB] = a[1023];  // total = nnz
}

// ---------------- scan step 1: per-block (1024 elems) sums ----------------
__global__ void k_scan_partial(const int* __restrict__ cnt, int n, int* __restrict__ bsums) {
  __shared__ int sh[THREADS];
  int t = threadIdx.x;
  int base = blockIdx.x * 1024 + t * 4;
  int s = 0;
#pragma unroll
  for (int k = 0; k < 4; k++) { int i = base + k; if (i < n) s += cnt[i]; }
  sh[t] = s; __syncthreads();
  for (int off = THREADS / 2; off > 0; off >>= 1) {
    if (t < off) sh[t] += sh[t + off];
    __syncthreads();
  }
  if (t == 0) bsums[blockIdx.x] = sh[0];
}

// ---------------- scan step 2: exclusive scan of block sums (<=512) ----------------
__global__ void k_scan_bsums(const int* __restrict__ bsums, int nb, int* __restrict__ boffs) {
  __shared__ int a[512];
  int t = threadIdx.x;
  int mine = (t < nb) ? bsums[t] : 0;
  a[t] = mine; __syncthreads();
  for (int off = 1; off < 512; off <<= 1) {
    int x = (t >= off) ? a[t - off] : 0;
    __syncthreads();
    a[t] += x;
    __syncthreads();
  }
  if (t < nb) boffs[t] = a[t] - mine;  // exclusive
}

// ---------------- scan step 3: final exclusive scan -> row_ptr ----------------
__global__ void k_scan_final(const int* __restrict__ cnt, int n, const int* __restrict__ boffs,
                             int* __restrict__ row_ptr, int nnz) {
  __shared__ int sh[THREADS];
  int t = threadIdx.x;
  int base = blockIdx.x * 1024 + t * 4;
  int v0 = (base + 0 < n) ? cnt[base + 0] : 0;
  int v1 = (base + 1 < n) ? cnt[base + 1] : 0;
  int v2 = (base + 2 < n) ? cnt[base + 2] : 0;
  int v3 = (base + 3 < n) ? cnt[base + 3] : 0;
  int mysum = v0 + v1 + v2 + v3;
  sh[t] = mysum; __syncthreads();
  for (int off = 1; off < THREADS; off <<= 1) {
    int x = (t >= off) ? sh[t - off] : 0;
    __syncthreads();
    sh[t] += x;
    __syncthreads();
  }
  int run = sh[t] - mysum + boffs[blockIdx.x];
  if (base + 0 < n) { row_ptr[base + 0] = run; run += v0; }
  if (base + 1 < n) { row_ptr[base + 1] = run; run += v1; }
  if (base + 2 < n) { row_ptr[base + 2] = run; run += v2; }
  if (base + 3 < n) { row_ptr[base + 3] = run; run += v3; }
  if (blockIdx.x == 0 && t == 0) row_ptr[n] = nnz;
}

// ---------------- Pass A: chunk-local LDS binning into row-buckets ----------------
// Each block owns one CH-edge chunk: LDS bucket histogram -> LDS scan ->
// global reservation per bucket -> scatter (packed rowLocal|col, val) in
// bucket-major bursts. Writes are ~(CH/nB)-edge bursts, not random 8B stores.
__global__ void __launch_bounds__(THREADS)
k_bin(const int* __restrict__ rows, const int* __restrict__ cols,
      const float* __restrict__ vals, int nnz, int nB,
      int* __restrict__ bucket_fill, int2* __restrict__ binned) {
  __shared__ int bcnt[MAX_NB];      // counts, then reused as global-base per bucket
  __shared__ int boff[MAX_NB + 1];  // chunk-local exclusive offsets
  __shared__ int bfill[MAX_NB];     // chunk-local running rank
  __shared__ int sarr[THREADS];
  int t = threadIdx.x;
  int c0 = blockIdx.x * CH;
  for (int j = t; j < nB; j += THREADS) { bcnt[j] = 0; bfill[j] = 0; }
  __syncthreads();
  // phase 1: count
  for (int k = 0; k < CH / THREADS; k++) {
    int e = c0 + t + k * THREADS;
    if (e < nnz) atomicAdd(&bcnt[rows[e] >> RB_LOG], 1);
  }
  __syncthreads();
  // phase 2: exclusive scan of bcnt -> boff (4 blocked slots per thread)
  int i0 = t * 4;
  int v0 = (i0 + 0 < nB) ? bcnt[i0 + 0] : 0;
  int v1 = (i0 + 1 < nB) ? bcnt[i0 + 1] : 0;
  int v2 = (i0 + 2 < nB) ? bcnt[i0 + 2] : 0;
  int v3 = (i0 + 3 < nB) ? bcnt[i0 + 3] : 0;
  int s = v0 + v1 + v2 + v3;
  sarr[t] = s; __syncthreads();
  for (int off = 1; off < THREADS; off <<= 1) {
    int x = (t >= off) ? sarr[t - off] : 0;
    __syncthreads();
    sarr[t] += x;
    __syncthreads();
  }
  int excl = sarr[t] - s;
  if (i0 + 0 < nB) boff[i0 + 0] = excl;
  if (i0 + 1 < nB) boff[i0 + 1] = excl + v0;
  if (i0 + 2 < nB) boff[i0 + 2] = excl + v0 + v1;
  if (i0 + 3 < nB) boff[i0 + 3] = excl + v0 + v1 + v2;
  if (t == THREADS - 1) boff[nB] = sarr[t];
  __syncthreads();
  // phase 3: reserve global ranges (bcnt becomes global base)
  for (int b = t; b < nB; b += THREADS) {
    int c = boff[b + 1] - boff[b];
    if (c > 0) bcnt[b] = atomicAdd(&bucket_fill[b], c);
  }
  __syncthreads();
  // phase 4: scatter into bucket-major bursts
  for (int k = 0; k < CH / THREADS; k++) {
    int e = c0 + t + k * THREADS;
    if (e < nnz) {
      int r = rows[e];
      int b = r >> RB_LOG;
      int rank = atomicAdd(&bfill[b], 1);
      int packed = ((r & (RB - 1)) << COL_BITS) | cols[e];
      binned[bcnt[b] + rank] = make_int2(packed, __float_as_int(vals[e]));
    }
  }
}

// ---------------- Pass B: per-bucket LDS counting sort -> sedge ----------------
// One block per bucket. Scattered writes confined to a ~68KB L2-captive window;
// positions derived from row_ptr (no global atomics).
__global__ void __launch_bounds__(512)
k_bucket_sedge(const int2* __restrict__ binned, const int* __restrict__ bucket_base,
               const int* __restrict__ row_ptr, int2* __restrict__ sedge) {
  __shared__ int rcnt[RB];
  __shared__ int sarr[512];
  int b = blockIdx.x, t = threadIdx.x;
  int e0 = bucket_base[b], e1 = bucket_base[b + 1];
  rcnt[t] = 0;
  __syncthreads();
  for (int j = e0 + t; j < e1; j += 512)
    atomicAdd(&rcnt[(unsigned)binned[j].x >> COL_BITS], 1);
  __syncthreads();
  int mine = rcnt[t];
  sarr[t] = mine; __syncthreads();
  for (int off = 1; off < 512; off <<= 1) {
    int x = (t >= off) ? sarr[t - off] : 0;
    __syncthreads();
    sarr[t] += x;
    __syncthreads();
  }
  int excl = sarr[t] - mine;
  __syncthreads();
  rcnt[t] = excl;            // becomes running fill counter
  __syncthreads();
  int base = row_ptr[b << RB_LOG];
  for (int j = e0 + t; j < e1; j += 512) {
    int2 ed = binned[j];
    int rL = (unsigned)ed.x >> COL_BITS;
    int pos = base + atomicAdd(&rcnt[rL], 1);
    sedge[pos] = make_int2(ed.x & COL_MASK, ed.y);
  }
}

// ---------------- row-parallel SpMM: 16 lanes per row, float4 per lane ----------------
// FUSED: layer 0 gathers directly from user/item (concat fused away).
// int4 edge loads: 2 edges per load, 2 independent gathers in flight.
template <bool FUSED>
__global__ void __launch_bounds__(THREADS)
k_spmm(const int* __restrict__ row_ptr, const int2* __restrict__ sedge,
       const float* __restrict__ prev,
       const float* __restrict__ user, const float* __restrict__ item, int nu,
       float* __restrict__ next, float* __restrict__ out, int n, int layer) {
  int gid = blockIdx.x * blockDim.x + threadIdx.x;
  int row = gid >> 4, l = gid & 15;
  if (row >= n) return;
  int s = row_ptr[row], e = row_ptr[row + 1];
  float ax = 0.f, ay = 0.f, az = 0.f, aw = 0.f;
  float bx = 0.f, by = 0.f, bz = 0.f, bw = 0.f;
  auto gather = [&](int c) -> float4 {
    const float* p;
    if (FUSED) p = (c < nu) ? user + (size_t)c * 64 : item + (size_t)(c - nu) * 64;
    else       p = prev + (size_t)c * 64;
    return *reinterpret_cast<const float4*>(p + l * 4);
  };
  int j = s;
  if (j < e && (j & 1)) {
    int2 ed = sedge[j];
    float v = __int_as_float(ed.y);
    float4 x = gather(ed.x);
    ax = fmaf(v, x.x, ax); ay = fmaf(v, x.y, ay);
    az = fmaf(v, x.z, az); aw = fmaf(v, x.w, aw);
    ++j;
  }
  for (; j + 2 <= e; j += 2) {
    int4 ee = *reinterpret_cast<const int4*>(sedge + j);  // 16B aligned (j even)
    float v0 = __int_as_float(ee.y);
    float v1 = __int_as_float(ee.w);
    float4 x0 = gather(ee.x);
    float4 x1 = gather(ee.z);
    ax = fmaf(v0, x0.x, ax); ay = fmaf(v0, x0.y, ay);
    az = fmaf(v0, x0.z, az); aw = fmaf(v0, x0.w, aw);
    bx = fmaf(v1, x1.x, bx); by = fmaf(v1, x1.y, by);
    bz = fmaf(v1, x1.z, bz); bw = fmaf(v1, x1.w, bw);
  }
  if (j < e) {
    int2 ed = sedge[j];
    float v = __int_as_float(ed.y);
    float4 x = gather(ed.x);
    ax = fmaf(v, x.x, ax); ay = fmaf(v, x.y, ay);
    az = fmaf(v, x.z, az); aw = fmaf(v, x.w, aw);
  }
  ax += bx; ay += by; az += bz; aw += bw;
  *reinterpret_cast<float4*>(next + (size_t)row * 64 + l * 4) = make_float4(ax, ay, az, aw);
  float4* op = reinterpret_cast<float4*>(out + (size_t)row * 64 + l * 4);
  if (layer == 0) {
    *op = make_float4(ax, ay, az, aw);
  } else if (layer == 1) {
    float4 o = *op; o.x += ax; o.y += ay; o.z += az; o.w += aw; *op = o;
  } else {
    const float inv3 = 1.0f / 3.0f;
    float4 o = *op;
    o.x = (o.x + ax) * inv3; o.y = (o.y + ay) * inv3;
    o.z = (o.z + az) * inv3; o.w = (o.w + aw) * inv3;
    *op = o;
  }
}

// ---------------- fallback path: edge-parallel atomics (if ws too small for CSR) ----------------
__global__ void k_edge_atomic(const int* __restrict__ rows, const int* __restrict__ cols,
                              const float* __restrict__ vals, long long tot16,
                              const float* __restrict__ prev, float* __restrict__ nxt) {
  long long stride = (long long)gridDim.x * blockDim.x;
  for (long long i = (long long)blockIdx.x * blockDim.x + threadIdx.x; i < tot16; i += stride) {
    int e = (int)(i >> 4), l = (int)(i & 15);
    int r = rows[e], c = cols[e];
    float v = vals[e];
    const float4 x = *reinterpret_cast<const float4*>(prev + (size_t)c * 64 + l * 4);
    float* d = nxt + (size_t)r * 64 + l * 4;
    atomicAdd(d + 0, v * x.x); atomicAdd(d + 1, v * x.y);
    atomicAdd(d + 2, v * x.z); atomicAdd(d + 3, v * x.w);
  }
}

__global__ void k_accum(const float4* __restrict__ nxt, float4* __restrict__ out, int tot, int layer) {
  int stride = gridDim.x * blockDim.x;
  for (int i = blockIdx.x * blockDim.x + threadIdx.x; i < tot; i += stride) {
    float4 a = nxt[i];
    if (layer == 0) {
      out[i] = a;
    } else if (layer == 1) {
      float4 o = out[i]; o.x += a.x; o.y += a.y; o.z += a.z; o.w += a.w; out[i] = o;
    } else {
      const float inv3 = 1.0f / 3.0f;
      float4 o = out[i];
      o.x = (o.x + a.x) * inv3; o.y = (o.y + a.y) * inv3;
      o.z = (o.z + a.z) * inv3; o.w = (o.w + a.w) * inv3;
      out[i] = o;
    }
  }
}

extern "C" void kernel_launch(void* const* d_in, const int* in_sizes, int n_in,
                              void* d_out, int out_size, void* d_ws, size_t ws_size,
                              hipStream_t stream) {
  const float* user = (const float*)d_in[0];
  const float* item = (const float*)d_in[1];
  const float* vals = (const float*)d_in[2];
  const int*   rows = (const int*)d_in[3];
  const int*   cols = (const int*)d_in[4];
  const int D = 64;
  const int num_users = in_sizes[0] / D;
  const int num_items = in_sizes[1] / D;
  const int nnz = in_sizes[2];
  const int N = num_users + num_items;
  float* out = (float*)d_out;

  // ---- carve workspace ----
  size_t off = 0;
  auto carve = [&](size_t bytes) -> char* {
    char* p = (char*)d_ws + off;
    off = (off + bytes + 255) & ~(size_t)255;
    return p;
  };
  size_t egoBytes = (size_t)N * D * sizeof(float);
  float* egoA = (float*)carve(egoBytes);
  float* egoB = (float*)carve(egoBytes);
  int nb = (N + 1023) / 1024;
  int nB = (N + RB - 1) >> RB_LOG;
  int*  row_cnt     = (int*)carve((size_t)N * 4);
  int*  row_ptr     = (int*)carve((size_t)(N + 1) * 4);
  int*  bsums       = (int*)carve(512 * 4);
  int*  boffs       = (int*)carve(512 * 4);
  int*  bucket_cnt  = (int*)carve((size_t)nB * 4);
  int*  bucket_base = (int*)carve((size_t)(nB + 1) * 4);
  int*  bucket_fill = (int*)carve((size_t)nB * 4);
  int2* sedge       = (int2*)carve((size_t)nnz * 8);
  int2* binned      = (int2*)egoB;  // aliased: egoB first written at layer 1, after Pass B
  bool use_csr = (off <= ws_size) && (nb <= 512) && (nB <= MAX_NB) &&
                 ((size_t)nnz * 8 <= egoBytes) && (N < (1 << COL_BITS));

  if (use_csr) {
    hipMemsetAsync(row_cnt, 0, (size_t)N * 4, stream);
    hipMemsetAsync(bucket_cnt, 0, (size_t)nB * 4, stream);
    k_hist2<<<GS_BLOCKS, THREADS, 0, stream>>>(rows, nnz, nB, row_cnt, bucket_cnt);
    k_scan_buckets<<<1, 1024, 0, stream>>>(bucket_cnt, nB, bucket_base, bucket_fill);
    k_scan_partial<<<nb, THREADS, 0, stream>>>(row_cnt, N, bsums);
    k_scan_bsums<<<1, 512, 0, stream>>>(bsums, nb, boffs);
    k_scan_final<<<nb, THREADS, 0, stream>>>(row_cnt, N, boffs, row_ptr, nnz);
    int nchunks = (nnz + CH - 1) / CH;
    k_bin<<<nchunks, THREADS, 0, stream>>>(rows, cols, vals, nnz, nB, bucket_fill, binned);
    k_bucket_sedge<<<nB, 512, 0, stream>>>(binned, bucket_base, row_ptr, sedge);

    int spmm_blocks = (N * 16 + THREADS - 1) / THREADS;
    // layer 0: fused concat (gathers straight from user/item), writes egoA
    k_spmm<true><<<spmm_blocks, THREADS, 0, stream>>>(row_ptr, sedge, nullptr,
                                                      user, item, num_users,
                                                      egoA, out, N, 0);
    // layer 1: egoA -> egoB (clobbers binned, which is dead now)
    k_spmm<false><<<spmm_blocks, THREADS, 0, stream>>>(row_ptr, sedge, egoA,
                                                       user, item, num_users,
                                                       egoB, out, N, 1);
    // layer 2: egoB -> egoA
    k_spmm<false><<<spmm_blocks, THREADS, 0, stream>>>(row_ptr, sedge, egoB,
                                                       user, item, num_users,
                                                       egoA, out, N, 2);
  } else {
    // atomic fallback: needs only the two ego buffers
    int totF4 = N * (D / 4);
    int uf4   = num_users * (D / 4);
    k_concat<<<GS_BLOCKS, THREADS, 0, stream>>>((const float4*)user, (const float4*)item,
                                                (float4*)egoA, uf4, totF4);
    float* prev = egoA;
    float* next = egoB;
    long long tot16 = (long long)nnz * 16;
    for (int layer = 0; layer < 3; ++layer) {
      hipMemsetAsync(next, 0, egoBytes, stream);
      k_edge_atomic<<<GS_BLOCKS * 2, THREADS, 0, stream>>>(rows, cols, vals, tot16, prev, next);
      k_accum<<<GS_BLOCKS, THREADS, 0, stream>>>((const float4*)next, (float4*)out, totF4, layer);
      float* t = prev; prev = next; next = t;
    }
  }
}

// Round 4
// 841.039 us; speedup vs baseline: 1.3289x; 1.2394x over previous
//
#include <hip/hip_runtime.h>

constexpr int GS_BLOCKS = 2048;
constexpr int THREADS   = 256;
constexpr int RB_LOG    = 9;               // rows per bucket = 512
constexpr int RB        = 1 << RB_LOG;
constexpr int CH        = 8192;            // edges per Pass-A chunk
constexpr int COL_BITS  = 19;              // N < 2^19
constexpr int COL_MASK  = (1 << COL_BITS) - 1;
constexpr int MAX_NB    = 1024;            // max buckets supported by LDS arrays
constexpr int BH_BLOCKS = 1024;            // bucket-hist blocks (merge atomics = nB*BH_BLOCKS)

// ---------------- ego0 = concat(user, item) (fallback path only) ----------------
__global__ void k_concat(const float4* __restrict__ u, const float4* __restrict__ it,
                         float4* __restrict__ dst, int uf4, int tot) {
  int stride = gridDim.x * blockDim.x;
  for (int i = blockIdx.x * blockDim.x + threadIdx.x; i < tot; i += stride)
    dst[i] = (i < uf4) ? u[i] : it[i - uf4];
}

// ---------------- bucket-only histogram: LDS counters, merged once per block ----------------
// No per-row global atomics (those cost 160MB of write-through last round).
__global__ void k_bhist(const int* __restrict__ rows, int nnz, int nB,
                        int* __restrict__ bucket_cnt) {
  __shared__ int lcnt[MAX_NB];
  int t = threadIdx.x;
  for (int j = t; j < nB; j += THREADS) lcnt[j] = 0;
  __syncthreads();
  int stride = gridDim.x * blockDim.x;
  for (int i = blockIdx.x * blockDim.x + t; i < nnz; i += stride)
    atomicAdd(&lcnt[__builtin_nontemporal_load(rows + i) >> RB_LOG], 1);
  __syncthreads();
  for (int j = t; j < nB; j += THREADS)
    if (lcnt[j]) atomicAdd(&bucket_cnt[j], lcnt[j]);
}

// ---------------- exclusive scan of bucket counts (nB <= 1024), 1 block ----------------
__global__ void __launch_bounds__(1024)
k_scan_buckets(const int* __restrict__ bucket_cnt, int nB,
               int* __restrict__ bucket_base, int* __restrict__ bucket_fill) {
  __shared__ int a[1024];
  int t = threadIdx.x;
  int mine = (t < nB) ? bucket_cnt[t] : 0;
  a[t] = mine; __syncthreads();
  for (int off = 1; off < 1024; off <<= 1) {
    int x = (t >= off) ? a[t - off] : 0;
    __syncthreads();
    a[t] += x;
    __syncthreads();
  }
  int excl = a[t] - mine;
  if (t < nB) { bucket_base[t] = excl; bucket_fill[t] = excl; }
  if (t == 1023) bucket_base[nB] = a[1023];  // total = nnz
}

// ---------------- Pass A: chunk-local LDS binning into row-buckets ----------------
__global__ void __launch_bounds__(THREADS)
k_bin(const int* __restrict__ rows, const int* __restrict__ cols,
      const float* __restrict__ vals, int nnz, int nB,
      int* __restrict__ bucket_fill, int2* __restrict__ binned) {
  __shared__ int bcnt[MAX_NB];      // counts, then reused as global-base per bucket
  __shared__ int boff[MAX_NB + 1];  // chunk-local exclusive offsets
  __shared__ int bfill[MAX_NB];     // chunk-local running rank
  __shared__ int sarr[THREADS];
  int t = threadIdx.x;
  int c0 = blockIdx.x * CH;
  for (int j = t; j < nB; j += THREADS) { bcnt[j] = 0; bfill[j] = 0; }
  __syncthreads();
  // phase 1: count
  for (int k = 0; k < CH / THREADS; k++) {
    int e = c0 + t + k * THREADS;
    if (e < nnz) atomicAdd(&bcnt[rows[e] >> RB_LOG], 1);
  }
  __syncthreads();
  // phase 2: exclusive scan of bcnt -> boff (4 blocked slots per thread)
  int i0 = t * 4;
  int v0 = (i0 + 0 < nB) ? bcnt[i0 + 0] : 0;
  int v1 = (i0 + 1 < nB) ? bcnt[i0 + 1] : 0;
  int v2 = (i0 + 2 < nB) ? bcnt[i0 + 2] : 0;
  int v3 = (i0 + 3 < nB) ? bcnt[i0 + 3] : 0;
  int s = v0 + v1 + v2 + v3;
  sarr[t] = s; __syncthreads();
  for (int off = 1; off < THREADS; off <<= 1) {
    int x = (t >= off) ? sarr[t - off] : 0;
    __syncthreads();
    sarr[t] += x;
    __syncthreads();
  }
  int excl = sarr[t] - s;
  if (i0 + 0 < nB) boff[i0 + 0] = excl;
  if (i0 + 1 < nB) boff[i0 + 1] = excl + v0;
  if (i0 + 2 < nB) boff[i0 + 2] = excl + v0 + v1;
  if (i0 + 3 < nB) boff[i0 + 3] = excl + v0 + v1 + v2;
  if (t == THREADS - 1) boff[nB] = sarr[t];
  __syncthreads();
  // phase 3: reserve global ranges (bcnt becomes global base)
  for (int b = t; b < nB; b += THREADS) {
    int c = boff[b + 1] - boff[b];
    if (c > 0) bcnt[b] = atomicAdd(&bucket_fill[b], c);
  }
  __syncthreads();
  // phase 4: scatter into bucket-major bursts
  for (int k = 0; k < CH / THREADS; k++) {
    int e = c0 + t + k * THREADS;
    if (e < nnz) {
      int r = rows[e];
      int b = r >> RB_LOG;
      int rank = atomicAdd(&bfill[b], 1);
      int packed = ((r & (RB - 1)) << COL_BITS) | cols[e];
      binned[bcnt[b] + rank] = make_int2(packed, __float_as_int(vals[e]));
    }
  }
}

// ---------------- Pass B: per-bucket LDS counting sort -> sedge + row_ptr ----------------
// One block per bucket; writes row_ptr from the LDS scan (per-row histogram fused away).
__global__ void __launch_bounds__(512)
k_bucket_sedge(const int2* __restrict__ binned, const int* __restrict__ bucket_base,
               int* __restrict__ row_ptr, int N, int nnz, int2* __restrict__ sedge) {
  __shared__ int rcnt[RB];
  __shared__ int sarr[512];
  int b = blockIdx.x, t = threadIdx.x;
  int e0 = bucket_base[b], e1 = bucket_base[b + 1];
  rcnt[t] = 0;
  __syncthreads();
  for (int j = e0 + t; j < e1; j += 512)
    atomicAdd(&rcnt[(unsigned)binned[j].x >> COL_BITS], 1);
  __syncthreads();
  int mine = rcnt[t];
  sarr[t] = mine; __syncthreads();
  for (int off = 1; off < 512; off <<= 1) {
    int x = (t >= off) ? sarr[t - off] : 0;
    __syncthreads();
    sarr[t] += x;
    __syncthreads();
  }
  int excl = sarr[t] - mine;
  int grow = (b << RB_LOG) + t;
  if (grow < N) row_ptr[grow] = e0 + excl;           // fused row_ptr construction
  if (b == 0 && t == 0) row_ptr[N] = nnz;
  __syncthreads();
  rcnt[t] = e0 + excl;       // absolute running fill counter
  __syncthreads();
  for (int j = e0 + t; j < e1; j += 512) {
    int2 ed = binned[j];
    int rL = (unsigned)ed.x >> COL_BITS;
    int pos = atomicAdd(&rcnt[rL], 1);
    sedge[pos] = make_int2(ed.x & COL_MASK, ed.y);
  }
}

// ---------------- row-parallel SpMM: 16 lanes per row, float4 per lane ----------------
// FUSED: layer 0 gathers directly from user/item (concat fused away).
// int4 edge loads: 2 edges per load, 2 independent gathers in flight.
template <bool FUSED>
__global__ void __launch_bounds__(THREADS)
k_spmm(const int* __restrict__ row_ptr, const int2* __restrict__ sedge,
       const float* __restrict__ prev,
       const float* __restrict__ user, const float* __restrict__ item, int nu,
       float* __restrict__ next, float* __restrict__ out, int n, int layer) {
  int gid = blockIdx.x * blockDim.x + threadIdx.x;
  int row = gid >> 4, l = gid & 15;
  if (row >= n) return;
  int s = row_ptr[row], e = row_ptr[row + 1];
  float ax = 0.f, ay = 0.f, az = 0.f, aw = 0.f;
  float bx = 0.f, by = 0.f, bz = 0.f, bw = 0.f;
  auto gather = [&](int c) -> float4 {
    const float* p;
    if (FUSED) p = (c < nu) ? user + (size_t)c * 64 : item + (size_t)(c - nu) * 64;
    else       p = prev + (size_t)c * 64;
    return *reinterpret_cast<const float4*>(p + l * 4);
  };
  int j = s;
  if (j < e && (j & 1)) {
    int2 ed = sedge[j];
    float v = __int_as_float(ed.y);
    float4 x = gather(ed.x);
    ax = fmaf(v, x.x, ax); ay = fmaf(v, x.y, ay);
    az = fmaf(v, x.z, az); aw = fmaf(v, x.w, aw);
    ++j;
  }
  for (; j + 2 <= e; j += 2) {
    int4 ee = *reinterpret_cast<const int4*>(sedge + j);  // 16B aligned (j even)
    float v0 = __int_as_float(ee.y);
    float v1 = __int_as_float(ee.w);
    float4 x0 = gather(ee.x);
    float4 x1 = gather(ee.z);
    ax = fmaf(v0, x0.x, ax); ay = fmaf(v0, x0.y, ay);
    az = fmaf(v0, x0.z, az); aw = fmaf(v0, x0.w, aw);
    bx = fmaf(v1, x1.x, bx); by = fmaf(v1, x1.y, by);
    bz = fmaf(v1, x1.z, bz); bw = fmaf(v1, x1.w, bw);
  }
  if (j < e) {
    int2 ed = sedge[j];
    float v = __int_as_float(ed.y);
    float4 x = gather(ed.x);
    ax = fmaf(v, x.x, ax); ay = fmaf(v, x.y, ay);
    az = fmaf(v, x.z, az); aw = fmaf(v, x.w, aw);
  }
  ax += bx; ay += by; az += bz; aw += bw;
  *reinterpret_cast<float4*>(next + (size_t)row * 64 + l * 4) = make_float4(ax, ay, az, aw);
  float4* op = reinterpret_cast<float4*>(out + (size_t)row * 64 + l * 4);
  if (layer == 0) {
    *op = make_float4(ax, ay, az, aw);
  } else if (layer == 1) {
    float4 o = *op; o.x += ax; o.y += ay; o.z += az; o.w += aw; *op = o;
  } else {
    const float inv3 = 1.0f / 3.0f;
    float4 o = *op;
    o.x = (o.x + ax) * inv3; o.y = (o.y + ay) * inv3;
    o.z = (o.z + az) * inv3; o.w = (o.w + aw) * inv3;
    *op = o;
  }
}

// ---------------- fallback path: edge-parallel atomics (if ws too small for CSR) ----------------
__global__ void k_edge_atomic(const int* __restrict__ rows, const int* __restrict__ cols,
                              const float* __restrict__ vals, long long tot16,
                              const float* __restrict__ prev, float* __restrict__ nxt) {
  long long stride = (long long)gridDim.x * blockDim.x;
  for (long long i = (long long)blockIdx.x * blockDim.x + threadIdx.x; i < tot16; i += stride) {
    int e = (int)(i >> 4), l = (int)(i & 15);
    int r = rows[e], c = cols[e];
    float v = vals[e];
    const float4 x = *reinterpret_cast<const float4*>(prev + (size_t)c * 64 + l * 4);
    float* d = nxt + (size_t)r * 64 + l * 4;
    atomicAdd(d + 0, v * x.x); atomicAdd(d + 1, v * x.y);
    atomicAdd(d + 2, v * x.z); atomicAdd(d + 3, v * x.w);
  }
}

__global__ void k_accum(const float4* __restrict__ nxt, float4* __restrict__ out, int tot, int layer) {
  int stride = gridDim.x * blockDim.x;
  for (int i = blockIdx.x * blockDim.x + threadIdx.x; i < tot; i += stride) {
    float4 a = nxt[i];
    if (layer == 0) {
      out[i] = a;
    } else if (layer == 1) {
      float4 o = out[i]; o.x += a.x; o.y += a.y; o.z += a.z; o.w += a.w; out[i] = o;
    } else {
      const float inv3 = 1.0f / 3.0f;
      float4 o = out[i];
      o.x = (o.x + a.x) * inv3; o.y = (o.y + a.y) * inv3;
      o.z = (o.z + a.z) * inv3; o.w = (o.w + a.w) * inv3;
      out[i] = o;
    }
  }
}

extern "C" void kernel_launch(void* const* d_in, const int* in_sizes, int n_in,
                              void* d_out, int out_size, void* d_ws, size_t ws_size,
                              hipStream_t stream) {
  const float* user = (const float*)d_in[0];
  const float* item = (const float*)d_in[1];
  const float* vals = (const float*)d_in[2];
  const int*   rows = (const int*)d_in[3];
  const int*   cols = (const int*)d_in[4];
  const int D = 64;
  const int num_users = in_sizes[0] / D;
  const int num_items = in_sizes[1] / D;
  const int nnz = in_sizes[2];
  const int N = num_users + num_items;
  float* out = (float*)d_out;

  // ---- carve workspace ----
  size_t off = 0;
  auto carve = [&](size_t bytes) -> char* {
    char* p = (char*)d_ws + off;
    off = (off + bytes + 255) & ~(size_t)255;
    return p;
  };
  size_t egoBytes = (size_t)N * D * sizeof(float);
  float* egoA = (float*)carve(egoBytes);
  float* egoB = (float*)carve(egoBytes);
  int nB = (N + RB - 1) >> RB_LOG;
  int*  row_ptr     = (int*)carve((size_t)(N + 1) * 4);
  int*  bucket_cnt  = (int*)carve((size_t)nB * 4);
  int*  bucket_base = (int*)carve((size_t)(nB + 1) * 4);
  int*  bucket_fill = (int*)carve((size_t)nB * 4);
  int2* sedge       = (int2*)carve((size_t)nnz * 8);
  int2* binned      = (int2*)egoB;  // aliased: egoB first written at layer 1, after Pass B
  bool use_csr = (off <= ws_size) && (nB <= MAX_NB) &&
                 ((size_t)nnz * 8 <= egoBytes) && (N < (1 << COL_BITS));

  if (use_csr) {
    hipMemsetAsync(bucket_cnt, 0, (size_t)nB * 4, stream);
    k_bhist<<<BH_BLOCKS, THREADS, 0, stream>>>(rows, nnz, nB, bucket_cnt);
    k_scan_buckets<<<1, 1024, 0, stream>>>(bucket_cnt, nB, bucket_base, bucket_fill);
    int nchunks = (nnz + CH - 1) / CH;
    k_bin<<<nchunks, THREADS, 0, stream>>>(rows, cols, vals, nnz, nB, bucket_fill, binned);
    k_bucket_sedge<<<nB, 512, 0, stream>>>(binned, bucket_base, row_ptr, N, nnz, sedge);

    int spmm_blocks = (N * 16 + THREADS - 1) / THREADS;
    // layer 0: fused concat (gathers straight from user/item), writes egoA
    k_spmm<true><<<spmm_blocks, THREADS, 0, stream>>>(row_ptr, sedge, nullptr,
                                                      user, item, num_users,
                                                      egoA, out, N, 0);
    // layer 1: egoA -> egoB (clobbers binned, which is dead now)
    k_spmm<false><<<spmm_blocks, THREADS, 0, stream>>>(row_ptr, sedge, egoA,
                                                       user, item, num_users,
                                                       egoB, out, N, 1);
    // layer 2: egoB -> egoA
    k_spmm<false><<<spmm_blocks, THREADS, 0, stream>>>(row_ptr, sedge, egoB,
                                                       user, item, num_users,
                                                       egoA, out, N, 2);
  } else {
    // atomic fallback: needs only the two ego buffers
    int totF4 = N * (D / 4);
    int uf4   = num_users * (D / 4);
    k_concat<<<GS_BLOCKS, THREADS, 0, stream>>>((const float4*)user, (const float4*)item,
                                                (float4*)egoA, uf4, totF4);
    float* prev = egoA;
    float* next = egoB;
    long long tot16 = (long long)nnz * 16;
    for (int layer = 0; layer < 3; ++layer) {
      hipMemsetAsync(next, 0, egoBytes, stream);
      k_edge_atomic<<<GS_BLOCKS * 2, THREADS, 0, stream>>>(rows, cols, vals, tot16, prev, next);
      k_accum<<<GS_BLOCKS, THREADS, 0, stream>>>((const float4*)next, (float4*)out, totF4, layer);
      float* t = prev; prev = next; next = t;
    }
  }
}

// Round 5
// 596.672 us; speedup vs baseline: 1.8732x; 1.4096x over previous
//
#include <hip/hip_runtime.h>

constexpr int GS_BLOCKS = 2048;
constexpr int THREADS   = 256;
constexpr int RB_LOG    = 9;               // rows per bucket = 512
constexpr int RB        = 1 << RB_LOG;
constexpr int CH        = 8192;            // edges per Pass-A chunk
constexpr int COL_BITS  = 19;              // N < 2^19
constexpr int COL_MASK  = (1 << COL_BITS) - 1;
constexpr int MAX_NB    = 1024;            // max buckets supported by LDS arrays
constexpr int BH_BLOCKS = 1024;

typedef _Float16 h4 __attribute__((ext_vector_type(4)));

// ---------------- ego0 = concat(user, item) as fp16 ----------------
__global__ void k_tofp16(const float4* __restrict__ u, const float4* __restrict__ it,
                         h4* __restrict__ dst, int uf4, int tot) {
  int stride = gridDim.x * blockDim.x;
  for (int i = blockIdx.x * blockDim.x + threadIdx.x; i < tot; i += stride) {
    float4 v = (i < uf4) ? u[i] : it[i - uf4];
    h4 o;
    o[0] = (_Float16)v.x; o[1] = (_Float16)v.y;
    o[2] = (_Float16)v.z; o[3] = (_Float16)v.w;
    dst[i] = o;
  }
}

// ---------------- ego0 = concat(user, item) f32 (fallback path only) ----------------
__global__ void k_concat(const float4* __restrict__ u, const float4* __restrict__ it,
                         float4* __restrict__ dst, int uf4, int tot) {
  int stride = gridDim.x * blockDim.x;
  for (int i = blockIdx.x * blockDim.x + threadIdx.x; i < tot; i += stride)
    dst[i] = (i < uf4) ? u[i] : it[i - uf4];
}

// ---------------- bucket-only histogram: LDS counters, merged once per block ----------------
__global__ void k_bhist(const int* __restrict__ rows, int nnz, int nB,
                        int* __restrict__ bucket_cnt) {
  __shared__ int lcnt[MAX_NB];
  int t = threadIdx.x;
  for (int j = t; j < nB; j += THREADS) lcnt[j] = 0;
  __syncthreads();
  int stride = gridDim.x * blockDim.x;
  for (int i = blockIdx.x * blockDim.x + t; i < nnz; i += stride)
    atomicAdd(&lcnt[__builtin_nontemporal_load(rows + i) >> RB_LOG], 1);
  __syncthreads();
  for (int j = t; j < nB; j += THREADS)
    if (lcnt[j]) atomicAdd(&bucket_cnt[j], lcnt[j]);
}

// ---------------- exclusive scan of bucket counts (nB <= 1024), 1 block ----------------
__global__ void __launch_bounds__(1024)
k_scan_buckets(const int* __restrict__ bucket_cnt, int nB,
               int* __restrict__ bucket_base, int* __restrict__ bucket_fill) {
  __shared__ int a[1024];
  int t = threadIdx.x;
  int mine = (t < nB) ? bucket_cnt[t] : 0;
  a[t] = mine; __syncthreads();
  for (int off = 1; off < 1024; off <<= 1) {
    int x = (t >= off) ? a[t - off] : 0;
    __syncthreads();
    a[t] += x;
    __syncthreads();
  }
  int excl = a[t] - mine;
  if (t < nB) { bucket_base[t] = excl; bucket_fill[t] = excl; }
  if (t == 1023) bucket_base[nB] = a[1023];  // total = nnz
}

// ---------------- Pass A: chunk-local LDS binning into row-buckets ----------------
__global__ void __launch_bounds__(THREADS)
k_bin(const int* __restrict__ rows, const int* __restrict__ cols,
      const float* __restrict__ vals, int nnz, int nB,
      int* __restrict__ bucket_fill, int2* __restrict__ binned) {
  __shared__ int bcnt[MAX_NB];      // counts, then reused as global-base per bucket
  __shared__ int boff[MAX_NB + 1];  // chunk-local exclusive offsets
  __shared__ int bfill[MAX_NB];     // chunk-local running rank
  __shared__ int sarr[THREADS];
  int t = threadIdx.x;
  int c0 = blockIdx.x * CH;
  for (int j = t; j < nB; j += THREADS) { bcnt[j] = 0; bfill[j] = 0; }
  __syncthreads();
  // phase 1: count
  for (int k = 0; k < CH / THREADS; k++) {
    int e = c0 + t + k * THREADS;
    if (e < nnz) atomicAdd(&bcnt[__builtin_nontemporal_load(rows + e) >> RB_LOG], 1);
  }
  __syncthreads();
  // phase 2: exclusive scan of bcnt -> boff (4 blocked slots per thread)
  int i0 = t * 4;
  int v0 = (i0 + 0 < nB) ? bcnt[i0 + 0] : 0;
  int v1 = (i0 + 1 < nB) ? bcnt[i0 + 1] : 0;
  int v2 = (i0 + 2 < nB) ? bcnt[i0 + 2] : 0;
  int v3 = (i0 + 3 < nB) ? bcnt[i0 + 3] : 0;
  int s = v0 + v1 + v2 + v3;
  sarr[t] = s; __syncthreads();
  for (int off = 1; off < THREADS; off <<= 1) {
    int x = (t >= off) ? sarr[t - off] : 0;
    __syncthreads();
    sarr[t] += x;
    __syncthreads();
  }
  int excl = sarr[t] - s;
  if (i0 + 0 < nB) boff[i0 + 0] = excl;
  if (i0 + 1 < nB) boff[i0 + 1] = excl + v0;
  if (i0 + 2 < nB) boff[i0 + 2] = excl + v0 + v1;
  if (i0 + 3 < nB) boff[i0 + 3] = excl + v0 + v1 + v2;
  if (t == THREADS - 1) boff[nB] = sarr[t];
  __syncthreads();
  // phase 3: reserve global ranges (bcnt becomes global base)
  for (int b = t; b < nB; b += THREADS) {
    int c = boff[b + 1] - boff[b];
    if (c > 0) bcnt[b] = atomicAdd(&bucket_fill[b], c);
  }
  __syncthreads();
  // phase 4: scatter into bucket-major bursts
  for (int k = 0; k < CH / THREADS; k++) {
    int e = c0 + t + k * THREADS;
    if (e < nnz) {
      int r = rows[e];
      int b = r >> RB_LOG;
      int rank = atomicAdd(&bfill[b], 1);
      int packed = ((r & (RB - 1)) << COL_BITS) | cols[e];
      binned[bcnt[b] + rank] = make_int2(packed, __float_as_int(vals[e]));
    }
  }
}

// ---------------- Pass B: per-bucket LDS counting sort -> sedge + row_ptr ----------------
__global__ void __launch_bounds__(512)
k_bucket_sedge(const int2* __restrict__ binned, const int* __restrict__ bucket_base,
               int* __restrict__ row_ptr, int N, int nnz, int2* __restrict__ sedge) {
  __shared__ int rcnt[RB];
  __shared__ int sarr[512];
  int b = blockIdx.x, t = threadIdx.x;
  int e0 = bucket_base[b], e1 = bucket_base[b + 1];
  rcnt[t] = 0;
  __syncthreads();
  for (int j = e0 + t; j < e1; j += 512)
    atomicAdd(&rcnt[(unsigned)binned[j].x >> COL_BITS], 1);
  __syncthreads();
  int mine = rcnt[t];
  sarr[t] = mine; __syncthreads();
  for (int off = 1; off < 512; off <<= 1) {
    int x = (t >= off) ? sarr[t - off] : 0;
    __syncthreads();
    sarr[t] += x;
    __syncthreads();
  }
  int excl = sarr[t] - mine;
  int grow = (b << RB_LOG) + t;
  if (grow < N) row_ptr[grow] = e0 + excl;           // fused row_ptr construction
  if (b == 0 && t == 0) row_ptr[N] = nnz;
  __syncthreads();
  rcnt[t] = e0 + excl;       // absolute running fill counter
  __syncthreads();
  for (int j = e0 + t; j < e1; j += 512) {
    int2 ed = binned[j];
    int rL = (unsigned)ed.x >> COL_BITS;
    int pos = atomicAdd(&rcnt[rL], 1);
    sedge[pos] = make_int2(ed.x & COL_MASK, ed.y);
  }
}

// ---------------- row-parallel SpMM over fp16 table: 16 lanes/row, h4 per lane ----------------
// Gathers fp16 (128B/row), FMAs in f32, writes fp16 next (skipped at layer 2),
// f32 running-mean accumulator in out (fed pre-rounding).
__global__ void __launch_bounds__(THREADS)
k_spmm_h(const int* __restrict__ row_ptr, const int2* __restrict__ sedge,
         const _Float16* __restrict__ prev, _Float16* __restrict__ next,
         float* __restrict__ out, int n, int layer) {
  int gid = blockIdx.x * blockDim.x + threadIdx.x;
  int row = gid >> 4, l = gid & 15;
  if (row >= n) return;
  int s = row_ptr[row], e = row_ptr[row + 1];
  float ax = 0.f, ay = 0.f, az = 0.f, aw = 0.f;
  float bx = 0.f, by = 0.f, bz = 0.f, bw = 0.f;
  auto gat = [&](int c) -> h4 {
    return *reinterpret_cast<const h4*>(prev + (size_t)c * 64 + l * 4);
  };
  int j = s;
  if (j < e && (j & 1)) {  // align to even for int4 edge loads
    int2 ed = sedge[j];
    float v = __int_as_float(ed.y);
    h4 g = gat(ed.x);
    ax = fmaf(v, (float)g[0], ax); ay = fmaf(v, (float)g[1], ay);
    az = fmaf(v, (float)g[2], az); aw = fmaf(v, (float)g[3], aw);
    ++j;
  }
  for (; j + 4 <= e; j += 4) {
    int4 e01 = *reinterpret_cast<const int4*>(sedge + j);
    int4 e23 = *reinterpret_cast<const int4*>(sedge + j + 2);
    h4 g0 = gat(e01.x), g1 = gat(e01.z), g2 = gat(e23.x), g3 = gat(e23.z);
    float v0 = __int_as_float(e01.y), v1 = __int_as_float(e01.w);
    float v2 = __int_as_float(e23.y), v3 = __int_as_float(e23.w);
    ax = fmaf(v0, (float)g0[0], ax); ay = fmaf(v0, (float)g0[1], ay);
    az = fmaf(v0, (float)g0[2], az); aw = fmaf(v0, (float)g0[3], aw);
    bx = fmaf(v1, (float)g1[0], bx); by = fmaf(v1, (float)g1[1], by);
    bz = fmaf(v1, (float)g1[2], bz); bw = fmaf(v1, (float)g1[3], bw);
    ax = fmaf(v2, (float)g2[0], ax); ay = fmaf(v2, (float)g2[1], ay);
    az = fmaf(v2, (float)g2[2], az); aw = fmaf(v2, (float)g2[3], aw);
    bx = fmaf(v3, (float)g3[0], bx); by = fmaf(v3, (float)g3[1], by);
    bz = fmaf(v3, (float)g3[2], bz); bw = fmaf(v3, (float)g3[3], bw);
  }
  if (j + 2 <= e) {
    int4 e01 = *reinterpret_cast<const int4*>(sedge + j);
    h4 g0 = gat(e01.x), g1 = gat(e01.z);
    float v0 = __int_as_float(e01.y), v1 = __int_as_float(e01.w);
    ax = fmaf(v0, (float)g0[0], ax); ay = fmaf(v0, (float)g0[1], ay);
    az = fmaf(v0, (float)g0[2], az); aw = fmaf(v0, (float)g0[3], aw);
    bx = fmaf(v1, (float)g1[0], bx); by = fmaf(v1, (float)g1[1], by);
    bz = fmaf(v1, (float)g1[2], bz); bw = fmaf(v1, (float)g1[3], bw);
    j += 2;
  }
  if (j < e) {
    int2 ed = sedge[j];
    float v = __int_as_float(ed.y);
    h4 g = gat(ed.x);
    ax = fmaf(v, (float)g[0], ax); ay = fmaf(v, (float)g[1], ay);
    az = fmaf(v, (float)g[2], az); aw = fmaf(v, (float)g[3], aw);
  }
  ax += bx; ay += by; az += bz; aw += bw;
  if (layer != 2) {  // layer-2 next is dead
    h4 o;
    o[0] = (_Float16)ax; o[1] = (_Float16)ay;
    o[2] = (_Float16)az; o[3] = (_Float16)aw;
    *reinterpret_cast<h4*>(next + (size_t)row * 64 + l * 4) = o;
  }
  float4* op = reinterpret_cast<float4*>(out + (size_t)row * 64 + l * 4);
  if (layer == 0) {
    *op = make_float4(ax, ay, az, aw);
  } else if (layer == 1) {
    float4 o = *op; o.x += ax; o.y += ay; o.z += az; o.w += aw; *op = o;
  } else {
    const float inv3 = 1.0f / 3.0f;
    float4 o = *op;
    o.x = (o.x + ax) * inv3; o.y = (o.y + ay) * inv3;
    o.z = (o.z + az) * inv3; o.w = (o.w + aw) * inv3;
    *op = o;
  }
}

// ---------------- fallback path: edge-parallel atomics (if ws too small for CSR) ----------------
__global__ void k_edge_atomic(const int* __restrict__ rows, const int* __restrict__ cols,
                              const float* __restrict__ vals, long long tot16,
                              const float* __restrict__ prev, float* __restrict__ nxt) {
  long long stride = (long long)gridDim.x * blockDim.x;
  for (long long i = (long long)blockIdx.x * blockDim.x + threadIdx.x; i < tot16; i += stride) {
    int e = (int)(i >> 4), l = (int)(i & 15);
    int r = rows[e], c = cols[e];
    float v = vals[e];
    const float4 x = *reinterpret_cast<const float4*>(prev + (size_t)c * 64 + l * 4);
    float* d = nxt + (size_t)r * 64 + l * 4;
    atomicAdd(d + 0, v * x.x); atomicAdd(d + 1, v * x.y);
    atomicAdd(d + 2, v * x.z); atomicAdd(d + 3, v * x.w);
  }
}

__global__ void k_accum(const float4* __restrict__ nxt, float4* __restrict__ out, int tot, int layer) {
  int stride = gridDim.x * blockDim.x;
  for (int i = blockIdx.x * blockDim.x + threadIdx.x; i < tot; i += stride) {
    float4 a = nxt[i];
    if (layer == 0) {
      out[i] = a;
    } else if (layer == 1) {
      float4 o = out[i]; o.x += a.x; o.y += a.y; o.z += a.z; o.w += a.w; out[i] = o;
    } else {
      const float inv3 = 1.0f / 3.0f;
      float4 o = out[i];
      o.x = (o.x + a.x) * inv3; o.y = (o.y + a.y) * inv3;
      o.z = (o.z + a.z) * inv3; o.w = (o.w + a.w) * inv3;
      out[i] = o;
    }
  }
}

extern "C" void kernel_launch(void* const* d_in, const int* in_sizes, int n_in,
                              void* d_out, int out_size, void* d_ws, size_t ws_size,
                              hipStream_t stream) {
  const float* user = (const float*)d_in[0];
  const float* item = (const float*)d_in[1];
  const float* vals = (const float*)d_in[2];
  const int*   rows = (const int*)d_in[3];
  const int*   cols = (const int*)d_in[4];
  const int D = 64;
  const int num_users = in_sizes[0] / D;
  const int num_items = in_sizes[1] / D;
  const int nnz = in_sizes[2];
  const int N = num_users + num_items;
  float* out = (float*)d_out;

  // ---- carve workspace ----
  size_t off = 0;
  auto carve = [&](size_t bytes) -> char* {
    char* p = (char*)d_ws + off;
    off = (off + bytes + 255) & ~(size_t)255;
    return p;
  };
  size_t egoBytesF = (size_t)N * D * sizeof(float);   // 76.8 MB
  size_t egoBytesH = (size_t)N * D * sizeof(_Float16);// 38.4 MB
  char* region1 = carve(egoBytesF);   // fp16 path: egoA_h + egoB_h ; fallback: egoA f32
  char* region2 = carve(egoBytesF);   // fp16 path: binned          ; fallback: egoB f32
  int nB = (N + RB - 1) >> RB_LOG;
  int*  row_ptr     = (int*)carve((size_t)(N + 1) * 4);
  int*  bucket_cnt  = (int*)carve((size_t)nB * 4);
  int*  bucket_base = (int*)carve((size_t)(nB + 1) * 4);
  int*  bucket_fill = (int*)carve((size_t)nB * 4);
  int2* sedge       = (int2*)carve((size_t)nnz * 8);

  _Float16* egoA_h = (_Float16*)region1;
  _Float16* egoB_h = (_Float16*)(region1 + egoBytesH);
  int2*     binned = (int2*)region2;
  bool use_csr = (off <= ws_size) && (nB <= MAX_NB) &&
                 ((size_t)nnz * 8 <= egoBytesF) && (N < (1 << COL_BITS)) &&
                 (2 * egoBytesH <= egoBytesF);

  if (use_csr) {
    hipMemsetAsync(bucket_cnt, 0, (size_t)nB * 4, stream);
    k_bhist<<<BH_BLOCKS, THREADS, 0, stream>>>(rows, nnz, nB, bucket_cnt);
    k_scan_buckets<<<1, 1024, 0, stream>>>(bucket_cnt, nB, bucket_base, bucket_fill);
    int nchunks = (nnz + CH - 1) / CH;
    k_bin<<<nchunks, THREADS, 0, stream>>>(rows, cols, vals, nnz, nB, bucket_fill, binned);
    k_bucket_sedge<<<nB, 512, 0, stream>>>(binned, bucket_base, row_ptr, N, nnz, sedge);
    // ego0 as fp16 concat (overlaps CSR build in no way, but independent of binned)
    int totF4 = N * (D / 4);
    int uf4   = num_users * (D / 4);
    k_tofp16<<<GS_BLOCKS, THREADS, 0, stream>>>((const float4*)user, (const float4*)item,
                                                (h4*)egoA_h, uf4, totF4);

    int spmm_blocks = (N * 16 + THREADS - 1) / THREADS;
    // layer 0: ego0(A) -> e1(B)
    k_spmm_h<<<spmm_blocks, THREADS, 0, stream>>>(row_ptr, sedge, egoA_h, egoB_h, out, N, 0);
    // layer 1: e1(B) -> e2(A)
    k_spmm_h<<<spmm_blocks, THREADS, 0, stream>>>(row_ptr, sedge, egoB_h, egoA_h, out, N, 1);
    // layer 2: e2(A) -> (next dead, skipped)
    k_spmm_h<<<spmm_blocks, THREADS, 0, stream>>>(row_ptr, sedge, egoA_h, egoB_h, out, N, 2);
  } else {
    // atomic fallback: f32 ego ping-pong in region1/region2
    float* egoA = (float*)region1;
    float* egoB = (float*)region2;
    int totF4 = N * (D / 4);
    int uf4   = num_users * (D / 4);
    k_concat<<<GS_BLOCKS, THREADS, 0, stream>>>((const float4*)user, (const float4*)item,
                                                (float4*)egoA, uf4, totF4);
    float* prev = egoA;
    float* next = egoB;
    long long tot16 = (long long)nnz * 16;
    for (int layer = 0; layer < 3; ++layer) {
      hipMemsetAsync(next, 0, egoBytesF, stream);
      k_edge_atomic<<<GS_BLOCKS * 2, THREADS, 0, stream>>>(rows, cols, vals, tot16, prev, next);
      k_accum<<<GS_BLOCKS, THREADS, 0, stream>>>((const float4*)next, (float4*)out, totF4, layer);
      float* t = prev; prev = next; next = t;
    }
  }
}

// Round 7
// 583.179 us; speedup vs baseline: 1.9165x; 1.0231x over previous
//
#include <hip/hip_runtime.h>

constexpr int GS_BLOCKS = 2048;
constexpr int THREADS   = 256;
constexpr int RB_LOG    = 9;               // rows per bucket = 512
constexpr int RB        = 1 << RB_LOG;
constexpr int CH        = 2048;            // edges per Pass-A chunk (small => high occupancy)
constexpr int COL_BITS  = 19;              // N < 2^19
constexpr int COL_MASK  = (1 << COL_BITS) - 1;
constexpr int MAX_NB    = 1024;            // max buckets supported by LDS arrays
constexpr int BH_BLOCKS = 1024;

typedef _Float16 h4 __attribute__((ext_vector_type(4)));
typedef int      i4 __attribute__((ext_vector_type(4)));

// ---------------- ego0 = concat(user, item) as fp16 ----------------
__global__ void k_tofp16(const float4* __restrict__ u, const float4* __restrict__ it,
                         h4* __restrict__ dst, int uf4, int tot) {
  int stride = gridDim.x * blockDim.x;
  for (int i = blockIdx.x * blockDim.x + threadIdx.x; i < tot; i += stride) {
    float4 v = (i < uf4) ? u[i] : it[i - uf4];
    h4 o;
    o[0] = (_Float16)v.x; o[1] = (_Float16)v.y;
    o[2] = (_Float16)v.z; o[3] = (_Float16)v.w;
    dst[i] = o;
  }
}

// ---------------- ego0 = concat(user, item) f32 (fallback path only) ----------------
__global__ void k_concat(const float4* __restrict__ u, const float4* __restrict__ it,
                         float4* __restrict__ dst, int uf4, int tot) {
  int stride = gridDim.x * blockDim.x;
  for (int i = blockIdx.x * blockDim.x + threadIdx.x; i < tot; i += stride)
    dst[i] = (i < uf4) ? u[i] : it[i - uf4];
}

// ---------------- bucket-only histogram: LDS counters, i4 vector loads ----------------
__global__ void k_bhist(const int* __restrict__ rows, int nnz, int nB,
                        int* __restrict__ bucket_cnt) {
  __shared__ int lcnt[MAX_NB];
  int t = threadIdx.x;
  for (int j = t; j < nB; j += THREADS) lcnt[j] = 0;
  __syncthreads();
  int gid = blockIdx.x * blockDim.x + t;
  int stride = gridDim.x * blockDim.x;
  int nnz4 = nnz >> 2;
  const i4* r4 = (const i4*)rows;
  for (int i = gid; i < nnz4; i += stride) {
    i4 v = __builtin_nontemporal_load(r4 + i);
    atomicAdd(&lcnt[v[0] >> RB_LOG], 1);
    atomicAdd(&lcnt[v[1] >> RB_LOG], 1);
    atomicAdd(&lcnt[v[2] >> RB_LOG], 1);
    atomicAdd(&lcnt[v[3] >> RB_LOG], 1);
  }
  for (int i = (nnz4 << 2) + gid; i < nnz; i += stride)
    atomicAdd(&lcnt[__builtin_nontemporal_load(rows + i) >> RB_LOG], 1);
  __syncthreads();
  for (int j = t; j < nB; j += THREADS)
    if (lcnt[j]) atomicAdd(&bucket_cnt[j], lcnt[j]);
}

// ---------------- exclusive scan of bucket counts (nB <= 1024), 1 block ----------------
__global__ void __launch_bounds__(1024)
k_scan_buckets(const int* __restrict__ bucket_cnt, int nB,
               int* __restrict__ bucket_base, int* __restrict__ bucket_fill) {
  __shared__ int a[1024];
  int t = threadIdx.x;
  int mine = (t < nB) ? bucket_cnt[t] : 0;
  a[t] = mine; __syncthreads();
  for (int off = 1; off < 1024; off <<= 1) {
    int x = (t >= off) ? a[t - off] : 0;
    __syncthreads();
    a[t] += x;
    __syncthreads();
  }
  int excl = a[t] - mine;
  if (t < nB) { bucket_base[t] = excl; bucket_fill[t] = excl; }
  if (t == 1023) bucket_base[nB] = a[1023];  // total = nnz
}

// ---------------- Pass A: chunk-local LDS binning into row-buckets ----------------
// CH=2048 -> ~2442 blocks (high occupancy); rows stashed in LDS (read once).
__global__ void __launch_bounds__(THREADS)
k_bin(const int* __restrict__ rows, const int* __restrict__ cols,
      const float* __restrict__ vals, int nnz, int nB,
      int* __restrict__ bucket_fill, int2* __restrict__ binned) {
  __shared__ int bcnt[MAX_NB];      // counts, then reused as global-base per bucket
  __shared__ int boff[MAX_NB + 1];  // chunk-local exclusive offsets
  __shared__ int bfill[MAX_NB];     // chunk-local running rank
  __shared__ int sarr[THREADS];
  __shared__ int rstash[CH];        // rows cached from phase 1 for phase 4
  int t = threadIdx.x;
  int c0 = blockIdx.x * CH;
  for (int j = t; j < nB; j += THREADS) { bcnt[j] = 0; bfill[j] = 0; }
  __syncthreads();
  // phase 1: count (+ stash rows)
#pragma unroll
  for (int k = 0; k < CH / THREADS; k++) {
    int e = c0 + t + k * THREADS;
    if (e < nnz) {
      int r = __builtin_nontemporal_load(rows + e);
      rstash[t + k * THREADS] = r;
      atomicAdd(&bcnt[r >> RB_LOG], 1);
    }
  }
  __syncthreads();
  // phase 2: exclusive scan of bcnt -> boff (4 blocked slots per thread)
  int i0 = t * 4;
  int v0 = (i0 + 0 < nB) ? bcnt[i0 + 0] : 0;
  int v1 = (i0 + 1 < nB) ? bcnt[i0 + 1] : 0;
  int v2 = (i0 + 2 < nB) ? bcnt[i0 + 2] : 0;
  int v3 = (i0 + 3 < nB) ? bcnt[i0 + 3] : 0;
  int s = v0 + v1 + v2 + v3;
  sarr[t] = s; __syncthreads();
  for (int off = 1; off < THREADS; off <<= 1) {
    int x = (t >= off) ? sarr[t - off] : 0;
    __syncthreads();
    sarr[t] += x;
    __syncthreads();
  }
  int excl = sarr[t] - s;
  if (i0 + 0 < nB) boff[i0 + 0] = excl;
  if (i0 + 1 < nB) boff[i0 + 1] = excl + v0;
  if (i0 + 2 < nB) boff[i0 + 2] = excl + v0 + v1;
  if (i0 + 3 < nB) boff[i0 + 3] = excl + v0 + v1 + v2;
  if (t == THREADS - 1) boff[nB] = sarr[t];
  __syncthreads();
  // phase 3: reserve global ranges (bcnt becomes global base)
  for (int b = t; b < nB; b += THREADS) {
    int c = boff[b + 1] - boff[b];
    if (c > 0) bcnt[b] = atomicAdd(&bucket_fill[b], c);
  }
  __syncthreads();
  // phase 4: scatter into bucket-major bursts (rows from LDS stash)
#pragma unroll
  for (int k = 0; k < CH / THREADS; k++) {
    int e = c0 + t + k * THREADS;
    if (e < nnz) {
      int r = rstash[t + k * THREADS];
      int b = r >> RB_LOG;
      int rank = atomicAdd(&bfill[b], 1);
      int packed = ((r & (RB - 1)) << COL_BITS) | __builtin_nontemporal_load(cols + e);
      binned[bcnt[b] + rank] =
          make_int2(packed, __float_as_int(__builtin_nontemporal_load(vals + e)));
    }
  }
}

// ---------------- Pass B: per-bucket LDS counting sort -> sedge + row_ptr ----------------
// 1024 threads per block for latency hiding; scan uses first 512 threads.
__global__ void __launch_bounds__(1024)
k_bucket_sedge(const int2* __restrict__ binned, const int* __restrict__ bucket_base,
               int* __restrict__ row_ptr, int N, int nnz, int2* __restrict__ sedge) {
  __shared__ int rcnt[RB];
  __shared__ int sarr[RB];
  int b = blockIdx.x, t = threadIdx.x;
  int e0 = bucket_base[b], e1 = bucket_base[b + 1];
  if (t < RB) rcnt[t] = 0;
  __syncthreads();
  for (int j = e0 + t; j < e1; j += 1024)
    atomicAdd(&rcnt[(unsigned)binned[j].x >> COL_BITS], 1);
  __syncthreads();
  int mine = (t < RB) ? rcnt[t] : 0;
  if (t < RB) sarr[t] = mine;
  __syncthreads();
  for (int off = 1; off < RB; off <<= 1) {
    int x = 0;
    if (t < RB && t >= off) x = sarr[t - off];
    __syncthreads();
    if (t < RB) sarr[t] += x;
    __syncthreads();
  }
  if (t < RB) {
    int excl = sarr[t] - mine;
    int grow = (b << RB_LOG) + t;
    if (grow < N) row_ptr[grow] = e0 + excl;   // fused row_ptr construction
    rcnt[t] = e0 + excl;                       // absolute running fill counter
  }
  if (b == 0 && t == 0) row_ptr[N] = nnz;
  __syncthreads();
  for (int j = e0 + t; j < e1; j += 1024) {
    int2 ed = binned[j];
    int rL = (unsigned)ed.x >> COL_BITS;
    int pos = atomicAdd(&rcnt[rL], 1);
    sedge[pos] = make_int2(ed.x & COL_MASK, ed.y);
  }
}

// ---------------- row-parallel SpMM over fp16 table: 16 lanes/row, h4 per lane ----------------
__global__ void __launch_bounds__(THREADS)
k_spmm_h(const int* __restrict__ row_ptr, const int2* __restrict__ sedge,
         const _Float16* __restrict__ prev, _Float16* __restrict__ next,
         float* __restrict__ out, int n, int layer) {
  int gid = blockIdx.x * blockDim.x + threadIdx.x;
  int row = gid >> 4, l = gid & 15;
  if (row >= n) return;
  int s = row_ptr[row], e = row_ptr[row + 1];
  float ax = 0.f, ay = 0.f, az = 0.f, aw = 0.f;
  float bx = 0.f, by = 0.f, bz = 0.f, bw = 0.f;
  auto gat = [&](int c) -> h4 {
    return *reinterpret_cast<const h4*>(prev + (size_t)c * 64 + l * 4);
  };
  int j = s;
  if (j < e && (j & 1)) {  // align to even for int4 edge loads
    int2 ed = sedge[j];
    float v = __int_as_float(ed.y);
    h4 g = gat(ed.x);
    ax = fmaf(v, (float)g[0], ax); ay = fmaf(v, (float)g[1], ay);
    az = fmaf(v, (float)g[2], az); aw = fmaf(v, (float)g[3], aw);
    ++j;
  }
  for (; j + 4 <= e; j += 4) {
    int4 e01 = *reinterpret_cast<const int4*>(sedge + j);
    int4 e23 = *reinterpret_cast<const int4*>(sedge + j + 2);
    h4 g0 = gat(e01.x), g1 = gat(e01.z), g2 = gat(e23.x), g3 = gat(e23.z);
    float v0 = __int_as_float(e01.y), v1 = __int_as_float(e01.w);
    float v2 = __int_as_float(e23.y), v3 = __int_as_float(e23.w);
    ax = fmaf(v0, (float)g0[0], ax); ay = fmaf(v0, (float)g0[1], ay);
    az = fmaf(v0, (float)g0[2], az); aw = fmaf(v0, (float)g0[3], aw);
    bx = fmaf(v1, (float)g1[0], bx); by = fmaf(v1, (float)g1[1], by);
    bz = fmaf(v1, (float)g1[2], bz); bw = fmaf(v1, (float)g1[3], bw);
    ax = fmaf(v2, (float)g2[0], ax); ay = fmaf(v2, (float)g2[1], ay);
    az = fmaf(v2, (float)g2[2], az); aw = fmaf(v2, (float)g2[3], aw);
    bx = fmaf(v3, (float)g3[0], bx); by = fmaf(v3, (float)g3[1], by);
    bz = fmaf(v3, (float)g3[2], bz); bw = fmaf(v3, (float)g3[3], bw);
  }
  if (j + 2 <= e) {
    int4 e01 = *reinterpret_cast<const int4*>(sedge + j);
    h4 g0 = gat(e01.x), g1 = gat(e01.z);
    float v0 = __int_as_float(e01.y), v1 = __int_as_float(e01.w);
    ax = fmaf(v0, (float)g0[0], ax); ay = fmaf(v0, (float)g0[1], ay);
    az = fmaf(v0, (float)g0[2], az); aw = fmaf(v0, (float)g0[3], aw);
    bx = fmaf(v1, (float)g1[0], bx); by = fmaf(v1, (float)g1[1], by);
    bz = fmaf(v1, (float)g1[2], bz); bw = fmaf(v1, (float)g1[3], bw);
    j += 2;
  }
  if (j < e) {
    int2 ed = sedge[j];
    float v = __int_as_float(ed.y);
    h4 g = gat(ed.x);
    ax = fmaf(v, (float)g[0], ax); ay = fmaf(v, (float)g[1], ay);
    az = fmaf(v, (float)g[2], az); aw = fmaf(v, (float)g[3], aw);
  }
  ax += bx; ay += by; az += bz; aw += bw;
  if (layer != 2) {  // layer-2 next is dead
    h4 o;
    o[0] = (_Float16)ax; o[1] = (_Float16)ay;
    o[2] = (_Float16)az; o[3] = (_Float16)aw;
    *reinterpret_cast<h4*>(next + (size_t)row * 64 + l * 4) = o;
  }
  float4* op = reinterpret_cast<float4*>(out + (size_t)row * 64 + l * 4);
  if (layer == 0) {
    *op = make_float4(ax, ay, az, aw);
  } else if (layer == 1) {
    float4 o = *op; o.x += ax; o.y += ay; o.z += az; o.w += aw; *op = o;
  } else {
    const float inv3 = 1.0f / 3.0f;
    float4 o = *op;
    o.x = (o.x + ax) * inv3; o.y = (o.y + ay) * inv3;
    o.z = (o.z + az) * inv3; o.w = (o.w + aw) * inv3;
    *op = o;
  }
}

// ---------------- fallback path: edge-parallel atomics (if ws too small for CSR) ----------------
__global__ void k_edge_atomic(const int* __restrict__ rows, const int* __restrict__ cols,
                              const float* __restrict__ vals, long long tot16,
                              const float* __restrict__ prev, float* __restrict__ nxt) {
  long long stride = (long long)gridDim.x * blockDim.x;
  for (long long i = (long long)blockIdx.x * blockDim.x + threadIdx.x; i < tot16; i += stride) {
    int e = (int)(i >> 4), l = (int)(i & 15);
    int r = rows[e], c = cols[e];
    float v = vals[e];
    const float4 x = *reinterpret_cast<const float4*>(prev + (size_t)c * 64 + l * 4);
    float* d = nxt + (size_t)r * 64 + l * 4;
    atomicAdd(d + 0, v * x.x); atomicAdd(d + 1, v * x.y);
    atomicAdd(d + 2, v * x.z); atomicAdd(d + 3, v * x.w);
  }
}

__global__ void k_accum(const float4* __restrict__ nxt, float4* __restrict__ out, int tot, int layer) {
  int stride = gridDim.x * blockDim.x;
  for (int i = blockIdx.x * blockDim.x + threadIdx.x; i < tot; i += stride) {
    float4 a = nxt[i];
    if (layer == 0) {
      out[i] = a;
    } else if (layer == 1) {
      float4 o = out[i]; o.x += a.x; o.y += a.y; o.z += a.z; o.w += a.w; out[i] = o;
    } else {
      const float inv3 = 1.0f / 3.0f;
      float4 o = out[i];
      o.x = (o.x + a.x) * inv3; o.y = (o.y + a.y) * inv3;
      o.z = (o.z + a.z) * inv3; o.w = (o.w + a.w) * inv3;
      out[i] = o;
    }
  }
}

extern "C" void kernel_launch(void* const* d_in, const int* in_sizes, int n_in,
                              void* d_out, int out_size, void* d_ws, size_t ws_size,
                              hipStream_t stream) {
  const float* user = (const float*)d_in[0];
  const float* item = (const float*)d_in[1];
  const float* vals = (const float*)d_in[2];
  const int*   rows = (const int*)d_in[3];
  const int*   cols = (const int*)d_in[4];
  const int D = 64;
  const int num_users = in_sizes[0] / D;
  const int num_items = in_sizes[1] / D;
  const int nnz = in_sizes[2];
  const int N = num_users + num_items;
  float* out = (float*)d_out;

  // ---- carve workspace ----
  size_t off = 0;
  auto carve = [&](size_t bytes) -> char* {
    char* p = (char*)d_ws + off;
    off = (off + bytes + 255) & ~(size_t)255;
    return p;
  };
  size_t egoBytesF = (size_t)N * D * sizeof(float);   // 76.8 MB
  size_t egoBytesH = (size_t)N * D * sizeof(_Float16);// 38.4 MB
  char* region1 = carve(egoBytesF);   // fp16 path: egoA_h + egoB_h ; fallback: egoA f32
  char* region2 = carve(egoBytesF);   // fp16 path: binned          ; fallback: egoB f32
  int nB = (N + RB - 1) >> RB_LOG;
  int*  row_ptr     = (int*)carve((size_t)(N + 1) * 4);
  int*  bucket_cnt  = (int*)carve((size_t)nB * 4);
  int*  bucket_base = (int*)carve((size_t)(nB + 1) * 4);
  int*  bucket_fill = (int*)carve((size_t)nB * 4);
  int2* sedge       = (int2*)carve((size_t)nnz * 8);

  _Float16* egoA_h = (_Float16*)region1;
  _Float16* egoB_h = (_Float16*)(region1 + egoBytesH);
  int2*     binned = (int2*)region2;
  bool use_csr = (off <= ws_size) && (nB <= MAX_NB) &&
                 ((size_t)nnz * 8 <= egoBytesF) && (N < (1 << COL_BITS)) &&
                 (2 * egoBytesH <= egoBytesF);

  if (use_csr) {
    hipMemsetAsync(bucket_cnt, 0, (size_t)nB * 4, stream);
    k_bhist<<<BH_BLOCKS, THREADS, 0, stream>>>(rows, nnz, nB, bucket_cnt);
    k_scan_buckets<<<1, 1024, 0, stream>>>(bucket_cnt, nB, bucket_base, bucket_fill);
    int nchunks = (nnz + CH - 1) / CH;
    k_bin<<<nchunks, THREADS, 0, stream>>>(rows, cols, vals, nnz, nB, bucket_fill, binned);
    k_bucket_sedge<<<nB, 1024, 0, stream>>>(binned, bucket_base, row_ptr, N, nnz, sedge);
    int totF4 = N * (D / 4);
    int uf4   = num_users * (D / 4);
    k_tofp16<<<GS_BLOCKS, THREADS, 0, stream>>>((const float4*)user, (const float4*)item,
                                                (h4*)egoA_h, uf4, totF4);

    int spmm_blocks = (N * 16 + THREADS - 1) / THREADS;
    // layer 0: ego0(A) -> e1(B)
    k_spmm_h<<<spmm_blocks, THREADS, 0, stream>>>(row_ptr, sedge, egoA_h, egoB_h, out, N, 0);
    // layer 1: e1(B) -> e2(A)
    k_spmm_h<<<spmm_blocks, THREADS, 0, stream>>>(row_ptr, sedge, egoB_h, egoA_h, out, N, 1);
    // layer 2: e2(A) -> (next dead, skipped)
    k_spmm_h<<<spmm_blocks, THREADS, 0, stream>>>(row_ptr, sedge, egoA_h, egoB_h, out, N, 2);
  } else {
    // atomic fallback: f32 ego ping-pong in region1/region2
    float* egoA = (float*)region1;
    float* egoB = (float*)region2;
    int totF4 = N * (D / 4);
    int uf4   = num_users * (D / 4);
    k_concat<<<GS_BLOCKS, THREADS, 0, stream>>>((const float4*)user, (const float4*)item,
                                                (float4*)egoA, uf4, totF4);
    float* prev = egoA;
    float* next = egoB;
    long long tot16 = (long long)nnz * 16;
    for (int layer = 0; layer < 3; ++layer) {
      hipMemsetAsync(next, 0, egoBytesF, stream);
      k_edge_atomic<<<GS_BLOCKS * 2, THREADS, 0, stream>>>(rows, cols, vals, tot16, prev, next);
      k_accum<<<GS_BLOCKS, THREADS, 0, stream>>>((const float4*)next, (float4*)out, totF4, layer);
      float* t = prev; prev = next; next = t;
    }
  }
}

// Round 8
// 535.040 us; speedup vs baseline: 2.0889x; 1.0900x over previous
//
#include <hip/hip_runtime.h>

constexpr int GS_BLOCKS = 2048;
constexpr int THREADS   = 256;
constexpr int RB_LOG    = 9;               // rows per bucket = 512
constexpr int RB        = 1 << RB_LOG;
constexpr int CH        = 8192;            // edges per Pass-A chunk (14-edge bursts)
constexpr int BT_BIN    = 1024;            // k_bin block size (16 waves -> occupancy)
constexpr int COL_BITS  = 19;              // N < 2^19
constexpr int COL_MASK  = (1 << COL_BITS) - 1;
constexpr int MAX_NB    = 1024;            // max buckets supported by LDS arrays
constexpr int BH_BLOCKS = 1024;

typedef _Float16 h4 __attribute__((ext_vector_type(4)));
typedef int      i4 __attribute__((ext_vector_type(4)));

// ---------------- ego0 = concat(user, item) as fp16 ----------------
__global__ void k_tofp16(const float4* __restrict__ u, const float4* __restrict__ it,
                         h4* __restrict__ dst, int uf4, int tot) {
  int stride = gridDim.x * blockDim.x;
  for (int i = blockIdx.x * blockDim.x + threadIdx.x; i < tot; i += stride) {
    float4 v = (i < uf4) ? u[i] : it[i - uf4];
    h4 o;
    o[0] = (_Float16)v.x; o[1] = (_Float16)v.y;
    o[2] = (_Float16)v.z; o[3] = (_Float16)v.w;
    dst[i] = o;
  }
}

// ---------------- ego0 = concat(user, item) f32 (fallback path only) ----------------
__global__ void k_concat(const float4* __restrict__ u, const float4* __restrict__ it,
                         float4* __restrict__ dst, int uf4, int tot) {
  int stride = gridDim.x * blockDim.x;
  for (int i = blockIdx.x * blockDim.x + threadIdx.x; i < tot; i += stride)
    dst[i] = (i < uf4) ? u[i] : it[i - uf4];
}

// ---------------- bucket-only histogram: LDS counters, i4 vector loads ----------------
__global__ void k_bhist(const int* __restrict__ rows, int nnz, int nB,
                        int* __restrict__ bucket_cnt) {
  __shared__ int lcnt[MAX_NB];
  int t = threadIdx.x;
  for (int j = t; j < nB; j += THREADS) lcnt[j] = 0;
  __syncthreads();
  int gid = blockIdx.x * blockDim.x + t;
  int stride = gridDim.x * blockDim.x;
  int nnz4 = nnz >> 2;
  const i4* r4 = (const i4*)rows;
  for (int i = gid; i < nnz4; i += stride) {
    i4 v = __builtin_nontemporal_load(r4 + i);
    atomicAdd(&lcnt[v[0] >> RB_LOG], 1);
    atomicAdd(&lcnt[v[1] >> RB_LOG], 1);
    atomicAdd(&lcnt[v[2] >> RB_LOG], 1);
    atomicAdd(&lcnt[v[3] >> RB_LOG], 1);
  }
  for (int i = (nnz4 << 2) + gid; i < nnz; i += stride)
    atomicAdd(&lcnt[__builtin_nontemporal_load(rows + i) >> RB_LOG], 1);
  __syncthreads();
  for (int j = t; j < nB; j += THREADS)
    if (lcnt[j]) atomicAdd(&bucket_cnt[j], lcnt[j]);
}

// ---------------- exclusive scan of bucket counts (nB <= 1024), 1 block ----------------
__global__ void __launch_bounds__(1024)
k_scan_buckets(const int* __restrict__ bucket_cnt, int nB,
               int* __restrict__ bucket_base, int* __restrict__ bucket_fill) {
  __shared__ int a[1024];
  int t = threadIdx.x;
  int mine = (t < nB) ? bucket_cnt[t] : 0;
  a[t] = mine; __syncthreads();
  for (int off = 1; off < 1024; off <<= 1) {
    int x = (t >= off) ? a[t - off] : 0;
    __syncthreads();
    a[t] += x;
    __syncthreads();
  }
  int excl = a[t] - mine;
  if (t < nB) { bucket_base[t] = excl; bucket_fill[t] = excl; }
  if (t == 1023) bucket_base[nB] = a[1023];  // total = nnz
}

// ---------------- Pass A: chunk-local LDS binning into row-buckets ----------------
// CH=8192 (14-edge bursts) + 1024-thread blocks (16 waves => full occupancy).
// No chunk-local scan needed: global base (reserve atomic) + LDS rank suffices.
__global__ void __launch_bounds__(BT_BIN)
k_bin(const int* __restrict__ rows, const int* __restrict__ cols,
      const float* __restrict__ vals, int nnz, int nB,
      int* __restrict__ bucket_fill, int2* __restrict__ binned) {
  __shared__ int bcnt[MAX_NB];      // counts, then reused as global-base per bucket
  __shared__ int bfill[MAX_NB];     // chunk-local running rank
  __shared__ int rstash[CH];        // rows cached from phase 1 for phase 3
  int t = threadIdx.x;
  int c0 = blockIdx.x * CH;
  if (t < nB) { bcnt[t] = 0; bfill[t] = 0; }
  __syncthreads();
  // phase 1: count (+ stash rows)
#pragma unroll
  for (int k = 0; k < CH / BT_BIN; k++) {
    int e = c0 + t + k * BT_BIN;
    if (e < nnz) {
      int r = __builtin_nontemporal_load(rows + e);
      rstash[t + k * BT_BIN] = r;
      atomicAdd(&bcnt[r >> RB_LOG], 1);
    }
  }
  __syncthreads();
  // phase 2: reserve global range per bucket (bcnt becomes global base)
  if (t < nB) {
    int c = bcnt[t];
    bcnt[t] = (c > 0) ? atomicAdd(&bucket_fill[t], c) : 0;
  }
  __syncthreads();
  // phase 3: scatter into bucket-major bursts (rows from LDS stash)
#pragma unroll
  for (int k = 0; k < CH / BT_BIN; k++) {
    int e = c0 + t + k * BT_BIN;
    if (e < nnz) {
      int r = rstash[t + k * BT_BIN];
      int b = r >> RB_LOG;
      int rank = atomicAdd(&bfill[b], 1);
      int packed = ((r & (RB - 1)) << COL_BITS) | __builtin_nontemporal_load(cols + e);
      binned[bcnt[b] + rank] =
          make_int2(packed, __float_as_int(__builtin_nontemporal_load(vals + e)));
    }
  }
}

// ---------------- Pass B: per-bucket LDS counting sort -> sedge + row_ptr ----------------
__global__ void __launch_bounds__(1024)
k_bucket_sedge(const int2* __restrict__ binned, const int* __restrict__ bucket_base,
               int* __restrict__ row_ptr, int N, int nnz, int2* __restrict__ sedge) {
  __shared__ int rcnt[RB];
  __shared__ int sarr[RB];
  int b = blockIdx.x, t = threadIdx.x;
  int e0 = bucket_base[b], e1 = bucket_base[b + 1];
  if (t < RB) rcnt[t] = 0;
  __syncthreads();
  for (int j = e0 + t; j < e1; j += 1024)
    atomicAdd(&rcnt[(unsigned)binned[j].x >> COL_BITS], 1);
  __syncthreads();
  int mine = (t < RB) ? rcnt[t] : 0;
  if (t < RB) sarr[t] = mine;
  __syncthreads();
  for (int off = 1; off < RB; off <<= 1) {
    int x = 0;
    if (t < RB && t >= off) x = sarr[t - off];
    __syncthreads();
    if (t < RB) sarr[t] += x;
    __syncthreads();
  }
  if (t < RB) {
    int excl = sarr[t] - mine;
    int grow = (b << RB_LOG) + t;
    if (grow < N) row_ptr[grow] = e0 + excl;   // fused row_ptr construction
    rcnt[t] = e0 + excl;                       // absolute running fill counter
  }
  if (b == 0 && t == 0) row_ptr[N] = nnz;
  __syncthreads();
  for (int j = e0 + t; j < e1; j += 1024) {
    int2 ed = binned[j];
    int rL = (unsigned)ed.x >> COL_BITS;
    int pos = atomicAdd(&rcnt[rL], 1);
    sedge[pos] = make_int2(ed.x & COL_MASK, ed.y);
  }
}

// ---------------- row-parallel SpMM over fp16 table: 16 lanes/row, h4 per lane ----------------
__global__ void __launch_bounds__(THREADS)
k_spmm_h(const int* __restrict__ row_ptr, const int2* __restrict__ sedge,
         const _Float16* __restrict__ prev, _Float16* __restrict__ next,
         float* __restrict__ out, int n, int layer) {
  int gid = blockIdx.x * blockDim.x + threadIdx.x;
  int row = gid >> 4, l = gid & 15;
  if (row >= n) return;
  int s = row_ptr[row], e = row_ptr[row + 1];
  float ax = 0.f, ay = 0.f, az = 0.f, aw = 0.f;
  float bx = 0.f, by = 0.f, bz = 0.f, bw = 0.f;
  auto gat = [&](int c) -> h4 {
    return *reinterpret_cast<const h4*>(prev + (size_t)c * 64 + l * 4);
  };
  int j = s;
  if (j < e && (j & 1)) {  // align to even for int4 edge loads
    int2 ed = sedge[j];
    float v = __int_as_float(ed.y);
    h4 g = gat(ed.x);
    ax = fmaf(v, (float)g[0], ax); ay = fmaf(v, (float)g[1], ay);
    az = fmaf(v, (float)g[2], az); aw = fmaf(v, (float)g[3], aw);
    ++j;
  }
  for (; j + 4 <= e; j += 4) {
    int4 e01 = *reinterpret_cast<const int4*>(sedge + j);
    int4 e23 = *reinterpret_cast<const int4*>(sedge + j + 2);
    h4 g0 = gat(e01.x), g1 = gat(e01.z), g2 = gat(e23.x), g3 = gat(e23.z);
    float v0 = __int_as_float(e01.y), v1 = __int_as_float(e01.w);
    float v2 = __int_as_float(e23.y), v3 = __int_as_float(e23.w);
    ax = fmaf(v0, (float)g0[0], ax); ay = fmaf(v0, (float)g0[1], ay);
    az = fmaf(v0, (float)g0[2], az); aw = fmaf(v0, (float)g0[3], aw);
    bx = fmaf(v1, (float)g1[0], bx); by = fmaf(v1, (float)g1[1], by);
    bz = fmaf(v1, (float)g1[2], bz); bw = fmaf(v1, (float)g1[3], bw);
    ax = fmaf(v2, (float)g2[0], ax); ay = fmaf(v2, (float)g2[1], ay);
    az = fmaf(v2, (float)g2[2], az); aw = fmaf(v2, (float)g2[3], aw);
    bx = fmaf(v3, (float)g3[0], bx); by = fmaf(v3, (float)g3[1], by);
    bz = fmaf(v3, (float)g3[2], bz); bw = fmaf(v3, (float)g3[3], bw);
  }
  if (j + 2 <= e) {
    int4 e01 = *reinterpret_cast<const int4*>(sedge + j);
    h4 g0 = gat(e01.x), g1 = gat(e01.z);
    float v0 = __int_as_float(e01.y), v1 = __int_as_float(e01.w);
    ax = fmaf(v0, (float)g0[0], ax); ay = fmaf(v0, (float)g0[1], ay);
    az = fmaf(v0, (float)g0[2], az); aw = fmaf(v0, (float)g0[3], aw);
    bx = fmaf(v1, (float)g1[0], bx); by = fmaf(v1, (float)g1[1], by);
    bz = fmaf(v1, (float)g1[2], bz); bw = fmaf(v1, (float)g1[3], bw);
    j += 2;
  }
  if (j < e) {
    int2 ed = sedge[j];
    float v = __int_as_float(ed.y);
    h4 g = gat(ed.x);
    ax = fmaf(v, (float)g[0], ax); ay = fmaf(v, (float)g[1], ay);
    az = fmaf(v, (float)g[2], az); aw = fmaf(v, (float)g[3], aw);
  }
  ax += bx; ay += by; az += bz; aw += bw;
  if (layer != 2) {  // layer-2 next is dead
    h4 o;
    o[0] = (_Float16)ax; o[1] = (_Float16)ay;
    o[2] = (_Float16)az; o[3] = (_Float16)aw;
    *reinterpret_cast<h4*>(next + (size_t)row * 64 + l * 4) = o;
  }
  float4* op = reinterpret_cast<float4*>(out + (size_t)row * 64 + l * 4);
  if (layer == 0) {
    *op = make_float4(ax, ay, az, aw);
  } else if (layer == 1) {
    float4 o = *op; o.x += ax; o.y += ay; o.z += az; o.w += aw; *op = o;
  } else {
    const float inv3 = 1.0f / 3.0f;
    float4 o = *op;
    o.x = (o.x + ax) * inv3; o.y = (o.y + ay) * inv3;
    o.z = (o.z + az) * inv3; o.w = (o.w + aw) * inv3;
    *op = o;
  }
}

// ---------------- fallback path: edge-parallel atomics (if ws too small for CSR) ----------------
__global__ void k_edge_atomic(const int* __restrict__ rows, const int* __restrict__ cols,
                              const float* __restrict__ vals, long long tot16,
                              const float* __restrict__ prev, float* __restrict__ nxt) {
  long long stride = (long long)gridDim.x * blockDim.x;
  for (long long i = (long long)blockIdx.x * blockDim.x + threadIdx.x; i < tot16; i += stride) {
    int e = (int)(i >> 4), l = (int)(i & 15);
    int r = rows[e], c = cols[e];
    float v = vals[e];
    const float4 x = *reinterpret_cast<const float4*>(prev + (size_t)c * 64 + l * 4);
    float* d = nxt + (size_t)r * 64 + l * 4;
    atomicAdd(d + 0, v * x.x); atomicAdd(d + 1, v * x.y);
    atomicAdd(d + 2, v * x.z); atomicAdd(d + 3, v * x.w);
  }
}

__global__ void k_accum(const float4* __restrict__ nxt, float4* __restrict__ out, int tot, int layer) {
  int stride = gridDim.x * blockDim.x;
  for (int i = blockIdx.x * blockDim.x + threadIdx.x; i < tot; i += stride) {
    float4 a = nxt[i];
    if (layer == 0) {
      out[i] = a;
    } else if (layer == 1) {
      float4 o = out[i]; o.x += a.x; o.y += a.y; o.z += a.z; o.w += a.w; out[i] = o;
    } else {
      const float inv3 = 1.0f / 3.0f;
      float4 o = out[i];
      o.x = (o.x + a.x) * inv3; o.y = (o.y + a.y) * inv3;
      o.z = (o.z + a.z) * inv3; o.w = (o.w + a.w) * inv3;
      out[i] = o;
    }
  }
}

extern "C" void kernel_launch(void* const* d_in, const int* in_sizes, int n_in,
                              void* d_out, int out_size, void* d_ws, size_t ws_size,
                              hipStream_t stream) {
  const float* user = (const float*)d_in[0];
  const float* item = (const float*)d_in[1];
  const float* vals = (const float*)d_in[2];
  const int*   rows = (const int*)d_in[3];
  const int*   cols = (const int*)d_in[4];
  const int D = 64;
  const int num_users = in_sizes[0] / D;
  const int num_items = in_sizes[1] / D;
  const int nnz = in_sizes[2];
  const int N = num_users + num_items;
  float* out = (float*)d_out;

  // ---- carve workspace ----
  size_t off = 0;
  auto carve = [&](size_t bytes) -> char* {
    char* p = (char*)d_ws + off;
    off = (off + bytes + 255) & ~(size_t)255;
    return p;
  };
  size_t egoBytesF = (size_t)N * D * sizeof(float);   // 76.8 MB
  size_t egoBytesH = (size_t)N * D * sizeof(_Float16);// 38.4 MB
  char* region1 = carve(egoBytesF);   // fp16 path: egoA_h + egoB_h ; fallback: egoA f32
  char* region2 = carve(egoBytesF);   // fp16 path: binned          ; fallback: egoB f32
  int nB = (N + RB - 1) >> RB_LOG;
  int*  row_ptr     = (int*)carve((size_t)(N + 1) * 4);
  int*  bucket_cnt  = (int*)carve((size_t)nB * 4);
  int*  bucket_base = (int*)carve((size_t)(nB + 1) * 4);
  int*  bucket_fill = (int*)carve((size_t)nB * 4);
  int2* sedge       = (int2*)carve((size_t)nnz * 8);

  _Float16* egoA_h = (_Float16*)region1;
  _Float16* egoB_h = (_Float16*)(region1 + egoBytesH);
  int2*     binned = (int2*)region2;
  bool use_csr = (off <= ws_size) && (nB <= MAX_NB) &&
                 ((size_t)nnz * 8 <= egoBytesF) && (N < (1 << COL_BITS)) &&
                 (2 * egoBytesH <= egoBytesF);

  if (use_csr) {
    hipMemsetAsync(bucket_cnt, 0, (size_t)nB * 4, stream);
    k_bhist<<<BH_BLOCKS, THREADS, 0, stream>>>(rows, nnz, nB, bucket_cnt);
    k_scan_buckets<<<1, 1024, 0, stream>>>(bucket_cnt, nB, bucket_base, bucket_fill);
    int nchunks = (nnz + CH - 1) / CH;
    k_bin<<<nchunks, BT_BIN, 0, stream>>>(rows, cols, vals, nnz, nB, bucket_fill, binned);
    k_bucket_sedge<<<nB, 1024, 0, stream>>>(binned, bucket_base, row_ptr, N, nnz, sedge);
    int totF4 = N * (D / 4);
    int uf4   = num_users * (D / 4);
    k_tofp16<<<GS_BLOCKS, THREADS, 0, stream>>>((const float4*)user, (const float4*)item,
                                                (h4*)egoA_h, uf4, totF4);

    int spmm_blocks = (N * 16 + THREADS - 1) / THREADS;
    // layer 0: ego0(A) -> e1(B)
    k_spmm_h<<<spmm_blocks, THREADS, 0, stream>>>(row_ptr, sedge, egoA_h, egoB_h, out, N, 0);
    // layer 1: e1(B) -> e2(A)
    k_spmm_h<<<spmm_blocks, THREADS, 0, stream>>>(row_ptr, sedge, egoB_h, egoA_h, out, N, 1);
    // layer 2: e2(A) -> (next dead, skipped)
    k_spmm_h<<<spmm_blocks, THREADS, 0, stream>>>(row_ptr, sedge, egoA_h, egoB_h, out, N, 2);
  } else {
    // atomic fallback: f32 ego ping-pong in region1/region2
    float* egoA = (float*)region1;
    float* egoB = (float*)region2;
    int totF4 = N * (D / 4);
    int uf4   = num_users * (D / 4);
    k_concat<<<GS_BLOCKS, THREADS, 0, stream>>>((const float4*)user, (const float4*)item,
                                                (float4*)egoA, uf4, totF4);
    float* prev = egoA;
    float* next = egoB;
    long long tot16 = (long long)nnz * 16;
    for (int layer = 0; layer < 3; ++layer) {
      hipMemsetAsync(next, 0, egoBytesF, stream);
      k_edge_atomic<<<GS_BLOCKS * 2, THREADS, 0, stream>>>(rows, cols, vals, tot16, prev, next);
      k_accum<<<GS_BLOCKS, THREADS, 0, stream>>>((const float4*)next, (float4*)out, totF4, layer);
      float* t = prev; prev = next; next = t;
    }
  }
}

// Round 9
// 527.097 us; speedup vs baseline: 2.1204x; 1.0151x over previous
//
#include <hip/hip_runtime.h>

constexpr int GS_BLOCKS = 2048;
constexpr int THREADS   = 256;
constexpr int RB_LOG    = 9;               // rows per bucket = 512
constexpr int RB        = 1 << RB_LOG;
constexpr int CH        = 8192;            // edges per Pass-A chunk (14-edge bursts)
constexpr int BT_BIN    = 1024;            // k_bin block size (16 waves -> occupancy)
constexpr int COL_BITS  = 19;              // N < 2^19
constexpr int COL_MASK  = (1 << COL_BITS) - 1;
constexpr int MAX_NB    = 1024;            // max buckets supported by LDS arrays
constexpr int BH_BLOCKS = 1024;

typedef _Float16 h4 __attribute__((ext_vector_type(4)));
typedef _Float16 h8 __attribute__((ext_vector_type(8)));
typedef float    f8 __attribute__((ext_vector_type(8)));
typedef int      i4 __attribute__((ext_vector_type(4)));

// ---------------- ego0 = concat(user, item) as fp16 ----------------
__global__ void k_tofp16(const float4* __restrict__ u, const float4* __restrict__ it,
                         h4* __restrict__ dst, int uf4, int tot) {
  int stride = gridDim.x * blockDim.x;
  for (int i = blockIdx.x * blockDim.x + threadIdx.x; i < tot; i += stride) {
    float4 v = (i < uf4) ? u[i] : it[i - uf4];
    h4 o;
    o[0] = (_Float16)v.x; o[1] = (_Float16)v.y;
    o[2] = (_Float16)v.z; o[3] = (_Float16)v.w;
    dst[i] = o;
  }
}

// ---------------- ego0 = concat(user, item) f32 (fallback path only) ----------------
__global__ void k_concat(const float4* __restrict__ u, const float4* __restrict__ it,
                         float4* __restrict__ dst, int uf4, int tot) {
  int stride = gridDim.x * blockDim.x;
  for (int i = blockIdx.x * blockDim.x + threadIdx.x; i < tot; i += stride)
    dst[i] = (i < uf4) ? u[i] : it[i - uf4];
}

// ---------------- bucket-only histogram: LDS counters, i4 vector loads ----------------
__global__ void k_bhist(const int* __restrict__ rows, int nnz, int nB,
                        int* __restrict__ bucket_cnt) {
  __shared__ int lcnt[MAX_NB];
  int t = threadIdx.x;
  for (int j = t; j < nB; j += THREADS) lcnt[j] = 0;
  __syncthreads();
  int gid = blockIdx.x * blockDim.x + t;
  int stride = gridDim.x * blockDim.x;
  int nnz4 = nnz >> 2;
  const i4* r4 = (const i4*)rows;
  for (int i = gid; i < nnz4; i += stride) {
    i4 v = __builtin_nontemporal_load(r4 + i);
    atomicAdd(&lcnt[v[0] >> RB_LOG], 1);
    atomicAdd(&lcnt[v[1] >> RB_LOG], 1);
    atomicAdd(&lcnt[v[2] >> RB_LOG], 1);
    atomicAdd(&lcnt[v[3] >> RB_LOG], 1);
  }
  for (int i = (nnz4 << 2) + gid; i < nnz; i += stride)
    atomicAdd(&lcnt[__builtin_nontemporal_load(rows + i) >> RB_LOG], 1);
  __syncthreads();
  for (int j = t; j < nB; j += THREADS)
    if (lcnt[j]) atomicAdd(&bucket_cnt[j], lcnt[j]);
}

// ---------------- exclusive scan of bucket counts (nB <= 1024), 1 block ----------------
__global__ void __launch_bounds__(1024)
k_scan_buckets(const int* __restrict__ bucket_cnt, int nB,
               int* __restrict__ bucket_base, int* __restrict__ bucket_fill) {
  __shared__ int a[1024];
  int t = threadIdx.x;
  int mine = (t < nB) ? bucket_cnt[t] : 0;
  a[t] = mine; __syncthreads();
  for (int off = 1; off < 1024; off <<= 1) {
    int x = (t >= off) ? a[t - off] : 0;
    __syncthreads();
    a[t] += x;
    __syncthreads();
  }
  int excl = a[t] - mine;
  if (t < nB) { bucket_base[t] = excl; bucket_fill[t] = excl; }
  if (t == 1023) bucket_base[nB] = a[1023];  // total = nnz
}

// ---------------- Pass A: chunk-local LDS binning into row-buckets ----------------
__global__ void __launch_bounds__(BT_BIN)
k_bin(const int* __restrict__ rows, const int* __restrict__ cols,
      const float* __restrict__ vals, int nnz, int nB,
      int* __restrict__ bucket_fill, int2* __restrict__ binned) {
  __shared__ int bcnt[MAX_NB];      // counts, then reused as global-base per bucket
  __shared__ int bfill[MAX_NB];     // chunk-local running rank
  __shared__ int rstash[CH];        // rows cached from phase 1 for phase 3
  int t = threadIdx.x;
  int c0 = blockIdx.x * CH;
  if (t < nB) { bcnt[t] = 0; bfill[t] = 0; }
  __syncthreads();
  // phase 1: count (+ stash rows)
#pragma unroll
  for (int k = 0; k < CH / BT_BIN; k++) {
    int e = c0 + t + k * BT_BIN;
    if (e < nnz) {
      int r = __builtin_nontemporal_load(rows + e);
      rstash[t + k * BT_BIN] = r;
      atomicAdd(&bcnt[r >> RB_LOG], 1);
    }
  }
  __syncthreads();
  // phase 2: reserve global range per bucket (bcnt becomes global base)
  if (t < nB) {
    int c = bcnt[t];
    bcnt[t] = (c > 0) ? atomicAdd(&bucket_fill[t], c) : 0;
  }
  __syncthreads();
  // phase 3: scatter into bucket-major bursts (rows from LDS stash)
#pragma unroll
  for (int k = 0; k < CH / BT_BIN; k++) {
    int e = c0 + t + k * BT_BIN;
    if (e < nnz) {
      int r = rstash[t + k * BT_BIN];
      int b = r >> RB_LOG;
      int rank = atomicAdd(&bfill[b], 1);
      int packed = ((r & (RB - 1)) << COL_BITS) | __builtin_nontemporal_load(cols + e);
      binned[bcnt[b] + rank] =
          make_int2(packed, __float_as_int(__builtin_nontemporal_load(vals + e)));
    }
  }
}

// ---------------- Pass B: per-bucket LDS counting sort -> sedge + row_ptr ----------------
__global__ void __launch_bounds__(1024)
k_bucket_sedge(const int2* __restrict__ binned, const int* __restrict__ bucket_base,
               int* __restrict__ row_ptr, int N, int nnz, int2* __restrict__ sedge) {
  __shared__ int rcnt[RB];
  __shared__ int sarr[RB];
  int b = blockIdx.x, t = threadIdx.x;
  int e0 = bucket_base[b], e1 = bucket_base[b + 1];
  if (t < RB) rcnt[t] = 0;
  __syncthreads();
  for (int j = e0 + t; j < e1; j += 1024)
    atomicAdd(&rcnt[(unsigned)binned[j].x >> COL_BITS], 1);
  __syncthreads();
  int mine = (t < RB) ? rcnt[t] : 0;
  if (t < RB) sarr[t] = mine;
  __syncthreads();
  for (int off = 1; off < RB; off <<= 1) {
    int x = 0;
    if (t < RB && t >= off) x = sarr[t - off];
    __syncthreads();
    if (t < RB) sarr[t] += x;
    __syncthreads();
  }
  if (t < RB) {
    int excl = sarr[t] - mine;
    int grow = (b << RB_LOG) + t;
    if (grow < N) row_ptr[grow] = e0 + excl;   // fused row_ptr construction
    rcnt[t] = e0 + excl;                       // absolute running fill counter
  }
  if (b == 0 && t == 0) row_ptr[N] = nnz;
  __syncthreads();
  for (int j = e0 + t; j < e1; j += 1024) {
    int2 ed = binned[j];
    int rL = (unsigned)ed.x >> COL_BITS;
    int pos = atomicAdd(&rcnt[rL], 1);
    sedge[pos] = make_int2(ed.x & COL_MASK, ed.y);
  }
}

// ---------------- row-parallel SpMM over fp16 table: 8 lanes/row, h8 (16B) per lane ----------------
// Writes ONLY fp16 next (out accumulation deferred to k_merge).
__global__ void __launch_bounds__(THREADS)
k_spmm_h8(const int* __restrict__ row_ptr, const int2* __restrict__ sedge,
          const _Float16* __restrict__ prev, _Float16* __restrict__ next, int n) {
  int gid = blockIdx.x * blockDim.x + threadIdx.x;
  int row = gid >> 3, l = gid & 7;
  if (row >= n) return;
  int s = row_ptr[row], e = row_ptr[row + 1];
  f8 acc = 0.f, accb = 0.f;
  auto gat = [&](int c) -> f8 {
    h8 g = *reinterpret_cast<const h8*>(prev + (size_t)c * 64 + l * 8);
    return __builtin_convertvector(g, f8);
  };
  int j = s;
  if (j < e && (j & 1)) {  // align to even for int4 edge loads
    int2 ed = sedge[j];
    acc += __int_as_float(ed.y) * gat(ed.x);
    ++j;
  }
  for (; j + 4 <= e; j += 4) {
    int4 e01 = *reinterpret_cast<const int4*>(sedge + j);
    int4 e23 = *reinterpret_cast<const int4*>(sedge + j + 2);
    f8 g0 = gat(e01.x), g1 = gat(e01.z), g2 = gat(e23.x), g3 = gat(e23.z);
    acc  += __int_as_float(e01.y) * g0;
    accb += __int_as_float(e01.w) * g1;
    acc  += __int_as_float(e23.y) * g2;
    accb += __int_as_float(e23.w) * g3;
  }
  if (j + 2 <= e) {
    int4 e01 = *reinterpret_cast<const int4*>(sedge + j);
    f8 g0 = gat(e01.x), g1 = gat(e01.z);
    acc  += __int_as_float(e01.y) * g0;
    accb += __int_as_float(e01.w) * g1;
    j += 2;
  }
  if (j < e) {
    int2 ed = sedge[j];
    acc += __int_as_float(ed.y) * gat(ed.x);
  }
  acc += accb;
  *reinterpret_cast<h8*>(next + (size_t)row * 64 + l * 8) =
      __builtin_convertvector(acc, h8);
}

// ---------------- final merge: out = (e1 + e2 + e3) / 3, pure stream ----------------
__global__ void k_merge(const h8* __restrict__ A, const h8* __restrict__ B,
                        const h8* __restrict__ C, float* __restrict__ out, int tot8) {
  int stride = gridDim.x * blockDim.x;
  const f8 inv3 = 1.0f / 3.0f;
  for (int i = blockIdx.x * blockDim.x + threadIdx.x; i < tot8; i += stride) {
    f8 s = (__builtin_convertvector(A[i], f8) +
            __builtin_convertvector(B[i], f8) +
            __builtin_convertvector(C[i], f8)) * inv3;
    float4 lo = make_float4(s[0], s[1], s[2], s[3]);
    float4 hi = make_float4(s[4], s[5], s[6], s[7]);
    float4* op = reinterpret_cast<float4*>(out + (size_t)i * 8);
    op[0] = lo; op[1] = hi;
  }
}

// ---------------- fallback path: edge-parallel atomics (if ws too small for CSR) ----------------
__global__ void k_edge_atomic(const int* __restrict__ rows, const int* __restrict__ cols,
                              const float* __restrict__ vals, long long tot16,
                              const float* __restrict__ prev, float* __restrict__ nxt) {
  long long stride = (long long)gridDim.x * blockDim.x;
  for (long long i = (long long)blockIdx.x * blockDim.x + threadIdx.x; i < tot16; i += stride) {
    int e = (int)(i >> 4), l = (int)(i & 15);
    int r = rows[e], c = cols[e];
    float v = vals[e];
    const float4 x = *reinterpret_cast<const float4*>(prev + (size_t)c * 64 + l * 4);
    float* d = nxt + (size_t)r * 64 + l * 4;
    atomicAdd(d + 0, v * x.x); atomicAdd(d + 1, v * x.y);
    atomicAdd(d + 2, v * x.z); atomicAdd(d + 3, v * x.w);
  }
}

__global__ void k_accum(const float4* __restrict__ nxt, float4* __restrict__ out, int tot, int layer) {
  int stride = gridDim.x * blockDim.x;
  for (int i = blockIdx.x * blockDim.x + threadIdx.x; i < tot; i += stride) {
    float4 a = nxt[i];
    if (layer == 0) {
      out[i] = a;
    } else if (layer == 1) {
      float4 o = out[i]; o.x += a.x; o.y += a.y; o.z += a.z; o.w += a.w; out[i] = o;
    } else {
      const float inv3 = 1.0f / 3.0f;
      float4 o = out[i];
      o.x = (o.x + a.x) * inv3; o.y = (o.y + a.y) * inv3;
      o.z = (o.z + a.z) * inv3; o.w = (o.w + a.w) * inv3;
      out[i] = o;
    }
  }
}

extern "C" void kernel_launch(void* const* d_in, const int* in_sizes, int n_in,
                              void* d_out, int out_size, void* d_ws, size_t ws_size,
                              hipStream_t stream) {
  const float* user = (const float*)d_in[0];
  const float* item = (const float*)d_in[1];
  const float* vals = (const float*)d_in[2];
  const int*   rows = (const int*)d_in[3];
  const int*   cols = (const int*)d_in[4];
  const int D = 64;
  const int num_users = in_sizes[0] / D;
  const int num_items = in_sizes[1] / D;
  const int nnz = in_sizes[2];
  const int N = num_users + num_items;
  float* out = (float*)d_out;

  // ---- carve workspace ----
  size_t off = 0;
  auto carve = [&](size_t bytes) -> char* {
    char* p = (char*)d_ws + off;
    off = (off + bytes + 255) & ~(size_t)255;
    return p;
  };
  size_t egoBytesF = (size_t)N * D * sizeof(float);   // 76.8 MB
  size_t egoBytesH = (size_t)N * D * sizeof(_Float16);// 38.4 MB
  char* region1 = carve(egoBytesF);   // fp16 path: A + B tables ; fallback: egoA f32
  char* region2 = carve(egoBytesF);   // fp16 path: C table / binned ; fallback: egoB f32
  int nB = (N + RB - 1) >> RB_LOG;
  int*  row_ptr     = (int*)carve((size_t)(N + 1) * 4);
  int*  bucket_cnt  = (int*)carve((size_t)nB * 4);
  int*  bucket_base = (int*)carve((size_t)(nB + 1) * 4);
  int*  bucket_fill = (int*)carve((size_t)nB * 4);
  int2* sedge       = (int2*)carve((size_t)nnz * 8);

  _Float16* egoA_h = (_Float16*)region1;              // ego0, then e3
  _Float16* egoB_h = (_Float16*)(region1 + egoBytesH);// e1
  _Float16* egoC_h = (_Float16*)region2;              // e2 (clobbers binned after it's dead)
  int2*     binned = (int2*)region2;
  bool use_csr = (off <= ws_size) && (nB <= MAX_NB) &&
                 ((size_t)nnz * 8 <= egoBytesF) && (N < (1 << COL_BITS)) &&
                 (2 * egoBytesH <= egoBytesF);

  if (use_csr) {
    hipMemsetAsync(bucket_cnt, 0, (size_t)nB * 4, stream);
    k_bhist<<<BH_BLOCKS, THREADS, 0, stream>>>(rows, nnz, nB, bucket_cnt);
    k_scan_buckets<<<1, 1024, 0, stream>>>(bucket_cnt, nB, bucket_base, bucket_fill);
    int nchunks = (nnz + CH - 1) / CH;
    k_bin<<<nchunks, BT_BIN, 0, stream>>>(rows, cols, vals, nnz, nB, bucket_fill, binned);
    k_bucket_sedge<<<nB, 1024, 0, stream>>>(binned, bucket_base, row_ptr, N, nnz, sedge);
    int totF4 = N * (D / 4);
    int uf4   = num_users * (D / 4);
    k_tofp16<<<GS_BLOCKS, THREADS, 0, stream>>>((const float4*)user, (const float4*)item,
                                                (h4*)egoA_h, uf4, totF4);

    int spmm_blocks = (N * 8 + THREADS - 1) / THREADS;
    // layer 0: ego0(A) -> e1(B)
    k_spmm_h8<<<spmm_blocks, THREADS, 0, stream>>>(row_ptr, sedge, egoA_h, egoB_h, N);
    // layer 1: e1(B) -> e2(C)  (binned dead now)
    k_spmm_h8<<<spmm_blocks, THREADS, 0, stream>>>(row_ptr, sedge, egoB_h, egoC_h, N);
    // layer 2: e2(C) -> e3(A)  (ego0 dead)
    k_spmm_h8<<<spmm_blocks, THREADS, 0, stream>>>(row_ptr, sedge, egoC_h, egoA_h, N);
    // out = (e1 + e2 + e3) / 3
    int tot8 = N * (D / 8);
    k_merge<<<GS_BLOCKS, THREADS, 0, stream>>>((const h8*)egoB_h, (const h8*)egoC_h,
                                               (const h8*)egoA_h, out, tot8);
  } else {
    // atomic fallback: f32 ego ping-pong in region1/region2
    float* egoA = (float*)region1;
    float* egoB = (float*)region2;
    int totF4 = N * (D / 4);
    int uf4   = num_users * (D / 4);
    k_concat<<<GS_BLOCKS, THREADS, 0, stream>>>((const float4*)user, (const float4*)item,
                                                (float4*)egoA, uf4, totF4);
    float* prev = egoA;
    float* next = egoB;
    long long tot16 = (long long)nnz * 16;
    for (int layer = 0; layer < 3; ++layer) {
      hipMemsetAsync(next, 0, egoBytesF, stream);
      k_edge_atomic<<<GS_BLOCKS * 2, THREADS, 0, stream>>>(rows, cols, vals, tot16, prev, next);
      k_accum<<<GS_BLOCKS, THREADS, 0, stream>>>((const float4*)next, (float4*)out, totF4, layer);
      float* t = prev; prev = next; next = t;
    }
  }
}

// Round 10
// 504.163 us; speedup vs baseline: 2.2169x; 1.0455x over previous
//
#include <hip/hip_runtime.h>

constexpr int GS_BLOCKS = 2048;
constexpr int THREADS   = 256;
constexpr int RB_LOG    = 9;               // rows per bucket = 512
constexpr int RB        = 1 << RB_LOG;
constexpr int CH        = 8192;            // edges per Pass-A chunk (14-edge bursts)
constexpr int BT_BIN    = 1024;            // k_bin block size
constexpr int COL_BITS  = 19;              // N < 2^19
constexpr int COL_MASK  = (1 << COL_BITS) - 1;
constexpr int MAX_NB    = 1024;            // max buckets supported by LDS arrays

typedef _Float16 h4 __attribute__((ext_vector_type(4)));
typedef _Float16 h8 __attribute__((ext_vector_type(8)));
typedef float    f8 __attribute__((ext_vector_type(8)));
typedef float    f4 __attribute__((ext_vector_type(4)));
typedef int      i4 __attribute__((ext_vector_type(4)));

// ---------------- ego0 = concat(user, item) as fp16 ----------------
__global__ void k_tofp16(const f4* __restrict__ u, const f4* __restrict__ it,
                         h4* __restrict__ dst, int uf4, int tot) {
  int stride = gridDim.x * blockDim.x;
  for (int i = blockIdx.x * blockDim.x + threadIdx.x; i < tot; i += stride) {
    f4 v = (i < uf4) ? __builtin_nontemporal_load(u + i)
                     : __builtin_nontemporal_load(it + (i - uf4));
    h4 o;
    o[0] = (_Float16)v[0]; o[1] = (_Float16)v[1];
    o[2] = (_Float16)v[2]; o[3] = (_Float16)v[3];
    dst[i] = o;
  }
}

// ---------------- ego0 = concat(user, item) f32 (fallback path only) ----------------
__global__ void k_concat(const float4* __restrict__ u, const float4* __restrict__ it,
                         float4* __restrict__ dst, int uf4, int tot) {
  int stride = gridDim.x * blockDim.x;
  for (int i = blockIdx.x * blockDim.x + threadIdx.x; i < tot; i += stride)
    dst[i] = (i < uf4) ? u[i] : it[i - uf4];
}

// ---------------- init: bucket_fill[b] = b*cap ----------------
__global__ void __launch_bounds__(1024)
k_init_fill(int* __restrict__ bucket_fill, int nB, int cap) {
  int t = threadIdx.x;
  for (int b = t; b < nB; b += 1024) bucket_fill[b] = b * cap;
}

// ---------------- Pass A: chunk-local LDS binning into fixed-cap buckets ----------------
// No pre-histogram needed: reserve atomics start from b*cap.
__global__ void __launch_bounds__(BT_BIN)
k_bin(const int* __restrict__ rows, const int* __restrict__ cols,
      const float* __restrict__ vals, int nnz, int nB, int cap,
      int* __restrict__ bucket_fill, int2* __restrict__ binned) {
  __shared__ int bcnt[MAX_NB];      // counts, then reused as global-base per bucket
  __shared__ int bfill[MAX_NB];     // chunk-local running rank
  __shared__ int rstash[CH];        // rows cached from phase 1 for phase 3
  int t = threadIdx.x;
  int c0 = blockIdx.x * CH;
  if (t < nB) { bcnt[t] = 0; bfill[t] = 0; }
  __syncthreads();
  // phase 1: vector count (+ stash rows as i4)
  const i4* r4 = (const i4*)(rows + c0);  // c0 % 8192 == 0 -> aligned
  i4* rs4 = (i4*)rstash;
#pragma unroll
  for (int k = 0; k < CH / (BT_BIN * 4); k++) {
    int q = t + k * BT_BIN;
    int e = c0 + q * 4;
    if (e + 3 < nnz) {
      i4 v = __builtin_nontemporal_load(r4 + q);
      rs4[q] = v;
      atomicAdd(&bcnt[v[0] >> RB_LOG], 1);
      atomicAdd(&bcnt[v[1] >> RB_LOG], 1);
      atomicAdd(&bcnt[v[2] >> RB_LOG], 1);
      atomicAdd(&bcnt[v[3] >> RB_LOG], 1);
    } else {
      for (int u = 0; u < 4; u++) {
        int ee = e + u;
        if (ee < nnz) {
          int r = rows[ee];
          rstash[q * 4 + u] = r;
          atomicAdd(&bcnt[r >> RB_LOG], 1);
        }
      }
    }
  }
  __syncthreads();
  // phase 2: reserve global range per bucket (bcnt becomes global base)
  if (t < nB) {
    int c = bcnt[t];
    bcnt[t] = (c > 0) ? atomicAdd(&bucket_fill[t], c) : 0;
  }
  __syncthreads();
  // phase 3: scatter into bucket-major bursts (vector cols/vals, rows from LDS)
  const i4* c4 = (const i4*)(cols + c0);
  const f4* v4 = (const f4*)(vals + c0);
#pragma unroll
  for (int k = 0; k < CH / (BT_BIN * 4); k++) {
    int q = t + k * BT_BIN;
    int e = c0 + q * 4;
    if (e + 3 < nnz) {
      i4 cc = __builtin_nontemporal_load(c4 + q);
      f4 vv = __builtin_nontemporal_load(v4 + q);
      i4 rr = rs4[q];
#pragma unroll
      for (int u = 0; u < 4; u++) {
        int r = rr[u];
        int b = r >> RB_LOG;
        int rank = atomicAdd(&bfill[b], 1);
        int packed = ((r & (RB - 1)) << COL_BITS) | cc[u];
        binned[bcnt[b] + rank] = make_int2(packed, __float_as_int(vv[u]));
      }
    } else {
      for (int u = 0; u < 4; u++) {
        int ee = e + u;
        if (ee < nnz) {
          int r = rstash[q * 4 + u];
          int b = r >> RB_LOG;
          int rank = atomicAdd(&bfill[b], 1);
          int packed = ((r & (RB - 1)) << COL_BITS) | cols[ee];
          binned[bcnt[b] + rank] = make_int2(packed, __float_as_int(vals[ee]));
        }
      }
    }
  }
}

// ---------------- post-scan: bucket_base = excl-scan(bucket_fill - b*cap) ----------------
__global__ void __launch_bounds__(1024)
k_scan_buckets(const int* __restrict__ bucket_fill, int nB, int cap,
               int* __restrict__ bucket_base) {
  __shared__ int a[1024];
  int t = threadIdx.x;
  int mine = (t < nB) ? (bucket_fill[t] - t * cap) : 0;
  a[t] = mine; __syncthreads();
  for (int off = 1; off < 1024; off <<= 1) {
    int x = (t >= off) ? a[t - off] : 0;
    __syncthreads();
    a[t] += x;
    __syncthreads();
  }
  int excl = a[t] - mine;
  if (t < nB) bucket_base[t] = excl;
  if (t == 1023) bucket_base[nB] = a[1023];
}

// ---------------- Pass B: per-bucket LDS counting sort -> sedge + row_ptr ----------------
__global__ void __launch_bounds__(1024)
k_bucket_sedge(const int2* __restrict__ binned, int cap,
               const int* __restrict__ bucket_fill, const int* __restrict__ bucket_base,
               int* __restrict__ row_ptr, int N, int nnz, int2* __restrict__ sedge) {
  __shared__ int rcnt[RB];
  __shared__ int sarr[RB];
  int b = blockIdx.x, t = threadIdx.x;
  int cnt = bucket_fill[b] - b * cap;
  const int2* src = binned + (size_t)b * cap;   // cap even -> 16B aligned
  int gbase = bucket_base[b];
  if (t < RB) rcnt[t] = 0;
  __syncthreads();
  for (int j = t * 2; j < cnt; j += 2048) {
    i4 two = *(const i4*)(src + j);
    atomicAdd(&rcnt[(unsigned)two[0] >> COL_BITS], 1);
    if (j + 1 < cnt) atomicAdd(&rcnt[(unsigned)two[2] >> COL_BITS], 1);
  }
  __syncthreads();
  int mine = (t < RB) ? rcnt[t] : 0;
  if (t < RB) sarr[t] = mine;
  __syncthreads();
  for (int off = 1; off < RB; off <<= 1) {
    int x = 0;
    if (t < RB && t >= off) x = sarr[t - off];
    __syncthreads();
    if (t < RB) sarr[t] += x;
    __syncthreads();
  }
  if (t < RB) {
    int excl = sarr[t] - mine;
    int grow = (b << RB_LOG) + t;
    if (grow < N) row_ptr[grow] = gbase + excl;  // fused row_ptr construction
    rcnt[t] = gbase + excl;                      // absolute running fill counter
  }
  if (b == 0 && t == 0) row_ptr[N] = nnz;
  __syncthreads();
  for (int j = t * 2; j < cnt; j += 2048) {
    i4 two = *(const i4*)(src + j);
    {
      int rL = (unsigned)two[0] >> COL_BITS;
      int pos = atomicAdd(&rcnt[rL], 1);
      sedge[pos] = make_int2(two[0] & COL_MASK, two[1]);
    }
    if (j + 1 < cnt) {
      int rL = (unsigned)two[2] >> COL_BITS;
      int pos = atomicAdd(&rcnt[rL], 1);
      sedge[pos] = make_int2(two[2] & COL_MASK, two[3]);
    }
  }
}

// ---------------- row-parallel SpMM over fp16 table: 8 lanes/row, h8 (16B) per lane ----------------
__global__ void __launch_bounds__(THREADS)
k_spmm_h8(const int* __restrict__ row_ptr, const int2* __restrict__ sedge,
          const _Float16* __restrict__ prev, _Float16* __restrict__ next, int n) {
  int gid = blockIdx.x * blockDim.x + threadIdx.x;
  int row = gid >> 3, l = gid & 7;
  if (row >= n) return;
  int s = row_ptr[row], e = row_ptr[row + 1];
  f8 acc = 0.f, accb = 0.f;
  auto gat = [&](int c) -> f8 {
    h8 g = *reinterpret_cast<const h8*>(prev + (size_t)c * 64 + l * 8);
    return __builtin_convertvector(g, f8);
  };
  int j = s;
  if (j < e && (j & 1)) {  // align to even for i4 edge loads
    int2 ed = sedge[j];
    acc += __int_as_float(ed.y) * gat(ed.x);
    ++j;
  }
  const i4* s4 = (const i4*)sedge;
  for (; j + 4 <= e; j += 4) {
    i4 e01 = __builtin_nontemporal_load(s4 + (j >> 1));
    i4 e23 = __builtin_nontemporal_load(s4 + (j >> 1) + 1);
    f8 g0 = gat(e01[0]), g1 = gat(e01[2]), g2 = gat(e23[0]), g3 = gat(e23[2]);
    acc  += __int_as_float(e01[1]) * g0;
    accb += __int_as_float(e01[3]) * g1;
    acc  += __int_as_float(e23[1]) * g2;
    accb += __int_as_float(e23[3]) * g3;
  }
  if (j + 2 <= e) {
    i4 e01 = __builtin_nontemporal_load(s4 + (j >> 1));
    f8 g0 = gat(e01[0]), g1 = gat(e01[2]);
    acc  += __int_as_float(e01[1]) * g0;
    accb += __int_as_float(e01[3]) * g1;
    j += 2;
  }
  if (j < e) {
    int2 ed = sedge[j];
    acc += __int_as_float(ed.y) * gat(ed.x);
  }
  acc += accb;
  *reinterpret_cast<h8*>(next + (size_t)row * 64 + l * 8) =
      __builtin_convertvector(acc, h8);
}

// ---------------- final merge: out = (e1 + e2 + e3) / 3, pure stream ----------------
__global__ void k_merge(const h8* __restrict__ A, const h8* __restrict__ B,
                        const h8* __restrict__ C, float* __restrict__ out, int tot8) {
  int stride = gridDim.x * blockDim.x;
  const f8 inv3 = 1.0f / 3.0f;
  for (int i = blockIdx.x * blockDim.x + threadIdx.x; i < tot8; i += stride) {
    h8 a = __builtin_nontemporal_load(A + i);
    h8 b = __builtin_nontemporal_load(B + i);
    h8 c = __builtin_nontemporal_load(C + i);
    f8 s = (__builtin_convertvector(a, f8) +
            __builtin_convertvector(b, f8) +
            __builtin_convertvector(c, f8)) * inv3;
    float4 lo = make_float4(s[0], s[1], s[2], s[3]);
    float4 hi = make_float4(s[4], s[5], s[6], s[7]);
    float4* op = reinterpret_cast<float4*>(out + (size_t)i * 8);
    op[0] = lo; op[1] = hi;
  }
}

// ---------------- fallback path: edge-parallel atomics (if ws too small for CSR) ----------------
__global__ void k_edge_atomic(const int* __restrict__ rows, const int* __restrict__ cols,
                              const float* __restrict__ vals, long long tot16,
                              const float* __restrict__ prev, float* __restrict__ nxt) {
  long long stride = (long long)gridDim.x * blockDim.x;
  for (long long i = (long long)blockIdx.x * blockDim.x + threadIdx.x; i < tot16; i += stride) {
    int e = (int)(i >> 4), l = (int)(i & 15);
    int r = rows[e], c = cols[e];
    float v = vals[e];
    const float4 x = *reinterpret_cast<const float4*>(prev + (size_t)c * 64 + l * 4);
    float* d = nxt + (size_t)r * 64 + l * 4;
    atomicAdd(d + 0, v * x.x); atomicAdd(d + 1, v * x.y);
    atomicAdd(d + 2, v * x.z); atomicAdd(d + 3, v * x.w);
  }
}

__global__ void k_accum(const float4* __restrict__ nxt, float4* __restrict__ out, int tot, int layer) {
  int stride = gridDim.x * blockDim.x;
  for (int i = blockIdx.x * blockDim.x + threadIdx.x; i < tot; i += stride) {
    float4 a = nxt[i];
    if (layer == 0) {
      out[i] = a;
    } else if (layer == 1) {
      float4 o = out[i]; o.x += a.x; o.y += a.y; o.z += a.z; o.w += a.w; out[i] = o;
    } else {
      const float inv3 = 1.0f / 3.0f;
      float4 o = out[i];
      o.x = (o.x + a.x) * inv3; o.y = (o.y + a.y) * inv3;
      o.z = (o.z + a.z) * inv3; o.w = (o.w + a.w) * inv3;
      out[i] = o;
    }
  }
}

extern "C" void kernel_launch(void* const* d_in, const int* in_sizes, int n_in,
                              void* d_out, int out_size, void* d_ws, size_t ws_size,
                              hipStream_t stream) {
  const float* user = (const float*)d_in[0];
  const float* item = (const float*)d_in[1];
  const float* vals = (const float*)d_in[2];
  const int*   rows = (const int*)d_in[3];
  const int*   cols = (const int*)d_in[4];
  const int D = 64;
  const int num_users = in_sizes[0] / D;
  const int num_items = in_sizes[1] / D;
  const int nnz = in_sizes[2];
  const int N = num_users + num_items;
  float* out = (float*)d_out;

  // ---- carve workspace ----
  size_t off = 0;
  auto carve = [&](size_t bytes) -> char* {
    char* p = (char*)d_ws + off;
    off = (off + bytes + 255) & ~(size_t)255;
    return p;
  };
  size_t egoBytesF = (size_t)N * D * sizeof(float);   // 76.8 MB
  size_t egoBytesH = (size_t)N * D * sizeof(_Float16);// 38.4 MB
  char* region1 = carve(egoBytesF);   // fp16 path: A + B tables ; fallback: egoA f32
  char* region2 = carve(egoBytesF);   // fp16 path: binned / C table ; fallback: egoB f32
  int nB = (N + RB - 1) >> RB_LOG;
  int*  row_ptr     = (int*)carve((size_t)(N + 1) * 4);
  int*  bucket_base = (int*)carve((size_t)(nB + 1) * 4);
  int*  bucket_fill = (int*)carve((size_t)nB * 4);
  int2* sedge       = (int2*)carve((size_t)nnz * 8);

  // fixed-capacity bucket regions in binned (25% + 64 margin, even)
  int cap = ((nnz / (nB > 0 ? nB : 1)) * 5 / 4 + 64) & ~1;

  _Float16* egoA_h = (_Float16*)region1;              // ego0, then e3
  _Float16* egoB_h = (_Float16*)(region1 + egoBytesH);// e1
  _Float16* egoC_h = (_Float16*)region2;              // e2 (clobbers binned after it's dead)
  int2*     binned = (int2*)region2;
  bool use_csr = (off <= ws_size) && (nB <= MAX_NB) &&
                 ((size_t)nnz * 8 <= egoBytesF) && (N < (1 << COL_BITS)) &&
                 (2 * egoBytesH <= egoBytesF) &&
                 ((size_t)nB * cap * 8 <= egoBytesF);

  if (use_csr) {
    k_init_fill<<<1, 1024, 0, stream>>>(bucket_fill, nB, cap);
    int nchunks = (nnz + CH - 1) / CH;
    k_bin<<<nchunks, BT_BIN, 0, stream>>>(rows, cols, vals, nnz, nB, cap,
                                          bucket_fill, binned);
    k_scan_buckets<<<1, 1024, 0, stream>>>(bucket_fill, nB, cap, bucket_base);
    k_bucket_sedge<<<nB, 1024, 0, stream>>>(binned, cap, bucket_fill, bucket_base,
                                            row_ptr, N, nnz, sedge);
    int totF4 = N * (D / 4);
    int uf4   = num_users * (D / 4);
    k_tofp16<<<GS_BLOCKS, THREADS, 0, stream>>>((const f4*)user, (const f4*)item,
                                                (h4*)egoA_h, uf4, totF4);

    int spmm_blocks = (N * 8 + THREADS - 1) / THREADS;
    // layer 0: ego0(A) -> e1(B)
    k_spmm_h8<<<spmm_blocks, THREADS, 0, stream>>>(row_ptr, sedge, egoA_h, egoB_h, N);
    // layer 1: e1(B) -> e2(C)  (binned dead now)
    k_spmm_h8<<<spmm_blocks, THREADS, 0, stream>>>(row_ptr, sedge, egoB_h, egoC_h, N);
    // layer 2: e2(C) -> e3(A)  (ego0 dead)
    k_spmm_h8<<<spmm_blocks, THREADS, 0, stream>>>(row_ptr, sedge, egoC_h, egoA_h, N);
    // out = (e1 + e2 + e3) / 3
    int tot8 = N * (D / 8);
    k_merge<<<GS_BLOCKS, THREADS, 0, stream>>>((const h8*)egoB_h, (const h8*)egoC_h,
                                               (const h8*)egoA_h, out, tot8);
  } else {
    // atomic fallback: f32 ego ping-pong in region1/region2
    float* egoA = (float*)region1;
    float* egoB = (float*)region2;
    int totF4 = N * (D / 4);
    int uf4   = num_users * (D / 4);
    k_concat<<<GS_BLOCKS, THREADS, 0, stream>>>((const float4*)user, (const float4*)item,
                                                (float4*)egoA, uf4, totF4);
    float* prev = egoA;
    float* next = egoB;
    long long tot16 = (long long)nnz * 16;
    for (int layer = 0; layer < 3; ++layer) {
      hipMemsetAsync(next, 0, egoBytesF, stream);
      k_edge_atomic<<<GS_BLOCKS * 2, THREADS, 0, stream>>>(rows, cols, vals, tot16, prev, next);
      k_accum<<<GS_BLOCKS, THREADS, 0, stream>>>((const float4*)next, (float4*)out, totF4, layer);
      float* t = prev; prev = next; next = t;
    }
  }
}

// Round 11
// 474.901 us; speedup vs baseline: 2.3535x; 1.0616x over previous
//
#include <hip/hip_runtime.h>

constexpr int GS_BLOCKS = 2048;
constexpr int THREADS   = 256;
constexpr int RB_LOG    = 9;               // rows per bucket = 512
constexpr int RB        = 1 << RB_LOG;
constexpr int CH        = 8192;            // edges per Pass-A chunk (14-edge bursts)
constexpr int BT_BIN    = 1024;            // k_bin block size
constexpr int COL_BITS  = 19;              // N < 2^19
constexpr int COL_MASK  = (1 << COL_BITS) - 1;
constexpr int MAX_NB    = 1024;            // max buckets supported by LDS arrays

typedef _Float16 h4 __attribute__((ext_vector_type(4)));
typedef _Float16 h8 __attribute__((ext_vector_type(8)));
typedef float    f8 __attribute__((ext_vector_type(8)));
typedef float    f4 __attribute__((ext_vector_type(4)));
typedef int      i4 __attribute__((ext_vector_type(4)));

// ---------------- ego0 = concat(user, item) as fp16 ----------------
__global__ void k_tofp16(const f4* __restrict__ u, const f4* __restrict__ it,
                         h4* __restrict__ dst, int uf4, int tot) {
  int stride = gridDim.x * blockDim.x;
  for (int i = blockIdx.x * blockDim.x + threadIdx.x; i < tot; i += stride) {
    f4 v = (i < uf4) ? __builtin_nontemporal_load(u + i)
                     : __builtin_nontemporal_load(it + (i - uf4));
    h4 o;
    o[0] = (_Float16)v[0]; o[1] = (_Float16)v[1];
    o[2] = (_Float16)v[2]; o[3] = (_Float16)v[3];
    dst[i] = o;
  }
}

// ---------------- ego0 = concat(user, item) f32 (fallback path only) ----------------
__global__ void k_concat(const float4* __restrict__ u, const float4* __restrict__ it,
                         float4* __restrict__ dst, int uf4, int tot) {
  int stride = gridDim.x * blockDim.x;
  for (int i = blockIdx.x * blockDim.x + threadIdx.x; i < tot; i += stride)
    dst[i] = (i < uf4) ? u[i] : it[i - uf4];
}

// ---------------- init: bucket_fill[b] = b*cap ----------------
__global__ void __launch_bounds__(1024)
k_init_fill(int* __restrict__ bucket_fill, int nB, int cap) {
  int t = threadIdx.x;
  for (int b = t; b < nB; b += 1024) bucket_fill[b] = b * cap;
}

// ---------------- Pass A: chunk-local LDS binning into fixed-cap buckets ----------------
__global__ void __launch_bounds__(BT_BIN)
k_bin(const int* __restrict__ rows, const int* __restrict__ cols,
      const float* __restrict__ vals, int nnz, int nB, int cap,
      int* __restrict__ bucket_fill, int2* __restrict__ binned) {
  __shared__ int bcnt[MAX_NB];      // counts, then reused as global-base per bucket
  __shared__ int bfill[MAX_NB];     // chunk-local running rank
  __shared__ int rstash[CH];        // rows cached from phase 1 for phase 3
  int t = threadIdx.x;
  int c0 = blockIdx.x * CH;
  if (t < nB) { bcnt[t] = 0; bfill[t] = 0; }
  __syncthreads();
  // phase 1: vector count (+ stash rows as i4)
  const i4* r4 = (const i4*)(rows + c0);  // c0 % 8192 == 0 -> aligned
  i4* rs4 = (i4*)rstash;
#pragma unroll
  for (int k = 0; k < CH / (BT_BIN * 4); k++) {
    int q = t + k * BT_BIN;
    int e = c0 + q * 4;
    if (e + 3 < nnz) {
      i4 v = __builtin_nontemporal_load(r4 + q);
      rs4[q] = v;
      atomicAdd(&bcnt[v[0] >> RB_LOG], 1);
      atomicAdd(&bcnt[v[1] >> RB_LOG], 1);
      atomicAdd(&bcnt[v[2] >> RB_LOG], 1);
      atomicAdd(&bcnt[v[3] >> RB_LOG], 1);
    } else {
      for (int u = 0; u < 4; u++) {
        int ee = e + u;
        if (ee < nnz) {
          int r = rows[ee];
          rstash[q * 4 + u] = r;
          atomicAdd(&bcnt[r >> RB_LOG], 1);
        }
      }
    }
  }
  __syncthreads();
  // phase 2: reserve global range per bucket (bcnt becomes global base)
  if (t < nB) {
    int c = bcnt[t];
    bcnt[t] = (c > 0) ? atomicAdd(&bucket_fill[t], c) : 0;
  }
  __syncthreads();
  // phase 3: scatter into bucket-major bursts (vector cols/vals, rows from LDS)
  const i4* c4 = (const i4*)(cols + c0);
  const f4* v4 = (const f4*)(vals + c0);
#pragma unroll
  for (int k = 0; k < CH / (BT_BIN * 4); k++) {
    int q = t + k * BT_BIN;
    int e = c0 + q * 4;
    if (e + 3 < nnz) {
      i4 cc = __builtin_nontemporal_load(c4 + q);
      f4 vv = __builtin_nontemporal_load(v4 + q);
      i4 rr = rs4[q];
#pragma unroll
      for (int u = 0; u < 4; u++) {
        int r = rr[u];
        int b = r >> RB_LOG;
        int rank = atomicAdd(&bfill[b], 1);
        int packed = ((r & (RB - 1)) << COL_BITS) | cc[u];
        binned[bcnt[b] + rank] = make_int2(packed, __float_as_int(vv[u]));
      }
    } else {
      for (int u = 0; u < 4; u++) {
        int ee = e + u;
        if (ee < nnz) {
          int r = rstash[q * 4 + u];
          int b = r >> RB_LOG;
          int rank = atomicAdd(&bfill[b], 1);
          int packed = ((r & (RB - 1)) << COL_BITS) | cols[ee];
          binned[bcnt[b] + rank] = make_int2(packed, __float_as_int(vals[ee]));
        }
      }
    }
  }
}

// ---------------- post-scan: bucket_base = excl-scan(bucket_fill - b*cap) ----------------
__global__ void __launch_bounds__(1024)
k_scan_buckets(const int* __restrict__ bucket_fill, int nB, int cap,
               int* __restrict__ bucket_base) {
  __shared__ int a[1024];
  int t = threadIdx.x;
  int mine = (t < nB) ? (bucket_fill[t] - t * cap) : 0;
  a[t] = mine; __syncthreads();
  for (int off = 1; off < 1024; off <<= 1) {
    int x = (t >= off) ? a[t - off] : 0;
    __syncthreads();
    a[t] += x;
    __syncthreads();
  }
  int excl = a[t] - mine;
  if (t < nB) bucket_base[t] = excl;
  if (t == 1023) bucket_base[nB] = a[1023];
}

// ---------------- Pass B: per-bucket LDS counting sort -> sedge + row_ptr ----------------
__global__ void __launch_bounds__(1024)
k_bucket_sedge(const int2* __restrict__ binned, int cap,
               const int* __restrict__ bucket_fill, const int* __restrict__ bucket_base,
               int* __restrict__ row_ptr, int N, int nnz, int2* __restrict__ sedge) {
  __shared__ int rcnt[RB];
  __shared__ int sarr[RB];
  int b = blockIdx.x, t = threadIdx.x;
  int cnt = bucket_fill[b] - b * cap;
  const int2* src = binned + (size_t)b * cap;   // cap even -> 16B aligned
  int gbase = bucket_base[b];
  if (t < RB) rcnt[t] = 0;
  __syncthreads();
  for (int j = t * 2; j < cnt; j += 2048) {
    i4 two = *(const i4*)(src + j);
    atomicAdd(&rcnt[(unsigned)two[0] >> COL_BITS], 1);
    if (j + 1 < cnt) atomicAdd(&rcnt[(unsigned)two[2] >> COL_BITS], 1);
  }
  __syncthreads();
  int mine = (t < RB) ? rcnt[t] : 0;
  if (t < RB) sarr[t] = mine;
  __syncthreads();
  for (int off = 1; off < RB; off <<= 1) {
    int x = 0;
    if (t < RB && t >= off) x = sarr[t - off];
    __syncthreads();
    if (t < RB) sarr[t] += x;
    __syncthreads();
  }
  if (t < RB) {
    int excl = sarr[t] - mine;
    int grow = (b << RB_LOG) + t;
    if (grow < N) row_ptr[grow] = gbase + excl;  // fused row_ptr construction
    rcnt[t] = gbase + excl;                      // absolute running fill counter
  }
  if (b == 0 && t == 0) row_ptr[N] = nnz;
  __syncthreads();
  for (int j = t * 2; j < cnt; j += 2048) {
    i4 two = *(const i4*)(src + j);
    {
      int rL = (unsigned)two[0] >> COL_BITS;
      int pos = atomicAdd(&rcnt[rL], 1);
      sedge[pos] = make_int2(two[0] & COL_MASK, two[1]);
    }
    if (j + 1 < cnt) {
      int rL = (unsigned)two[2] >> COL_BITS;
      int pos = atomicAdd(&rcnt[rL], 1);
      sedge[pos] = make_int2(two[2] & COL_MASK, two[3]);
    }
  }
}

// ---------------- row-parallel SpMM over fp16 table: 8 lanes/row, h8 (16B) per lane ----------------
// Plain (cache-allocating) sedge loads: the edge list is re-read by 3 layers
// and fits L3 — nt loads cost +40MB HBM fetch per layer (round-10 regression).
__global__ void __launch_bounds__(THREADS)
k_spmm_h8(const int* __restrict__ row_ptr, const int2* __restrict__ sedge,
          const _Float16* __restrict__ prev, _Float16* __restrict__ next, int n) {
  int gid = blockIdx.x * blockDim.x + threadIdx.x;
  int row = gid >> 3, l = gid & 7;
  if (row >= n) return;
  int s = row_ptr[row], e = row_ptr[row + 1];
  f8 acc = 0.f, accb = 0.f;
  auto gat = [&](int c) -> f8 {
    h8 g = *reinterpret_cast<const h8*>(prev + (size_t)c * 64 + l * 8);
    return __builtin_convertvector(g, f8);
  };
  int j = s;
  if (j < e && (j & 1)) {  // align to even for i4 edge loads
    int2 ed = sedge[j];
    acc += __int_as_float(ed.y) * gat(ed.x);
    ++j;
  }
  const i4* s4 = (const i4*)sedge;
  for (; j + 4 <= e; j += 4) {
    i4 e01 = s4[j >> 1];
    i4 e23 = s4[(j >> 1) + 1];
    f8 g0 = gat(e01[0]), g1 = gat(e01[2]), g2 = gat(e23[0]), g3 = gat(e23[2]);
    acc  += __int_as_float(e01[1]) * g0;
    accb += __int_as_float(e01[3]) * g1;
    acc  += __int_as_float(e23[1]) * g2;
    accb += __int_as_float(e23[3]) * g3;
  }
  if (j + 2 <= e) {
    i4 e01 = s4[j >> 1];
    f8 g0 = gat(e01[0]), g1 = gat(e01[2]);
    acc  += __int_as_float(e01[1]) * g0;
    accb += __int_as_float(e01[3]) * g1;
    j += 2;
  }
  if (j < e) {
    int2 ed = sedge[j];
    acc += __int_as_float(ed.y) * gat(ed.x);
  }
  acc += accb;
  *reinterpret_cast<h8*>(next + (size_t)row * 64 + l * 8) =
      __builtin_convertvector(acc, h8);
}

// ---------------- final merge: out = (e1 + e2 + e3) / 3, pure stream ----------------
// Plain loads: A/B/C were just written and are L3-hot.
__global__ void k_merge(const h8* __restrict__ A, const h8* __restrict__ B,
                        const h8* __restrict__ C, float* __restrict__ out, int tot8) {
  int stride = gridDim.x * blockDim.x;
  const f8 inv3 = 1.0f / 3.0f;
  for (int i = blockIdx.x * blockDim.x + threadIdx.x; i < tot8; i += stride) {
    f8 s = (__builtin_convertvector(A[i], f8) +
            __builtin_convertvector(B[i], f8) +
            __builtin_convertvector(C[i], f8)) * inv3;
    float4 lo = make_float4(s[0], s[1], s[2], s[3]);
    float4 hi = make_float4(s[4], s[5], s[6], s[7]);
    float4* op = reinterpret_cast<float4*>(out + (size_t)i * 8);
    op[0] = lo; op[1] = hi;
  }
}

// ---------------- fallback path: edge-parallel atomics (if ws too small for CSR) ----------------
__global__ void k_edge_atomic(const int* __restrict__ rows, const int* __restrict__ cols,
                              const float* __restrict__ vals, long long tot16,
                              const float* __restrict__ prev, float* __restrict__ nxt) {
  long long stride = (long long)gridDim.x * blockDim.x;
  for (long long i = (long long)blockIdx.x * blockDim.x + threadIdx.x; i < tot16; i += stride) {
    int e = (int)(i >> 4), l = (int)(i & 15);
    int r = rows[e], c = cols[e];
    float v = vals[e];
    const float4 x = *reinterpret_cast<const float4*>(prev + (size_t)c * 64 + l * 4);
    float* d = nxt + (size_t)r * 64 + l * 4;
    atomicAdd(d + 0, v * x.x); atomicAdd(d + 1, v * x.y);
    atomicAdd(d + 2, v * x.z); atomicAdd(d + 3, v * x.w);
  }
}

__global__ void k_accum(const float4* __restrict__ nxt, float4* __restrict__ out, int tot, int layer) {
  int stride = gridDim.x * blockDim.x;
  for (int i = blockIdx.x * blockDim.x + threadIdx.x; i < tot; i += stride) {
    float4 a = nxt[i];
    if (layer == 0) {
      out[i] = a;
    } else if (layer == 1) {
      float4 o = out[i]; o.x += a.x; o.y += a.y; o.z += a.z; o.w += a.w; out[i] = o;
    } else {
      const float inv3 = 1.0f / 3.0f;
      float4 o = out[i];
      o.x = (o.x + a.x) * inv3; o.y = (o.y + a.y) * inv3;
      o.z = (o.z + a.z) * inv3; o.w = (o.w + a.w) * inv3;
      out[i] = o;
    }
  }
}

extern "C" void kernel_launch(void* const* d_in, const int* in_sizes, int n_in,
                              void* d_out, int out_size, void* d_ws, size_t ws_size,
                              hipStream_t stream) {
  const float* user = (const float*)d_in[0];
  const float* item = (const float*)d_in[1];
  const float* vals = (const float*)d_in[2];
  const int*   rows = (const int*)d_in[3];
  const int*   cols = (const int*)d_in[4];
  const int D = 64;
  const int num_users = in_sizes[0] / D;
  const int num_items = in_sizes[1] / D;
  const int nnz = in_sizes[2];
  const int N = num_users + num_items;
  float* out = (float*)d_out;

  // ---- carve workspace ----
  size_t off = 0;
  auto carve = [&](size_t bytes) -> char* {
    char* p = (char*)d_ws + off;
    off = (off + bytes + 255) & ~(size_t)255;
    return p;
  };
  size_t egoBytesF = (size_t)N * D * sizeof(float);   // 76.8 MB
  size_t egoBytesH = (size_t)N * D * sizeof(_Float16);// 38.4 MB
  char* region1 = carve(egoBytesF);   // fp16 path: A + B tables ; fallback: egoA f32
  char* region2 = carve(egoBytesF);   // fp16 path: binned / C table ; fallback: egoB f32
  int nB = (N + RB - 1) >> RB_LOG;
  int*  row_ptr     = (int*)carve((size_t)(N + 1) * 4);
  int*  bucket_base = (int*)carve((size_t)(nB + 1) * 4);
  int*  bucket_fill = (int*)carve((size_t)nB * 4);
  int2* sedge       = (int2*)carve((size_t)nnz * 8);

  // fixed-capacity bucket regions in binned (25% + 64 margin, even)
  int cap = ((nnz / (nB > 0 ? nB : 1)) * 5 / 4 + 64) & ~1;

  _Float16* egoA_h = (_Float16*)region1;              // ego0, then e3
  _Float16* egoB_h = (_Float16*)(region1 + egoBytesH);// e1
  _Float16* egoC_h = (_Float16*)region2;              // e2 (clobbers binned after it's dead)
  int2*     binned = (int2*)region2;
  bool use_csr = (off <= ws_size) && (nB <= MAX_NB) &&
                 ((size_t)nnz * 8 <= egoBytesF) && (N < (1 << COL_BITS)) &&
                 (2 * egoBytesH <= egoBytesF) &&
                 ((size_t)nB * cap * 8 <= egoBytesF);

  if (use_csr) {
    k_init_fill<<<1, 1024, 0, stream>>>(bucket_fill, nB, cap);
    int nchunks = (nnz + CH - 1) / CH;
    k_bin<<<nchunks, BT_BIN, 0, stream>>>(rows, cols, vals, nnz, nB, cap,
                                          bucket_fill, binned);
    k_scan_buckets<<<1, 1024, 0, stream>>>(bucket_fill, nB, cap, bucket_base);
    k_bucket_sedge<<<nB, 1024, 0, stream>>>(binned, cap, bucket_fill, bucket_base,
                                            row_ptr, N, nnz, sedge);
    int totF4 = N * (D / 4);
    int uf4   = num_users * (D / 4);
    k_tofp16<<<GS_BLOCKS, THREADS, 0, stream>>>((const f4*)user, (const f4*)item,
                                                (h4*)egoA_h, uf4, totF4);

    int spmm_blocks = (N * 8 + THREADS - 1) / THREADS;
    // layer 0: ego0(A) -> e1(B)
    k_spmm_h8<<<spmm_blocks, THREADS, 0, stream>>>(row_ptr, sedge, egoA_h, egoB_h, N);
    // layer 1: e1(B) -> e2(C)  (binned dead now)
    k_spmm_h8<<<spmm_blocks, THREADS, 0, stream>>>(row_ptr, sedge, egoB_h, egoC_h, N);
    // layer 2: e2(C) -> e3(A)  (ego0 dead)
    k_spmm_h8<<<spmm_blocks, THREADS, 0, stream>>>(row_ptr, sedge, egoC_h, egoA_h, N);
    // out = (e1 + e2 + e3) / 3
    int tot8 = N * (D / 8);
    k_merge<<<GS_BLOCKS, THREADS, 0, stream>>>((const h8*)egoB_h, (const h8*)egoC_h,
                                               (const h8*)egoA_h, out, tot8);
  } else {
    // atomic fallback: f32 ego ping-pong in region1/region2
    float* egoA = (float*)region1;
    float* egoB = (float*)region2;
    int totF4 = N * (D / 4);
    int uf4   = num_users * (D / 4);
    k_concat<<<GS_BLOCKS, THREADS, 0, stream>>>((const float4*)user, (const float4*)item,
                                                (float4*)egoA, uf4, totF4);
    float* prev = egoA;
    float* next = egoB;
    long long tot16 = (long long)nnz * 16;
    for (int layer = 0; layer < 3; ++layer) {
      hipMemsetAsync(next, 0, egoBytesF, stream);
      k_edge_atomic<<<GS_BLOCKS * 2, THREADS, 0, stream>>>(rows, cols, vals, tot16, prev, next);
      k_accum<<<GS_BLOCKS, THREADS, 0, stream>>>((const float4*)next, (float4*)out, totF4, layer);
      float* t = prev; prev = next; next = t;
    }
  }
}

// Round 12
// 466.134 us; speedup vs baseline: 2.3977x; 1.0188x over previous
//
#include <hip/hip_runtime.h>

constexpr int GS_BLOCKS = 2048;
constexpr int THREADS   = 256;
constexpr int RB_LOG    = 9;               // rows per bucket = 512
constexpr int RB        = 1 << RB_LOG;
constexpr int CH        = 8192;            // edges per Pass-A chunk (14-edge bursts)
constexpr int BT_BIN    = 1024;            // k_bin block size
constexpr int COL_BITS  = 19;              // N < 2^19
constexpr int COL_MASK  = (1 << COL_BITS) - 1;
constexpr int MAX_NB    = 1024;            // max buckets supported by LDS arrays

typedef _Float16 h4 __attribute__((ext_vector_type(4)));
typedef _Float16 h8 __attribute__((ext_vector_type(8)));
typedef float    f8 __attribute__((ext_vector_type(8)));
typedef float    f4 __attribute__((ext_vector_type(4)));
typedef int      i4 __attribute__((ext_vector_type(4)));

// ---------------- ego0 = concat(user, item) as fp16 ----------------
__global__ void k_tofp16(const f4* __restrict__ u, const f4* __restrict__ it,
                         h4* __restrict__ dst, int uf4, int tot) {
  int stride = gridDim.x * blockDim.x;
  for (int i = blockIdx.x * blockDim.x + threadIdx.x; i < tot; i += stride) {
    f4 v = (i < uf4) ? __builtin_nontemporal_load(u + i)
                     : __builtin_nontemporal_load(it + (i - uf4));
    h4 o;
    o[0] = (_Float16)v[0]; o[1] = (_Float16)v[1];
    o[2] = (_Float16)v[2]; o[3] = (_Float16)v[3];
    dst[i] = o;
  }
}

// ---------------- ego0 = concat(user, item) f32 (fallback path only) ----------------
__global__ void k_concat(const float4* __restrict__ u, const float4* __restrict__ it,
                         float4* __restrict__ dst, int uf4, int tot) {
  int stride = gridDim.x * blockDim.x;
  for (int i = blockIdx.x * blockDim.x + threadIdx.x; i < tot; i += stride)
    dst[i] = (i < uf4) ? u[i] : it[i - uf4];
}

// ---------------- init: bucket_fill[b] = b*cap ----------------
__global__ void __launch_bounds__(1024)
k_init_fill(int* __restrict__ bucket_fill, int nB, int cap) {
  int t = threadIdx.x;
  for (int b = t; b < nB; b += 1024) bucket_fill[b] = b * cap;
}

// ---------------- Pass A: chunk-local LDS binning into fixed-cap buckets ----------------
__global__ void __launch_bounds__(BT_BIN)
k_bin(const int* __restrict__ rows, const int* __restrict__ cols,
      const float* __restrict__ vals, int nnz, int nB, int cap,
      int* __restrict__ bucket_fill, int2* __restrict__ binned) {
  __shared__ int bcnt[MAX_NB];      // counts, then reused as global-base per bucket
  __shared__ int bfill[MAX_NB];     // chunk-local running rank
  __shared__ int rstash[CH];        // rows cached from phase 1 for phase 3
  int t = threadIdx.x;
  int c0 = blockIdx.x * CH;
  if (t < nB) { bcnt[t] = 0; bfill[t] = 0; }
  __syncthreads();
  // phase 1: vector count (+ stash rows as i4)
  const i4* r4 = (const i4*)(rows + c0);  // c0 % 8192 == 0 -> aligned
  i4* rs4 = (i4*)rstash;
#pragma unroll
  for (int k = 0; k < CH / (BT_BIN * 4); k++) {
    int q = t + k * BT_BIN;
    int e = c0 + q * 4;
    if (e + 3 < nnz) {
      i4 v = __builtin_nontemporal_load(r4 + q);
      rs4[q] = v;
      atomicAdd(&bcnt[v[0] >> RB_LOG], 1);
      atomicAdd(&bcnt[v[1] >> RB_LOG], 1);
      atomicAdd(&bcnt[v[2] >> RB_LOG], 1);
      atomicAdd(&bcnt[v[3] >> RB_LOG], 1);
    } else {
      for (int u = 0; u < 4; u++) {
        int ee = e + u;
        if (ee < nnz) {
          int r = rows[ee];
          rstash[q * 4 + u] = r;
          atomicAdd(&bcnt[r >> RB_LOG], 1);
        }
      }
    }
  }
  __syncthreads();
  // phase 2: reserve global range per bucket (bcnt becomes global base)
  if (t < nB) {
    int c = bcnt[t];
    bcnt[t] = (c > 0) ? atomicAdd(&bucket_fill[t], c) : 0;
  }
  __syncthreads();
  // phase 3: scatter into bucket-major bursts (vector cols/vals, rows from LDS)
  const i4* c4 = (const i4*)(cols + c0);
  const f4* v4 = (const f4*)(vals + c0);
#pragma unroll
  for (int k = 0; k < CH / (BT_BIN * 4); k++) {
    int q = t + k * BT_BIN;
    int e = c0 + q * 4;
    if (e + 3 < nnz) {
      i4 cc = __builtin_nontemporal_load(c4 + q);
      f4 vv = __builtin_nontemporal_load(v4 + q);
      i4 rr = rs4[q];
#pragma unroll
      for (int u = 0; u < 4; u++) {
        int r = rr[u];
        int b = r >> RB_LOG;
        int rank = atomicAdd(&bfill[b], 1);
        int packed = ((r & (RB - 1)) << COL_BITS) | cc[u];
        binned[bcnt[b] + rank] = make_int2(packed, __float_as_int(vv[u]));
      }
    } else {
      for (int u = 0; u < 4; u++) {
        int ee = e + u;
        if (ee < nnz) {
          int r = rstash[q * 4 + u];
          int b = r >> RB_LOG;
          int rank = atomicAdd(&bfill[b], 1);
          int packed = ((r & (RB - 1)) << COL_BITS) | cols[ee];
          binned[bcnt[b] + rank] = make_int2(packed, __float_as_int(vals[ee]));
        }
      }
    }
  }
}

// ---------------- post-scan: bucket_base = excl-scan(bucket_fill - b*cap) ----------------
__global__ void __launch_bounds__(1024)
k_scan_buckets(const int* __restrict__ bucket_fill, int nB, int cap,
               int* __restrict__ bucket_base) {
  __shared__ int a[1024];
  int t = threadIdx.x;
  int mine = (t < nB) ? (bucket_fill[t] - t * cap) : 0;
  a[t] = mine; __syncthreads();
  for (int off = 1; off < 1024; off <<= 1) {
    int x = (t >= off) ? a[t - off] : 0;
    __syncthreads();
    a[t] += x;
    __syncthreads();
  }
  int excl = a[t] - mine;
  if (t < nB) bucket_base[t] = excl;
  if (t == 1023) bucket_base[nB] = a[1023];
}

// ---------------- Pass B: per-bucket LDS counting sort -> sedge + row_ptr ----------------
// 4 edges per loop iteration (2x i4 loads) in both passes.
__global__ void __launch_bounds__(1024)
k_bucket_sedge(const int2* __restrict__ binned, int cap,
               const int* __restrict__ bucket_fill, const int* __restrict__ bucket_base,
               int* __restrict__ row_ptr, int N, int nnz, int2* __restrict__ sedge) {
  __shared__ int rcnt[RB];
  __shared__ int sarr[RB];
  int b = blockIdx.x, t = threadIdx.x;
  int cnt = bucket_fill[b] - b * cap;
  const int2* src = binned + (size_t)b * cap;   // cap even -> 16B aligned
  int gbase = bucket_base[b];
  if (t < RB) rcnt[t] = 0;
  __syncthreads();
  for (int j = t * 4; j < cnt; j += 4096) {
    i4 two = *(const i4*)(src + j);
    atomicAdd(&rcnt[(unsigned)two[0] >> COL_BITS], 1);
    if (j + 1 < cnt) atomicAdd(&rcnt[(unsigned)two[2] >> COL_BITS], 1);
    if (j + 2 < cnt) {
      i4 tw2 = *(const i4*)(src + j + 2);
      atomicAdd(&rcnt[(unsigned)tw2[0] >> COL_BITS], 1);
      if (j + 3 < cnt) atomicAdd(&rcnt[(unsigned)tw2[2] >> COL_BITS], 1);
    }
  }
  __syncthreads();
  int mine = (t < RB) ? rcnt[t] : 0;
  if (t < RB) sarr[t] = mine;
  __syncthreads();
  for (int off = 1; off < RB; off <<= 1) {
    int x = 0;
    if (t < RB && t >= off) x = sarr[t - off];
    __syncthreads();
    if (t < RB) sarr[t] += x;
    __syncthreads();
  }
  if (t < RB) {
    int excl = sarr[t] - mine;
    int grow = (b << RB_LOG) + t;
    if (grow < N) row_ptr[grow] = gbase + excl;  // fused row_ptr construction
    rcnt[t] = gbase + excl;                      // absolute running fill counter
  }
  if (b == 0 && t == 0) row_ptr[N] = nnz;
  __syncthreads();
  for (int j = t * 4; j < cnt; j += 4096) {
    i4 two = *(const i4*)(src + j);
    {
      int pos = atomicAdd(&rcnt[(unsigned)two[0] >> COL_BITS], 1);
      sedge[pos] = make_int2(two[0] & COL_MASK, two[1]);
    }
    if (j + 1 < cnt) {
      int pos = atomicAdd(&rcnt[(unsigned)two[2] >> COL_BITS], 1);
      sedge[pos] = make_int2(two[2] & COL_MASK, two[3]);
    }
    if (j + 2 < cnt) {
      i4 tw2 = *(const i4*)(src + j + 2);
      {
        int pos = atomicAdd(&rcnt[(unsigned)tw2[0] >> COL_BITS], 1);
        sedge[pos] = make_int2(tw2[0] & COL_MASK, tw2[1]);
      }
      if (j + 3 < cnt) {
        int pos = atomicAdd(&rcnt[(unsigned)tw2[2] >> COL_BITS], 1);
        sedge[pos] = make_int2(tw2[2] & COL_MASK, tw2[3]);
      }
    }
  }
}

// ---------------- row-parallel SpMM over fp16 table: 8 lanes/row, h8 (16B) per lane ----------------
// FINAL=false: writes fp16 next.  FINAL=true: fused epilogue, reads e1/e2 rows
// (contiguous, cache-hot) and writes f32 out=(e1+e2+acc)/3 — kills k_merge.
template <bool FINAL>
__global__ void __launch_bounds__(THREADS)
k_spmm_h8(const int* __restrict__ row_ptr, const int2* __restrict__ sedge,
          const _Float16* __restrict__ prev, _Float16* __restrict__ next,
          const _Float16* __restrict__ e1, const _Float16* __restrict__ e2,
          float* __restrict__ out, int n) {
  int gid = blockIdx.x * blockDim.x + threadIdx.x;
  int row = gid >> 3, l = gid & 7;
  if (row >= n) return;
  int s = row_ptr[row], e = row_ptr[row + 1];
  f8 acc = 0.f, accb = 0.f;
  auto gat = [&](int c) -> f8 {
    h8 g = *reinterpret_cast<const h8*>(prev + (size_t)c * 64 + l * 8);
    return __builtin_convertvector(g, f8);
  };
  int j = s;
  if (j < e && (j & 1)) {  // align to even for i4 edge loads
    int2 ed = sedge[j];
    acc += __int_as_float(ed.y) * gat(ed.x);
    ++j;
  }
  const i4* s4 = (const i4*)sedge;
  for (; j + 4 <= e; j += 4) {
    i4 e01 = s4[j >> 1];
    i4 e23 = s4[(j >> 1) + 1];
    f8 g0 = gat(e01[0]), g1 = gat(e01[2]), g2 = gat(e23[0]), g3 = gat(e23[2]);
    acc  += __int_as_float(e01[1]) * g0;
    accb += __int_as_float(e01[3]) * g1;
    acc  += __int_as_float(e23[1]) * g2;
    accb += __int_as_float(e23[3]) * g3;
  }
  if (j + 2 <= e) {
    i4 e01 = s4[j >> 1];
    f8 g0 = gat(e01[0]), g1 = gat(e01[2]);
    acc  += __int_as_float(e01[1]) * g0;
    accb += __int_as_float(e01[3]) * g1;
    j += 2;
  }
  if (j < e) {
    int2 ed = sedge[j];
    acc += __int_as_float(ed.y) * gat(ed.x);
  }
  acc += accb;
  if (!FINAL) {
    *reinterpret_cast<h8*>(next + (size_t)row * 64 + l * 8) =
        __builtin_convertvector(acc, h8);
  } else {
    size_t o = (size_t)row * 64 + l * 8;
    h8 a1 = *reinterpret_cast<const h8*>(e1 + o);
    h8 a2 = *reinterpret_cast<const h8*>(e2 + o);
    f8 s3 = (acc + __builtin_convertvector(a1, f8) +
                   __builtin_convertvector(a2, f8)) * (1.0f / 3.0f);
    float4 lo = make_float4(s3[0], s3[1], s3[2], s3[3]);
    float4 hi = make_float4(s3[4], s3[5], s3[6], s3[7]);
    float4* op = reinterpret_cast<float4*>(out + o);
    op[0] = lo; op[1] = hi;
  }
}

// ---------------- fallback path: edge-parallel atomics (if ws too small for CSR) ----------------
__global__ void k_edge_atomic(const int* __restrict__ rows, const int* __restrict__ cols,
                              const float* __restrict__ vals, long long tot16,
                              const float* __restrict__ prev, float* __restrict__ nxt) {
  long long stride = (long long)gridDim.x * blockDim.x;
  for (long long i = (long long)blockIdx.x * blockDim.x + threadIdx.x; i < tot16; i += stride) {
    int e = (int)(i >> 4), l = (int)(i & 15);
    int r = rows[e], c = cols[e];
    float v = vals[e];
    const float4 x = *reinterpret_cast<const float4*>(prev + (size_t)c * 64 + l * 4);
    float* d = nxt + (size_t)r * 64 + l * 4;
    atomicAdd(d + 0, v * x.x); atomicAdd(d + 1, v * x.y);
    atomicAdd(d + 2, v * x.z); atomicAdd(d + 3, v * x.w);
  }
}

__global__ void k_accum(const float4* __restrict__ nxt, float4* __restrict__ out, int tot, int layer) {
  int stride = gridDim.x * blockDim.x;
  for (int i = blockIdx.x * blockDim.x + threadIdx.x; i < tot; i += stride) {
    float4 a = nxt[i];
    if (layer == 0) {
      out[i] = a;
    } else if (layer == 1) {
      float4 o = out[i]; o.x += a.x; o.y += a.y; o.z += a.z; o.w += a.w; out[i] = o;
    } else {
      const float inv3 = 1.0f / 3.0f;
      float4 o = out[i];
      o.x = (o.x + a.x) * inv3; o.y = (o.y + a.y) * inv3;
      o.z = (o.z + a.z) * inv3; o.w = (o.w + a.w) * inv3;
      out[i] = o;
    }
  }
}

extern "C" void kernel_launch(void* const* d_in, const int* in_sizes, int n_in,
                              void* d_out, int out_size, void* d_ws, size_t ws_size,
                              hipStream_t stream) {
  const float* user = (const float*)d_in[0];
  const float* item = (const float*)d_in[1];
  const float* vals = (const float*)d_in[2];
  const int*   rows = (const int*)d_in[3];
  const int*   cols = (const int*)d_in[4];
  const int D = 64;
  const int num_users = in_sizes[0] / D;
  const int num_items = in_sizes[1] / D;
  const int nnz = in_sizes[2];
  const int N = num_users + num_items;
  float* out = (float*)d_out;

  // ---- carve workspace ----
  size_t off = 0;
  auto carve = [&](size_t bytes) -> char* {
    char* p = (char*)d_ws + off;
    off = (off + bytes + 255) & ~(size_t)255;
    return p;
  };
  size_t egoBytesF = (size_t)N * D * sizeof(float);   // 76.8 MB
  size_t egoBytesH = (size_t)N * D * sizeof(_Float16);// 38.4 MB
  char* region1 = carve(egoBytesF);   // fp16 path: A + B tables ; fallback: egoA f32
  char* region2 = carve(egoBytesF);   // fp16 path: binned / C table ; fallback: egoB f32
  int nB = (N + RB - 1) >> RB_LOG;
  int*  row_ptr     = (int*)carve((size_t)(N + 1) * 4);
  int*  bucket_base = (int*)carve((size_t)(nB + 1) * 4);
  int*  bucket_fill = (int*)carve((size_t)nB * 4);
  int2* sedge       = (int2*)carve((size_t)nnz * 8);

  // fixed-capacity bucket regions in binned (25% + 64 margin, even)
  int cap = ((nnz / (nB > 0 ? nB : 1)) * 5 / 4 + 64) & ~1;

  _Float16* egoA_h = (_Float16*)region1;              // ego0
  _Float16* egoB_h = (_Float16*)(region1 + egoBytesH);// e1
  _Float16* egoC_h = (_Float16*)region2;              // e2 (clobbers binned after it's dead)
  int2*     binned = (int2*)region2;
  bool use_csr = (off <= ws_size) && (nB <= MAX_NB) &&
                 ((size_t)nnz * 8 <= egoBytesF) && (N < (1 << COL_BITS)) &&
                 (2 * egoBytesH <= egoBytesF) &&
                 ((size_t)nB * cap * 8 <= egoBytesF);

  if (use_csr) {
    k_init_fill<<<1, 1024, 0, stream>>>(bucket_fill, nB, cap);
    int nchunks = (nnz + CH - 1) / CH;
    k_bin<<<nchunks, BT_BIN, 0, stream>>>(rows, cols, vals, nnz, nB, cap,
                                          bucket_fill, binned);
    k_scan_buckets<<<1, 1024, 0, stream>>>(bucket_fill, nB, cap, bucket_base);
    k_bucket_sedge<<<nB, 1024, 0, stream>>>(binned, cap, bucket_fill, bucket_base,
                                            row_ptr, N, nnz, sedge);
    int totF4 = N * (D / 4);
    int uf4   = num_users * (D / 4);
    k_tofp16<<<GS_BLOCKS, THREADS, 0, stream>>>((const f4*)user, (const f4*)item,
                                                (h4*)egoA_h, uf4, totF4);

    int spmm_blocks = (N * 8 + THREADS - 1) / THREADS;
    // layer 0: ego0(A) -> e1(B)
    k_spmm_h8<false><<<spmm_blocks, THREADS, 0, stream>>>(row_ptr, sedge, egoA_h, egoB_h,
                                                          nullptr, nullptr, nullptr, N);
    // layer 1: e1(B) -> e2(C)  (binned dead now)
    k_spmm_h8<false><<<spmm_blocks, THREADS, 0, stream>>>(row_ptr, sedge, egoB_h, egoC_h,
                                                          nullptr, nullptr, nullptr, N);
    // layer 2 fused: acc = A·e2 ; out = (e1 + e2 + acc)/3
    k_spmm_h8<true><<<spmm_blocks, THREADS, 0, stream>>>(row_ptr, sedge, egoC_h, nullptr,
                                                         egoB_h, egoC_h, out, N);
  } else {
    // atomic fallback: f32 ego ping-pong in region1/region2
    float* egoA = (float*)region1;
    float* egoB = (float*)region2;
    int totF4 = N * (D / 4);
    int uf4   = num_users * (D / 4);
    k_concat<<<GS_BLOCKS, THREADS, 0, stream>>>((const float4*)user, (const float4*)item,
                                                (float4*)egoA, uf4, totF4);
    float* prev = egoA;
    float* next = egoB;
    long long tot16 = (long long)nnz * 16;
    for (int layer = 0; layer < 3; ++layer) {
      hipMemsetAsync(next, 0, egoBytesF, stream);
      k_edge_atomic<<<GS_BLOCKS * 2, THREADS, 0, stream>>>(rows, cols, vals, tot16, prev, next);
      k_accum<<<GS_BLOCKS, THREADS, 0, stream>>>((const float4*)next, (float4*)out, totF4, layer);
      float* t = prev; prev = next; next = t;
    }
  }
}

// Round 13
// 455.108 us; speedup vs baseline: 2.4558x; 1.0242x over previous
//
#include <hip/hip_runtime.h>

constexpr int GS_BLOCKS = 2048;
constexpr int THREADS   = 256;
constexpr int RB_LOG    = 9;               // rows per bucket = 512
constexpr int RB        = 1 << RB_LOG;
constexpr int CH        = 4096;            // edges per Pass-A chunk (occupancy 2.4->4.8 blk/CU)
constexpr int BT_BIN    = 1024;            // k_bin block size
constexpr int COL_BITS  = 19;              // N < 2^19
constexpr int COL_MASK  = (1 << COL_BITS) - 1;
constexpr int MAX_NB    = 1024;            // max buckets supported by LDS arrays

typedef _Float16 h4 __attribute__((ext_vector_type(4)));
typedef _Float16 h8 __attribute__((ext_vector_type(8)));
typedef float    f8 __attribute__((ext_vector_type(8)));
typedef float    f4 __attribute__((ext_vector_type(4)));
typedef int      i4 __attribute__((ext_vector_type(4)));

// ---------------- ego0 = concat(user, item) as fp16 ----------------
__global__ void k_tofp16(const f4* __restrict__ u, const f4* __restrict__ it,
                         h4* __restrict__ dst, int uf4, int tot) {
  int stride = gridDim.x * blockDim.x;
  for (int i = blockIdx.x * blockDim.x + threadIdx.x; i < tot; i += stride) {
    f4 v = (i < uf4) ? __builtin_nontemporal_load(u + i)
                     : __builtin_nontemporal_load(it + (i - uf4));
    h4 o;
    o[0] = (_Float16)v[0]; o[1] = (_Float16)v[1];
    o[2] = (_Float16)v[2]; o[3] = (_Float16)v[3];
    dst[i] = o;
  }
}

// ---------------- ego0 = concat(user, item) f32 (fallback path only) ----------------
__global__ void k_concat(const float4* __restrict__ u, const float4* __restrict__ it,
                         float4* __restrict__ dst, int uf4, int tot) {
  int stride = gridDim.x * blockDim.x;
  for (int i = blockIdx.x * blockDim.x + threadIdx.x; i < tot; i += stride)
    dst[i] = (i < uf4) ? u[i] : it[i - uf4];
}

// ---------------- init: bucket_fill[b] = b*cap ----------------
__global__ void __launch_bounds__(1024)
k_init_fill(int* __restrict__ bucket_fill, int nB, int cap) {
  int t = threadIdx.x;
  for (int b = t; b < nB; b += 1024) bucket_fill[b] = b * cap;
}

// ---------------- Pass A: chunk-local LDS binning into fixed-cap buckets ----------------
__global__ void __launch_bounds__(BT_BIN)
k_bin(const int* __restrict__ rows, const int* __restrict__ cols,
      const float* __restrict__ vals, int nnz, int nB, int cap,
      int* __restrict__ bucket_fill, int2* __restrict__ binned) {
  __shared__ int bcnt[MAX_NB];      // counts, then reused as global-base per bucket
  __shared__ int bfill[MAX_NB];     // chunk-local running rank
  __shared__ int rstash[CH];        // rows cached from phase 1 for phase 3
  int t = threadIdx.x;
  int c0 = blockIdx.x * CH;
  if (t < nB) { bcnt[t] = 0; bfill[t] = 0; }
  __syncthreads();
  // phase 1: vector count (+ stash rows as i4)
  const i4* r4 = (const i4*)(rows + c0);  // c0 % 4096 == 0 -> aligned
  i4* rs4 = (i4*)rstash;
#pragma unroll
  for (int k = 0; k < CH / (BT_BIN * 4); k++) {
    int q = t + k * BT_BIN;
    int e = c0 + q * 4;
    if (e + 3 < nnz) {
      i4 v = __builtin_nontemporal_load(r4 + q);
      rs4[q] = v;
      atomicAdd(&bcnt[v[0] >> RB_LOG], 1);
      atomicAdd(&bcnt[v[1] >> RB_LOG], 1);
      atomicAdd(&bcnt[v[2] >> RB_LOG], 1);
      atomicAdd(&bcnt[v[3] >> RB_LOG], 1);
    } else {
      for (int u = 0; u < 4; u++) {
        int ee = e + u;
        if (ee < nnz) {
          int r = rows[ee];
          rstash[q * 4 + u] = r;
          atomicAdd(&bcnt[r >> RB_LOG], 1);
        }
      }
    }
  }
  __syncthreads();
  // phase 2: reserve global range per bucket (bcnt becomes global base)
  if (t < nB) {
    int c = bcnt[t];
    bcnt[t] = (c > 0) ? atomicAdd(&bucket_fill[t], c) : 0;
  }
  __syncthreads();
  // phase 3: scatter into bucket-major bursts (vector cols/vals, rows from LDS)
  const i4* c4 = (const i4*)(cols + c0);
  const f4* v4 = (const f4*)(vals + c0);
#pragma unroll
  for (int k = 0; k < CH / (BT_BIN * 4); k++) {
    int q = t + k * BT_BIN;
    int e = c0 + q * 4;
    if (e + 3 < nnz) {
      i4 cc = __builtin_nontemporal_load(c4 + q);
      f4 vv = __builtin_nontemporal_load(v4 + q);
      i4 rr = rs4[q];
#pragma unroll
      for (int u = 0; u < 4; u++) {
        int r = rr[u];
        int b = r >> RB_LOG;
        int rank = atomicAdd(&bfill[b], 1);
        int packed = ((r & (RB - 1)) << COL_BITS) | cc[u];
        binned[bcnt[b] + rank] = make_int2(packed, __float_as_int(vv[u]));
      }
    } else {
      for (int u = 0; u < 4; u++) {
        int ee = e + u;
        if (ee < nnz) {
          int r = rstash[q * 4 + u];
          int b = r >> RB_LOG;
          int rank = atomicAdd(&bfill[b], 1);
          int packed = ((r & (RB - 1)) << COL_BITS) | cols[ee];
          binned[bcnt[b] + rank] = make_int2(packed, __float_as_int(vals[ee]));
        }
      }
    }
  }
}

// ---------------- post-scan: bucket_base = excl-scan(bucket_fill - b*cap) ----------------
__global__ void __launch_bounds__(1024)
k_scan_buckets(const int* __restrict__ bucket_fill, int nB, int cap,
               int* __restrict__ bucket_base) {
  __shared__ int a[1024];
  int t = threadIdx.x;
  int mine = (t < nB) ? (bucket_fill[t] - t * cap) : 0;
  a[t] = mine; __syncthreads();
  for (int off = 1; off < 1024; off <<= 1) {
    int x = (t >= off) ? a[t - off] : 0;
    __syncthreads();
    a[t] += x;
    __syncthreads();
  }
  int excl = a[t] - mine;
  if (t < nB) bucket_base[t] = excl;
  if (t == 1023) bucket_base[nB] = a[1023];
}

// ---------------- Pass B: per-bucket LDS counting sort -> sedge + row_ptr ----------------
// 4 edges per loop iteration (2x i4 loads) in both passes.
__global__ void __launch_bounds__(1024)
k_bucket_sedge(const int2* __restrict__ binned, int cap,
               const int* __restrict__ bucket_fill, const int* __restrict__ bucket_base,
               int* __restrict__ row_ptr, int N, int nnz, int2* __restrict__ sedge) {
  __shared__ int rcnt[RB];
  __shared__ int sarr[RB];
  int b = blockIdx.x, t = threadIdx.x;
  int cnt = bucket_fill[b] - b * cap;
  const int2* src = binned + (size_t)b * cap;   // cap even -> 16B aligned
  int gbase = bucket_base[b];
  if (t < RB) rcnt[t] = 0;
  __syncthreads();
  for (int j = t * 4; j < cnt; j += 4096) {
    i4 two = *(const i4*)(src + j);
    atomicAdd(&rcnt[(unsigned)two[0] >> COL_BITS], 1);
    if (j + 1 < cnt) atomicAdd(&rcnt[(unsigned)two[2] >> COL_BITS], 1);
    if (j + 2 < cnt) {
      i4 tw2 = *(const i4*)(src + j + 2);
      atomicAdd(&rcnt[(unsigned)tw2[0] >> COL_BITS], 1);
      if (j + 3 < cnt) atomicAdd(&rcnt[(unsigned)tw2[2] >> COL_BITS], 1);
    }
  }
  __syncthreads();
  int mine = (t < RB) ? rcnt[t] : 0;
  if (t < RB) sarr[t] = mine;
  __syncthreads();
  for (int off = 1; off < RB; off <<= 1) {
    int x = 0;
    if (t < RB && t >= off) x = sarr[t - off];
    __syncthreads();
    if (t < RB) sarr[t] += x;
    __syncthreads();
  }
  if (t < RB) {
    int excl = sarr[t] - mine;
    int grow = (b << RB_LOG) + t;
    if (grow < N) row_ptr[grow] = gbase + excl;  // fused row_ptr construction
    rcnt[t] = gbase + excl;                      // absolute running fill counter
  }
  if (b == 0 && t == 0) row_ptr[N] = nnz;
  __syncthreads();
  for (int j = t * 4; j < cnt; j += 4096) {
    i4 two = *(const i4*)(src + j);
    {
      int pos = atomicAdd(&rcnt[(unsigned)two[0] >> COL_BITS], 1);
      sedge[pos] = make_int2(two[0] & COL_MASK, two[1]);
    }
    if (j + 1 < cnt) {
      int pos = atomicAdd(&rcnt[(unsigned)two[2] >> COL_BITS], 1);
      sedge[pos] = make_int2(two[2] & COL_MASK, two[3]);
    }
    if (j + 2 < cnt) {
      i4 tw2 = *(const i4*)(src + j + 2);
      {
        int pos = atomicAdd(&rcnt[(unsigned)tw2[0] >> COL_BITS], 1);
        sedge[pos] = make_int2(tw2[0] & COL_MASK, tw2[1]);
      }
      if (j + 3 < cnt) {
        int pos = atomicAdd(&rcnt[(unsigned)tw2[2] >> COL_BITS], 1);
        sedge[pos] = make_int2(tw2[2] & COL_MASK, tw2[3]);
      }
    }
  }
}

// ---------------- row-parallel SpMM over fp16 table: 8 lanes/row, h8 (16B) per lane ----------------
// FINAL=false: writes fp16 next.  FINAL=true: fused epilogue, reads e1/e2 rows
// and writes f32 out=(e1+e2+acc)/3.
template <bool FINAL>
__global__ void __launch_bounds__(THREADS)
k_spmm_h8(const int* __restrict__ row_ptr, const int2* __restrict__ sedge,
          const _Float16* __restrict__ prev, _Float16* __restrict__ next,
          const _Float16* __restrict__ e1, const _Float16* __restrict__ e2,
          float* __restrict__ out, int n) {
  int gid = blockIdx.x * blockDim.x + threadIdx.x;
  int row = gid >> 3, l = gid & 7;
  if (row >= n) return;
  int s = row_ptr[row], e = row_ptr[row + 1];
  f8 acc = 0.f, accb = 0.f;
  auto gat = [&](int c) -> f8 {
    h8 g = *reinterpret_cast<const h8*>(prev + (size_t)c * 64 + l * 8);
    return __builtin_convertvector(g, f8);
  };
  int j = s;
  if (j < e && (j & 1)) {  // align to even for i4 edge loads
    int2 ed = sedge[j];
    acc += __int_as_float(ed.y) * gat(ed.x);
    ++j;
  }
  const i4* s4 = (const i4*)sedge;
  for (; j + 4 <= e; j += 4) {
    i4 e01 = s4[j >> 1];
    i4 e23 = s4[(j >> 1) + 1];
    f8 g0 = gat(e01[0]), g1 = gat(e01[2]), g2 = gat(e23[0]), g3 = gat(e23[2]);
    acc  += __int_as_float(e01[1]) * g0;
    accb += __int_as_float(e01[3]) * g1;
    acc  += __int_as_float(e23[1]) * g2;
    accb += __int_as_float(e23[3]) * g3;
  }
  if (j + 2 <= e) {
    i4 e01 = s4[j >> 1];
    f8 g0 = gat(e01[0]), g1 = gat(e01[2]);
    acc  += __int_as_float(e01[1]) * g0;
    accb += __int_as_float(e01[3]) * g1;
    j += 2;
  }
  if (j < e) {
    int2 ed = sedge[j];
    acc += __int_as_float(ed.y) * gat(ed.x);
  }
  acc += accb;
  if (!FINAL) {
    *reinterpret_cast<h8*>(next + (size_t)row * 64 + l * 8) =
        __builtin_convertvector(acc, h8);
  } else {
    size_t o = (size_t)row * 64 + l * 8;
    h8 a1 = *reinterpret_cast<const h8*>(e1 + o);
    h8 a2 = *reinterpret_cast<const h8*>(e2 + o);
    f8 s3 = (acc + __builtin_convertvector(a1, f8) +
                   __builtin_convertvector(a2, f8)) * (1.0f / 3.0f);
    float4 lo = make_float4(s3[0], s3[1], s3[2], s3[3]);
    float4 hi = make_float4(s3[4], s3[5], s3[6], s3[7]);
    float4* op = reinterpret_cast<float4*>(out + o);
    op[0] = lo; op[1] = hi;
  }
}

// ---------------- fallback path: edge-parallel atomics (if ws too small for CSR) ----------------
__global__ void k_edge_atomic(const int* __restrict__ rows, const int* __restrict__ cols,
                              const float* __restrict__ vals, long long tot16,
                              const float* __restrict__ prev, float* __restrict__ nxt) {
  long long stride = (long long)gridDim.x * blockDim.x;
  for (long long i = (long long)blockIdx.x * blockDim.x + threadIdx.x; i < tot16; i += stride) {
    int e = (int)(i >> 4), l = (int)(i & 15);
    int r = rows[e], c = cols[e];
    float v = vals[e];
    const float4 x = *reinterpret_cast<const float4*>(prev + (size_t)c * 64 + l * 4);
    float* d = nxt + (size_t)r * 64 + l * 4;
    atomicAdd(d + 0, v * x.x); atomicAdd(d + 1, v * x.y);
    atomicAdd(d + 2, v * x.z); atomicAdd(d + 3, v * x.w);
  }
}

__global__ void k_accum(const float4* __restrict__ nxt, float4* __restrict__ out, int tot, int layer) {
  int stride = gridDim.x * blockDim.x;
  for (int i = blockIdx.x * blockDim.x + threadIdx.x; i < tot; i += stride) {
    float4 a = nxt[i];
    if (layer == 0) {
      out[i] = a;
    } else if (layer == 1) {
      float4 o = out[i]; o.x += a.x; o.y += a.y; o.z += a.z; o.w += a.w; out[i] = o;
    } else {
      const float inv3 = 1.0f / 3.0f;
      float4 o = out[i];
      o.x = (o.x + a.x) * inv3; o.y = (o.y + a.y) * inv3;
      o.z = (o.z + a.z) * inv3; o.w = (o.w + a.w) * inv3;
      out[i] = o;
    }
  }
}

extern "C" void kernel_launch(void* const* d_in, const int* in_sizes, int n_in,
                              void* d_out, int out_size, void* d_ws, size_t ws_size,
                              hipStream_t stream) {
  const float* user = (const float*)d_in[0];
  const float* item = (const float*)d_in[1];
  const float* vals = (const float*)d_in[2];
  const int*   rows = (const int*)d_in[3];
  const int*   cols = (const int*)d_in[4];
  const int D = 64;
  const int num_users = in_sizes[0] / D;
  const int num_items = in_sizes[1] / D;
  const int nnz = in_sizes[2];
  const int N = num_users + num_items;
  float* out = (float*)d_out;

  // ---- carve workspace ----
  size_t off = 0;
  auto carve = [&](size_t bytes) -> char* {
    char* p = (char*)d_ws + off;
    off = (off + bytes + 255) & ~(size_t)255;
    return p;
  };
  size_t egoBytesF = (size_t)N * D * sizeof(float);   // 76.8 MB
  size_t egoBytesH = (size_t)N * D * sizeof(_Float16);// 38.4 MB
  char* region1 = carve(egoBytesF);   // fp16 path: A + B tables ; fallback: egoA f32
  char* region2 = carve(egoBytesF);   // fp16 path: binned / C table ; fallback: egoB f32
  int nB = (N + RB - 1) >> RB_LOG;
  int*  row_ptr     = (int*)carve((size_t)(N + 1) * 4);
  int*  bucket_base = (int*)carve((size_t)(nB + 1) * 4);
  int*  bucket_fill = (int*)carve((size_t)nB * 4);
  int2* sedge       = (int2*)carve((size_t)nnz * 8);

  // fixed-capacity bucket regions in binned (25% + 64 margin, even)
  int cap = ((nnz / (nB > 0 ? nB : 1)) * 5 / 4 + 64) & ~1;

  _Float16* egoA_h = (_Float16*)region1;              // ego0
  _Float16* egoB_h = (_Float16*)(region1 + egoBytesH);// e1
  _Float16* egoC_h = (_Float16*)region2;              // e2 (clobbers binned after it's dead)
  int2*     binned = (int2*)region2;
  bool use_csr = (off <= ws_size) && (nB <= MAX_NB) &&
                 ((size_t)nnz * 8 <= egoBytesF) && (N < (1 << COL_BITS)) &&
                 (2 * egoBytesH <= egoBytesF) &&
                 ((size_t)nB * cap * 8 <= egoBytesF);

  if (use_csr) {
    k_init_fill<<<1, 1024, 0, stream>>>(bucket_fill, nB, cap);
    int nchunks = (nnz + CH - 1) / CH;
    k_bin<<<nchunks, BT_BIN, 0, stream>>>(rows, cols, vals, nnz, nB, cap,
                                          bucket_fill, binned);
    k_scan_buckets<<<1, 1024, 0, stream>>>(bucket_fill, nB, cap, bucket_base);
    k_bucket_sedge<<<nB, 1024, 0, stream>>>(binned, cap, bucket_fill, bucket_base,
                                            row_ptr, N, nnz, sedge);
    int totF4 = N * (D / 4);
    int uf4   = num_users * (D / 4);
    k_tofp16<<<GS_BLOCKS, THREADS, 0, stream>>>((const f4*)user, (const f4*)item,
                                                (h4*)egoA_h, uf4, totF4);

    int spmm_blocks = (N * 8 + THREADS - 1) / THREADS;
    // layer 0: ego0(A) -> e1(B)
    k_spmm_h8<false><<<spmm_blocks, THREADS, 0, stream>>>(row_ptr, sedge, egoA_h, egoB_h,
                                                          nullptr, nullptr, nullptr, N);
    // layer 1: e1(B) -> e2(C)  (binned dead now)
    k_spmm_h8<false><<<spmm_blocks, THREADS, 0, stream>>>(row_ptr, sedge, egoB_h, egoC_h,
                                                          nullptr, nullptr, nullptr, N);
    // layer 2 fused: acc = A·e2 ; out = (e1 + e2 + acc)/3
    k_spmm_h8<true><<<spmm_blocks, THREADS, 0, stream>>>(row_ptr, sedge, egoC_h, nullptr,
                                                         egoB_h, egoC_h, out, N);
  } else {
    // atomic fallback: f32 ego ping-pong in region1/region2
    float* egoA = (float*)region1;
    float* egoB = (float*)region2;
    int totF4 = N * (D / 4);
    int uf4   = num_users * (D / 4);
    k_concat<<<GS_BLOCKS, THREADS, 0, stream>>>((const float4*)user, (const float4*)item,
                                                (float4*)egoA, uf4, totF4);
    float* prev = egoA;
    float* next = egoB;
    long long tot16 = (long long)nnz * 16;
    for (int layer = 0; layer < 3; ++layer) {
      hipMemsetAsync(next, 0, egoBytesF, stream);
      k_edge_atomic<<<GS_BLOCKS * 2, THREADS, 0, stream>>>(rows, cols, vals, tot16, prev, next);
      k_accum<<<GS_BLOCKS, THREADS, 0, stream>>>((const float4*)next, (float4*)out, totF4, layer);
      float* t = prev; prev = next; next = t;
    }
  }
}